// Round 4
// baseline (1047.675 us; speedup 1.0000x reference)
//
#include <hip/hip_runtime.h>
#include <math.h>

#define NUM_GRAPHS 64

typedef unsigned short ushortT;
typedef __attribute__((ext_vector_type(8))) short bf16x8;
typedef __attribute__((ext_vector_type(4))) float f32x4;

// ---- static level tables (host + device) ----
constexpr int cN[5]       = {20000, 10000, 5000, 2500, 1250};
constexpr int cE[5]       = {320000, 160000, 80000, 40000, 20000};
constexpr int cNOFF[6]    = {0, 20000, 30000, 35000, 37500, 38750};
constexpr int cEOFF[6]    = {0, 320000, 480000, 560000, 600000, 620000};
constexpr int cEBLKOFF[6] = {0, 1250, 1875, 2188, 2345, 2424};   // ceil(E/256) prefix
constexpr int cNBLKOFF[6] = {0, 79, 119, 139, 149, 154};         // ceil(N/256) prefix
constexpr int cMT[5]      = {5064, 2564, 1314, 689, 377};        // E/64 + 64 tiles
constexpr int cTILEOFF[6] = {0, 5064, 7628, 8942, 9631, 10008};
constexpr int cSEOFF[6]   = {0, 324096, 488192, 572288, 616384, 640512}; // tileOff*64

struct EPtrs { const float* ps[5]; const int* ei[5]; };

__device__ __forceinline__ int lvl_e(int b) {
    return (b >= cEBLKOFF[4]) ? 4 : (b >= cEBLKOFF[3]) ? 3 : (b >= cEBLKOFF[2]) ? 2 : (b >= cEBLKOFF[1]) ? 1 : 0;
}
__device__ __forceinline__ int lvl_n(int b) {
    return (b >= cNBLKOFF[4]) ? 4 : (b >= cNBLKOFF[3]) ? 3 : (b >= cNBLKOFF[2]) ? 2 : (b >= cNBLKOFF[1]) ? 1 : 0;
}

__device__ __forceinline__ ushortT f2bf(float f) {
    union { float f; unsigned int u; } v; v.f = f;
    unsigned int r = (v.u + 0x7FFFu + ((v.u >> 16) & 1u)) >> 16;
    return (ushortT)r;
}
__device__ __forceinline__ float bf2f(ushortT h) {
    union { float f; unsigned int u; } v; v.u = ((unsigned int)h) << 16;
    return v.f;
}

// ---------------- fused hist: per-block cell histogram + dst degree count ----------------
__global__ void k_hist(EPtrs P, int* __restrict__ dcnt, int* __restrict__ bb) {
    int b = blockIdx.x;
    int l = lvl_e(b);
    int lb = b - cEBLKOFF[l];
    int E = cE[l];
    __shared__ int h[64];
    int t = threadIdx.x;
    if (t < 64) h[t] = 0;
    __syncthreads();
    int e = lb * 256 + t;
    if (e < E) {
        const int* ei = P.ei[l];
        atomicAdd(&dcnt[cNOFF[l] + ei[E + e]], 1);
        const float* ps = P.ps[l];
        int c = (int)floorf(ps[e * 3] * 4.f) * 16 + (int)floorf(ps[e * 3 + 1] * 4.f) * 4
              + (int)floorf(ps[e * 3 + 2] * 4.f);
        atomicAdd(&h[c], 1);
    }
    __syncthreads();
    if (t < 64) bb[(size_t)b * 64 + t] = h[t];
}

// ---------------- cell scan (one block per level, lane = cell) ----------------
__global__ void k_cellscan(int* __restrict__ bb_all, int* __restrict__ csPad,
                           int* __restrict__ cellTot, int* __restrict__ cot_all) {
    int l = blockIdx.x;
    int c = threadIdx.x;
    int* bb = bb_all + (size_t)cEBLKOFF[l] * 64;
    int nblk = cEBLKOFF[l + 1] - cEBLKOFF[l];
    int run = 0;
    int b = 0;
    for (; b + 16 <= nblk; b += 16) {
        int v[16];
#pragma unroll
        for (int u = 0; u < 16; u++) v[u] = bb[(b + u) * 64 + c];
#pragma unroll
        for (int u = 0; u < 16; u++) { bb[(b + u) * 64 + c] = run; run += v[u]; }
    }
    for (; b < nblk; b++) { int v = bb[b * 64 + c]; bb[b * 64 + c] = run; run += v; }
    int tot = run;
    cellTot[l * 64 + c] = tot;
    int tiles = (tot + 63) >> 6;
    int x = tiles;
#pragma unroll
    for (int off = 1; off < 64; off <<= 1) { int y = __shfl_up(x, off, 64); if (c >= off) x += y; }
    int tileBase = x - tiles;
    csPad[l * 64 + c] = tileBase * 64;
    int* cot = cot_all + cTILEOFF[l];
    for (int i = 0; i < tiles; i++) cot[tileBase + i] = c;
    int nT = __shfl(x, 63, 64);
    int mt = cMT[l];
    for (int i = nT + c; i < mt; i += 64) cot[i] = -1;
}

// ---------------- cell scatter (all levels) ----------------
__global__ void k_cellscatter(EPtrs P, const int* __restrict__ bb, const int* __restrict__ csPad,
                              int* __restrict__ ssd, float* __restrict__ sfx, float* __restrict__ sfy,
                              float* __restrict__ sfz, int* __restrict__ eposc) {
    int b = blockIdx.x;
    int l = lvl_e(b);
    int lb = b - cEBLKOFF[l];
    int E = cE[l];
    __shared__ int base[64];
    __shared__ int cnt[64];
    int t = threadIdx.x;
    if (t < 64) { base[t] = bb[(size_t)b * 64 + t] + csPad[l * 64 + t]; cnt[t] = 0; }
    __syncthreads();
    int e = lb * 256 + t;
    if (e < E) {
        const float* ps = P.ps[l];
        float v0 = ps[e * 3] * 4.f, v1 = ps[e * 3 + 1] * 4.f, v2 = ps[e * 3 + 2] * 4.f;
        float f0 = floorf(v0), f1v = floorf(v1), f2 = floorf(v2);
        int c = (int)f0 * 16 + (int)f1v * 4 + (int)f2;
        int r = atomicAdd(&cnt[c], 1);
        int pos = base[c] + r;
        const int* ei = P.ei[l];
        ssd[cSEOFF[l] + pos] = ei[e] | (ei[E + e] << 16);
        sfx[cSEOFF[l] + pos] = v0 - f0;
        sfy[cSEOFF[l] + pos] = v1 - f1v;
        sfz[cSEOFF[l] + pos] = v2 - f2;
        eposc[cEOFF[l] + e] = pos;
    }
}

// ---------------- node-degree scan stage 1 (per-256 block scan) ----------------
__global__ void k_nscan1(const int* __restrict__ dcnt, int* __restrict__ dbase, int* __restrict__ bsum) {
    int b = blockIdx.x;
    int l = lvl_n(b);
    int lb = b - cNBLKOFF[l];
    int n = cN[l];
    __shared__ int sh[256];
    int t = threadIdx.x;
    int i = lb * 256 + t;
    int v = (i < n) ? dcnt[cNOFF[l] + i] : 0;
    sh[t] = v;
    __syncthreads();
    for (int off = 1; off < 256; off <<= 1) {
        int y = (t >= off) ? sh[t - off] : 0;
        __syncthreads();
        sh[t] += y;
        __syncthreads();
    }
    if (i < n) dbase[cNOFF[l] + i] = sh[t] - v;
    if (t == 255) bsum[b] = sh[255];
}

// ---------------- node-degree scan stage 2 (block sums, one block per level) -----------
__global__ void k_nscan2(const int* __restrict__ bsum, int* __restrict__ boff) {
    int l = blockIdx.x;
    int o = cNBLKOFF[l];
    int nb = cNBLKOFF[l + 1] - o;
    int t = threadIdx.x;
    int v = (t < nb) ? bsum[o + t] : 0;
    int s = v;
#pragma unroll
    for (int off = 1; off < 64; off <<= 1) { int y = __shfl_up(s, off, 64); if (t >= off) s += y; }
    int tot = __shfl(s, 63, 64);
    if (t < nb) boff[o + t] = s - v;
    int t2 = t + 64;
    int v2 = (t2 < nb) ? bsum[o + t2] : 0;
    int s2 = v2;
#pragma unroll
    for (int off = 1; off < 64; off <<= 1) { int y = __shfl_up(s2, off, 64); if (t >= off) s2 += y; }
    if (t2 < nb) boff[o + t2] = tot + s2 - v2;
}

// ---------------- dst scatter: cpos maps dst-order position -> cell-order position -----
__global__ void k_dscatter(EPtrs P, const int* __restrict__ dbase, const int* __restrict__ boff,
                           int* __restrict__ rank, const int* __restrict__ eposc,
                           int* __restrict__ cpos) {
    int b = blockIdx.x;
    int l = lvl_e(b);
    int lb = b - cEBLKOFF[l];
    int E = cE[l];
    int e = lb * 256 + threadIdx.x;
    if (e >= E) return;
    int dst = P.ei[l][E + e];
    int p = dbase[cNOFF[l] + dst] + boff[cNBLKOFF[l] + (dst >> 8)]
          + atomicAdd(&rank[cNOFF[l] + dst], 1);
    cpos[cEOFF[l] + p] = eposc[cEOFF[l] + e];
}

// -------- W swizzle: Wb[125][CIN][64] fp32 -> MFMA B-frag-ordered bf16 hi/lo ----------
template<int CIN>
__global__ void wswz(const float* __restrict__ Wb, uint4* __restrict__ hi4, uint4* __restrict__ lo4) {
    const int T = CIN / 32;
    int idx = blockIdx.x * 256 + threadIdx.x;
    if (idx >= 125 * T * 4 * 64) return;
    int lane = idx & 63;
    int blk = (idx >> 6) & 3;
    int rest = idx >> 8;
    int st = rest % T;
    int s = rest / T;
    int q = lane >> 4, n = blk * 16 + (lane & 15);
    union { ushortT u[8]; uint4 v; } ph, pl;
#pragma unroll
    for (int j = 0; j < 8; j++) {
        int k = st * 32 + q * 8 + j;
        float wv = Wb[((size_t)s * CIN + k) * 64 + n];
        ushortT hh = f2bf(wv);
        ph.u[j] = hh;
        pl.u[j] = f2bf(wv - bf2f(hh));
    }
    hi4[idx] = ph.v;
    lo4[idx] = pl.v;
}

// ---------------- Conv A: dst-ordered edges, register run-accumulate, flush on change ---
template<int C1>
__launch_bounds__(256)
__global__ void conv_a(const float* __restrict__ x, const float* __restrict__ Wa,
                       const int* __restrict__ cpos, const int* __restrict__ ssd,
                       const float* __restrict__ sfx, const float* __restrict__ sfy,
                       const float* __restrict__ sfz, const int* __restrict__ cot,
                       int E, float* __restrict__ f1) {
    int lane = threadIdx.x & 63;
    int gid = blockIdx.x * 4 + (threadIdx.x >> 6);
    int base = gid * 32;
    if (base >= E) return;
    int nn = E - base; if (nn > 32) nn = 32;
    float acc = 0.f;
    int cur = -1;
    for (int j = 0; j < nn; j++) {
        int cp = cpos[base + j];
        int sd = ssd[cp];
        int dst = sd >> 16, src = sd & 0xFFFF;
        if (dst != cur) {
            if (cur >= 0 && lane < C1) atomicAdd(&f1[(size_t)cur * C1 + lane], acc);
            acc = 0.f; cur = dst;
        }
        int cell = cot[cp >> 6];
        float fx = sfx[cp], fy = sfy[cp], fz = sfz[cp];
        float xs = x[src];
        float gx = 1.f - fx, gy = 1.f - fy, gz = 1.f - fz;
        int cx = cell >> 4, cy = (cell >> 2) & 3, cz = cell & 3;
#pragma unroll
        for (int cor = 0; cor < 8; cor++) {
            int slot = (cx + (cor & 1)) * 25 + (cy + ((cor >> 1) & 1)) * 5 + (cz + ((cor >> 2) & 1));
            float wc = ((cor & 1) ? fx : gx) * (((cor >> 1) & 1) ? fy : gy) * (((cor >> 2) & 1) ? fz : gz);
            float wv = (lane < C1) ? Wa[slot * C1 + lane] : 0.f;
            acc = fmaf(wc * xs, wv, acc);
        }
    }
    if (cur >= 0 && lane < C1) atomicAdd(&f1[(size_t)cur * C1 + lane], acc);
}

// ---------------- Conv A epilogue ----------------
template<int C1>
__global__ void node_a2(float* __restrict__ f1, const float* __restrict__ x,
                        const float* __restrict__ root, const float* __restrict__ bias,
                        const int* __restrict__ dcnt, int n) {
    int i = blockIdx.x * blockDim.x + threadIdx.x;
    if (i >= n * C1) return;
    int node = i / C1, ch = i - node * C1;
    int dv = dcnt[node];
    float d = (float)(dv > 1 ? dv : 1);
    float o = f1[i] / d + x[node] * root[ch] + bias[ch];
    f1[i] = fmaxf(o, 0.f);
}

// ---------------- Conv B: MFMA, col-split waves, A-frags VGPR-resident over corners ----
template<int CIN>
__launch_bounds__(256)
__global__ void conv_b2(const float* __restrict__ f1, const int* __restrict__ ssd,
                        const float* __restrict__ sfx, const float* __restrict__ sfy,
                        const float* __restrict__ sfz,
                        const uint4* __restrict__ whi, const uint4* __restrict__ wlo,
                        const int* __restrict__ cot, const int* __restrict__ csPad,
                        const int* __restrict__ cellTot, float* __restrict__ accb) {
    const int T = CIN / 32;
    const int SA = CIN + 8;
    int tile = blockIdx.x;
    int cell = cot[tile];
    if (cell < 0) return;
    int tb = tile * 64;
    int valid = csPad[cell] + cellTot[cell] - tb;
    if (valid > 64) valid = 64;

    __shared__ alignas(16) ushortT Ahi[64 * (CIN + 8)];
    __shared__ alignas(16) ushortT Alo[64 * (CIN + 8)];
    __shared__ float fxs[64], fys[64], fzs[64];
    __shared__ int dsts[64];

    int t = threadIdx.x;
    if (t < 64) {
        bool v = t < valid;
        int sd = v ? ssd[tb + t] : 0;
        dsts[t] = sd >> 16;
        fxs[t] = v ? sfx[tb + t] : 0.f;
        fys[t] = v ? sfy[tb + t] : 0.f;
        fzs[t] = v ? sfz[tb + t] : 0.f;
    }
    {
        const int FPT = CIN / 16;
        int edge = t >> 2, seg = t & 3;
        ushortT* ah = &Ahi[edge * SA + seg * (CIN / 4)];
        ushortT* al = &Alo[edge * SA + seg * (CIN / 4)];
        if (edge < valid) {
            int src = ssd[tb + edge] & 0xFFFF;
            const float4* fp = (const float4*)(f1 + (size_t)src * CIN);
#pragma unroll
            for (int u = 0; u < FPT; u++) {
                float4 vv = fp[seg * FPT + u];
                float vals[4] = {vv.x, vv.y, vv.z, vv.w};
                ushort4 hh, ll;
                ushortT* hp = (ushortT*)&hh; ushortT* lp = (ushortT*)&ll;
#pragma unroll
                for (int c2 = 0; c2 < 4; c2++) {
                    ushortT h = f2bf(vals[c2]);
                    hp[c2] = h;
                    lp[c2] = f2bf(vals[c2] - bf2f(h));
                }
                *(ushort4*)(ah + u * 4) = hh;
                *(ushort4*)(al + u * 4) = ll;
            }
        } else {
            ushort4 z; ushortT* zp = (ushortT*)&z;
            zp[0] = zp[1] = zp[2] = zp[3] = 0;
#pragma unroll
            for (int u = 0; u < FPT; u++) {
                *(ushort4*)(ah + u * 4) = z;
                *(ushort4*)(al + u * 4) = z;
            }
        }
    }
    __syncthreads();

    int lane = t & 63, w = t >> 6;
    int q = lane >> 4, m = lane & 15;

    bf16x8 ahr[4][T], alr[4][T];
#pragma unroll
    for (int mt = 0; mt < 4; mt++)
#pragma unroll
        for (int st = 0; st < T; st++) {
            ahr[mt][st] = *(const bf16x8*)&Ahi[(16 * mt + m) * SA + st * 32 + q * 8];
            alr[mt][st] = *(const bf16x8*)&Alo[(16 * mt + m) * SA + st * 32 + q * 8];
        }
    float fxr[16], fyr[16], fzr[16];
#pragma unroll
    for (int mt = 0; mt < 4; mt++)
#pragma unroll
        for (int rr = 0; rr < 4; rr++) {
            int row = 16 * mt + q * 4 + rr;
            fxr[mt * 4 + rr] = fxs[row];
            fyr[mt * 4 + rr] = fys[row];
            fzr[mt * 4 + rr] = fzs[row];
        }
    int cx = cell >> 4, cy = (cell >> 2) & 3, cz = cell & 3;
    f32x4 acc[4];
#pragma unroll
    for (int mt = 0; mt < 4; mt++) acc[mt] = (f32x4){0.f, 0.f, 0.f, 0.f};

#pragma unroll
    for (int cor = 0; cor < 8; cor++) {
        const int bx = cor & 1, by = (cor >> 1) & 1, bz = (cor >> 2) & 1;
        int slot = (cx + bx) * 25 + (cy + by) * 5 + (cz + bz);
        f32x4 C[4];
#pragma unroll
        for (int mt = 0; mt < 4; mt++) C[mt] = (f32x4){0.f, 0.f, 0.f, 0.f};
#pragma unroll
        for (int st = 0; st < T; st++) {
            size_t fb = ((size_t)(slot * T + st) * 4 + w) * 64 + lane;
            bf16x8 bh = __builtin_bit_cast(bf16x8, whi[fb]);
            bf16x8 bl = __builtin_bit_cast(bf16x8, wlo[fb]);
#pragma unroll
            for (int mt = 0; mt < 4; mt++) {
                C[mt] = __builtin_amdgcn_mfma_f32_16x16x32_bf16(ahr[mt][st], bh, C[mt], 0, 0, 0);
                C[mt] = __builtin_amdgcn_mfma_f32_16x16x32_bf16(alr[mt][st], bh, C[mt], 0, 0, 0);
                C[mt] = __builtin_amdgcn_mfma_f32_16x16x32_bf16(ahr[mt][st], bl, C[mt], 0, 0, 0);
            }
        }
#pragma unroll
        for (int mt = 0; mt < 4; mt++)
#pragma unroll
            for (int rr = 0; rr < 4; rr++) {
                int i16 = mt * 4 + rr;
                float wr = (bx ? fxr[i16] : 1.f - fxr[i16]) * (by ? fyr[i16] : 1.f - fyr[i16])
                         * (bz ? fzr[i16] : 1.f - fzr[i16]);
                acc[mt][rr] = fmaf(wr, C[mt][rr], acc[mt][rr]);
            }
    }
#pragma unroll
    for (int mt = 0; mt < 4; mt++)
#pragma unroll
        for (int rr = 0; rr < 4; rr++) {
            int row = 16 * mt + q * 4 + rr;
            if (row < valid)
                atomicAdd(&accb[(size_t)dsts[row] * 64 + 16 * w + m], acc[mt][rr]);
        }
}

// ---------------- Conv B epilogue + readout: run-aggregated hsum flush ----------------
template<int CIN>
__launch_bounds__(256)
__global__ void node_b2(const float* __restrict__ accb, const float* __restrict__ f1,
                        const float* __restrict__ rootb, const float* __restrict__ biasb,
                        const int* __restrict__ dcnt, const int* __restrict__ batch,
                        int n, float* __restrict__ hsum, float* __restrict__ gcnt, int lvloff) {
    __shared__ float rt[CIN * 64];
    int t = threadIdx.x;
    for (int i = t; i < CIN * 64; i += 256) rt[i] = rootb[i];
    __syncthreads();
    int lane = t & 63;
    int gid = blockIdx.x * 4 + (t >> 6);
    int base = gid * 16;
    if (base >= n) return;
    float bias = biasb[lane];
    int curg = -1; float hacc = 0.f; int crun = 0;
    int nn = n - base; if (nn > 16) nn = 16;
    for (int j = 0; j < nn; j++) {
        int node = base + j;
        int g = batch[node];
        if (g != curg) {
            if (curg >= 0) {
                atomicAdd(&hsum[curg * 320 + lvloff + lane], hacc);
                if (lane == 0) atomicAdd(&gcnt[curg], (float)crun);
            }
            curg = g; hacc = 0.f; crun = 0;
        }
        float s = accb[(size_t)node * 64 + lane];
        int dv = dcnt[node];
        float d = (float)(dv > 1 ? dv : 1);
        s /= d;
        float fr = (lane < CIN) ? f1[(size_t)node * CIN + lane] : 0.f;
#pragma unroll
        for (int i = 0; i < CIN; i++) s = fmaf(__shfl(fr, i, 64), rt[i * 64 + lane], s);
        s += bias;
        s = fmaxf(s, 0.f);
        hacc += s; crun++;
    }
    if (curg >= 0) {
        atomicAdd(&hsum[curg * 320 + lvloff + lane], hacc);
        if (lane == 0) atomicAdd(&gcnt[curg], (float)crun);
    }
}

// ---------------- FC + log_softmax ----------------
__global__ void fc_kernel(const float* __restrict__ hsum, const float* __restrict__ gcnt,
                          const float* __restrict__ fcw, const float* __restrict__ fcb,
                          float* __restrict__ out) {
    int g = threadIdx.x;
    if (g >= NUM_GRAPHS) return;
    float logit[10];
#pragma unroll
    for (int t = 0; t < 10; t++) logit[t] = fcb[t];
    for (int j = 0; j < 320; j++) {
        float c = fmaxf(gcnt[(j >> 6) * NUM_GRAPHS + g], 1.f);
        float h = hsum[g * 320 + j] / c;
#pragma unroll
        for (int t = 0; t < 10; t++) logit[t] = fmaf(h, fcw[j * 10 + t], logit[t]);
    }
    float m = logit[0];
#pragma unroll
    for (int t = 1; t < 10; t++) m = fmaxf(m, logit[t]);
    float sum = 0.f;
#pragma unroll
    for (int t = 0; t < 10; t++) sum += expf(logit[t] - m);
    float lse = m + logf(sum);
#pragma unroll
    for (int t = 0; t < 10; t++) out[g * 10 + t] = logit[t] - lse;
}

extern "C" void kernel_launch(void* const* d_in, const int* in_sizes, int n_in,
                              void* d_out, int out_size, void* d_ws, size_t ws_size,
                              hipStream_t stream) {
    int* wsI = (int*)d_ws;
    int*   dcnt    = wsI;                        // 38750
    int*   rank    = dcnt + 38750;               // 38750
    float* hsum    = (float*)(rank + 38750);     // 20480
    float* gcnt    = hsum + 20480;               // 320
    float* f1      = gcnt + 320;                 // 640000
    float* accb    = f1 + 640000;                // 1280000
    int*   dbase   = (int*)(accb + 1280000);     // 38750
    int*   bsum    = dbase + 38750;              // 160
    int*   boff    = bsum + 160;                 // 160
    int*   cposA   = boff + 160;                 // 620000
    int*   eposc   = cposA + 620000;             // 620000
    int*   ssd     = eposc + 620000;             // 640512
    float* sfx     = (float*)(ssd + 640512);
    float* sfy     = sfx + 640512;
    float* sfz     = sfy + 640512;
    int*   bb      = (int*)(sfz + 640512);       // 2424*64 = 155136
    int*   csPad   = bb + 155136;                // 320
    int*   cellTot = csPad + 320;                // 320
    int*   cot     = cellTot + 320;              // 10008
    uint4* whi     = (uint4*)(((size_t)(cot + 10008) + 15) & ~(size_t)15);
    uint4* wlo     = whi + 64000;

    // zero dcnt + rank + hsum + gcnt (contiguous)
    hipMemsetAsync(dcnt, 0, (size_t)(38750 * 2 + 20480 + 320) * sizeof(int), stream);

    EPtrs P;
    for (int l = 0; l < 5; l++) {
        P.ps[l] = (const float*)d_in[l * 10 + 1];
        P.ei[l] = (const int*)d_in[l * 10 + 2];
    }

    // fused prep across all levels
    k_hist<<<2424, 256, 0, stream>>>(P, dcnt, bb);
    k_cellscan<<<5, 64, 0, stream>>>(bb, csPad, cellTot, cot);
    k_cellscatter<<<2424, 256, 0, stream>>>(P, bb, csPad, ssd, sfx, sfy, sfz, eposc);
    k_nscan1<<<154, 256, 0, stream>>>(dcnt, dbase, bsum);
    k_nscan2<<<5, 64, 0, stream>>>(bsum, boff);
    k_dscatter<<<2424, 256, 0, stream>>>(P, dbase, boff, rank, eposc, cposA);

    for (int l = 0; l < 5; l++) {
        const int b = l * 10;
        const float* x     = (const float*)d_in[b + 0];
        const int*   batch = (const int*)d_in[b + 3];
        const float* Wa    = (const float*)d_in[b + 4];
        const float* roota = (const float*)d_in[b + 5];
        const float* biasa = (const float*)d_in[b + 6];
        const float* Wb    = (const float*)d_in[b + 7];
        const float* rootb = (const float*)d_in[b + 8];
        const float* biasb = (const float*)d_in[b + 9];
        int n = cN[l], e = cE[l];

        hipMemsetAsync(f1, 0, (size_t)(640000 + 1280000) * sizeof(float), stream);

        int gridA = (e + 127) / 128;
        int gridB = (((n + 15) / 16) + 3) / 4;
        if (l == 0) {
            wswz<32><<<(125 * 1 * 4 * 64 + 255) / 256, 256, 0, stream>>>(Wb, whi, wlo);
            conv_a<32><<<gridA, 256, 0, stream>>>(x, Wa, cposA + cEOFF[l], ssd + cSEOFF[l],
                                                  sfx + cSEOFF[l], sfy + cSEOFF[l], sfz + cSEOFF[l],
                                                  cot + cTILEOFF[l], e, f1);
            node_a2<32><<<(n * 32 + 255) / 256, 256, 0, stream>>>(f1, x, roota, biasa, dcnt + cNOFF[l], n);
            conv_b2<32><<<cMT[l], 256, 0, stream>>>(f1, ssd + cSEOFF[l], sfx + cSEOFF[l],
                                                    sfy + cSEOFF[l], sfz + cSEOFF[l], whi, wlo,
                                                    cot + cTILEOFF[l], csPad + l * 64, cellTot + l * 64, accb);
            node_b2<32><<<gridB, 256, 0, stream>>>(accb, f1, rootb, biasb, dcnt + cNOFF[l], batch,
                                                   n, hsum, gcnt + l * 64, l * 64);
        } else {
            wswz<64><<<(125 * 2 * 4 * 64 + 255) / 256, 256, 0, stream>>>(Wb, whi, wlo);
            conv_a<64><<<gridA, 256, 0, stream>>>(x, Wa, cposA + cEOFF[l], ssd + cSEOFF[l],
                                                  sfx + cSEOFF[l], sfy + cSEOFF[l], sfz + cSEOFF[l],
                                                  cot + cTILEOFF[l], e, f1);
            node_a2<64><<<(n * 64 + 255) / 256, 256, 0, stream>>>(f1, x, roota, biasa, dcnt + cNOFF[l], n);
            conv_b2<64><<<cMT[l], 256, 0, stream>>>(f1, ssd + cSEOFF[l], sfx + cSEOFF[l],
                                                    sfy + cSEOFF[l], sfz + cSEOFF[l], whi, wlo,
                                                    cot + cTILEOFF[l], csPad + l * 64, cellTot + l * 64, accb);
            node_b2<64><<<gridB, 256, 0, stream>>>(accb, f1, rootb, biasb, dcnt + cNOFF[l], batch,
                                                   n, hsum, gcnt + l * 64, l * 64);
        }
    }

    const float* fcw = (const float*)d_in[50];
    const float* fcb = (const float*)d_in[51];
    fc_kernel<<<1, 64, 0, stream>>>(hsum, gcnt, fcw, fcb, (float*)d_out);
}

// Round 5
// 763.068 us; speedup vs baseline: 1.3730x; 1.3730x over previous
//
#include <hip/hip_runtime.h>
#include <hip/hip_fp16.h>
#include <math.h>

#define NUM_GRAPHS 64

typedef unsigned short ushortT;
typedef __attribute__((ext_vector_type(8))) short bf16x8;
typedef __attribute__((ext_vector_type(4))) float f32x4;

// ---- static level tables ----
constexpr int cN[5]       = {20000, 10000, 5000, 2500, 1250};
constexpr int cE[5]       = {320000, 160000, 80000, 40000, 20000};
constexpr int cNOFF[6]    = {0, 20000, 30000, 35000, 37500, 38750};
constexpr int cEOFF[6]    = {0, 320000, 480000, 560000, 600000, 620000};
constexpr int cEBLKOFF[6] = {0, 1250, 1875, 2188, 2345, 2424};
constexpr int cNBLKOFF[6] = {0, 79, 119, 139, 149, 154};
constexpr int cMT[5]      = {5064, 2564, 1314, 689, 377};
constexpr int cTILEOFF[6] = {0, 5064, 7628, 8942, 9631, 10008};
constexpr int cSEOFF[6]   = {0, 324096, 488192, 572288, 616384, 640512};
constexpr int cF1OFF[6]   = {0, 640000, 1280000, 1600000, 1760000, 1840000}; // f1 compact stride C1
constexpr int cWOFF[6]    = {0, 32000, 96000, 160000, 224000, 288000};       // uint4 units

struct P5f { const float* p[5]; };
struct P5i { const int* p[5]; };

__device__ __forceinline__ int lvl_e(int b) {
    return (b >= cEBLKOFF[4]) ? 4 : (b >= cEBLKOFF[3]) ? 3 : (b >= cEBLKOFF[2]) ? 2 : (b >= cEBLKOFF[1]) ? 1 : 0;
}
__device__ __forceinline__ int lvl_n(int b) {
    return (b >= cNBLKOFF[4]) ? 4 : (b >= cNBLKOFF[3]) ? 3 : (b >= cNBLKOFF[2]) ? 2 : (b >= cNBLKOFF[1]) ? 1 : 0;
}

__device__ __forceinline__ ushortT f2bf(float f) {
    union { float f; unsigned int u; } v; v.f = f;
    unsigned int r = (v.u + 0x7FFFu + ((v.u >> 16) & 1u)) >> 16;
    return (ushortT)r;
}
__device__ __forceinline__ float bf2f(ushortT h) {
    union { float f; unsigned int u; } v; v.u = ((unsigned int)h) << 16;
    return v.f;
}

// ---------------- prep: per-block cell histogram + dst degree count ----------------
__global__ void k_hist(P5f PS, P5i EI, int* __restrict__ dcnt, int* __restrict__ bb) {
    int b = blockIdx.x;
    int l = lvl_e(b);
    int lb = b - cEBLKOFF[l];
    int E = cE[l];
    __shared__ int h[64];
    int t = threadIdx.x;
    if (t < 64) h[t] = 0;
    __syncthreads();
    int e = lb * 256 + t;
    if (e < E) {
        atomicAdd(&dcnt[cNOFF[l] + EI.p[l][E + e]], 1);
        const float* ps = PS.p[l];
        int c = (int)floorf(ps[e * 3] * 4.f) * 16 + (int)floorf(ps[e * 3 + 1] * 4.f) * 4
              + (int)floorf(ps[e * 3 + 2] * 4.f);
        atomicAdd(&h[c], 1);
    }
    __syncthreads();
    if (t < 64) bb[(size_t)b * 64 + t] = h[t];
}

// ---------------- cell scan ----------------
__global__ void k_cellscan(int* __restrict__ bb_all, int* __restrict__ csPad,
                           int* __restrict__ cellTot, int* __restrict__ cot_all) {
    int l = blockIdx.x;
    int c = threadIdx.x;
    int* bb = bb_all + (size_t)cEBLKOFF[l] * 64;
    int nblk = cEBLKOFF[l + 1] - cEBLKOFF[l];
    int run = 0;
    int b = 0;
    for (; b + 16 <= nblk; b += 16) {
        int v[16];
#pragma unroll
        for (int u = 0; u < 16; u++) v[u] = bb[(b + u) * 64 + c];
#pragma unroll
        for (int u = 0; u < 16; u++) { bb[(b + u) * 64 + c] = run; run += v[u]; }
    }
    for (; b < nblk; b++) { int v = bb[b * 64 + c]; bb[b * 64 + c] = run; run += v; }
    int tot = run;
    cellTot[l * 64 + c] = tot;
    int tiles = (tot + 63) >> 6;
    int x = tiles;
#pragma unroll
    for (int off = 1; off < 64; off <<= 1) { int y = __shfl_up(x, off, 64); if (c >= off) x += y; }
    int tileBase = x - tiles;
    csPad[l * 64 + c] = tileBase * 64;
    int* cot = cot_all + cTILEOFF[l];
    for (int i = 0; i < tiles; i++) cot[tileBase + i] = c;
    int nT = __shfl(x, 63, 64);
    int mt = cMT[l];
    for (int i = nT + c; i < mt; i += 64) cot[i] = -1;
}

// ---------------- cell scatter ----------------
__global__ void k_cellscatter(P5f PS, P5i EI, const int* __restrict__ bb, const int* __restrict__ csPad,
                              int* __restrict__ ssd, float* __restrict__ sfx, float* __restrict__ sfy,
                              float* __restrict__ sfz, int* __restrict__ eposc) {
    int b = blockIdx.x;
    int l = lvl_e(b);
    int lb = b - cEBLKOFF[l];
    int E = cE[l];
    __shared__ int base[64];
    __shared__ int cnt[64];
    int t = threadIdx.x;
    if (t < 64) { base[t] = bb[(size_t)b * 64 + t] + csPad[l * 64 + t]; cnt[t] = 0; }
    __syncthreads();
    int e = lb * 256 + t;
    if (e < E) {
        const float* ps = PS.p[l];
        float v0 = ps[e * 3] * 4.f, v1 = ps[e * 3 + 1] * 4.f, v2 = ps[e * 3 + 2] * 4.f;
        float f0 = floorf(v0), f1v = floorf(v1), f2v = floorf(v2);
        int c = (int)f0 * 16 + (int)f1v * 4 + (int)f2v;
        int r = atomicAdd(&cnt[c], 1);
        int pos = base[c] + r;
        const int* ei = EI.p[l];
        ssd[cSEOFF[l] + pos] = ei[e] | (ei[E + e] << 16);
        sfx[cSEOFF[l] + pos] = v0 - f0;
        sfy[cSEOFF[l] + pos] = v1 - f1v;
        sfz[cSEOFF[l] + pos] = v2 - f2v;
        eposc[cEOFF[l] + e] = pos;
    }
}

// ---------------- node-degree scans ----------------
__global__ void k_nscan1(const int* __restrict__ dcnt, int* __restrict__ dbase, int* __restrict__ bsum) {
    int b = blockIdx.x;
    int l = lvl_n(b);
    int lb = b - cNBLKOFF[l];
    int n = cN[l];
    __shared__ int sh[256];
    int t = threadIdx.x;
    int i = lb * 256 + t;
    int v = (i < n) ? dcnt[cNOFF[l] + i] : 0;
    sh[t] = v;
    __syncthreads();
    for (int off = 1; off < 256; off <<= 1) {
        int y = (t >= off) ? sh[t - off] : 0;
        __syncthreads();
        sh[t] += y;
        __syncthreads();
    }
    if (i < n) dbase[cNOFF[l] + i] = sh[t] - v;
    if (t == 255) bsum[b] = sh[255];
}

__global__ void k_nscan2(const int* __restrict__ bsum, int* __restrict__ boff) {
    int l = blockIdx.x;
    int o = cNBLKOFF[l];
    int nb = cNBLKOFF[l + 1] - o;
    int t = threadIdx.x;
    int v = (t < nb) ? bsum[o + t] : 0;
    int s = v;
#pragma unroll
    for (int off = 1; off < 64; off <<= 1) { int y = __shfl_up(s, off, 64); if (t >= off) s += y; }
    int tot = __shfl(s, 63, 64);
    if (t < nb) boff[o + t] = s - v;
    int t2 = t + 64;
    int v2 = (t2 < nb) ? bsum[o + t2] : 0;
    int s2 = v2;
#pragma unroll
    for (int off = 1; off < 64; off <<= 1) { int y = __shfl_up(s2, off, 64); if (t >= off) s2 += y; }
    if (t2 < nb) boff[o + t2] = tot + s2 - v2;
}

// ---------------- dst scatter: cposA (dst-pos->cell-pos), c2d (cell-pos->dst-pos) -----
__global__ void k_dscatter(P5i EI, const int* __restrict__ dbase, const int* __restrict__ boff,
                           int* __restrict__ rank, const int* __restrict__ eposc,
                           int* __restrict__ cposA, int* __restrict__ c2d) {
    int b = blockIdx.x;
    int l = lvl_e(b);
    int lb = b - cEBLKOFF[l];
    int E = cE[l];
    int e = lb * 256 + threadIdx.x;
    if (e >= E) return;
    int dst = EI.p[l][E + e];
    int p = dbase[cNOFF[l] + dst] + boff[cNBLKOFF[l] + (dst >> 8)]
          + atomicAdd(&rank[cNOFF[l] + dst], 1);
    int posc = eposc[cEOFF[l] + e];
    cposA[cEOFF[l] + p] = posc;
    c2d[cSEOFF[l] + posc] = p;
}

// -------- W swizzle (all levels): Wb[125][CIN][64] fp32 -> MFMA B-frag bf16 hi/lo -----
__global__ void k_wswz(P5f WB, uint4* __restrict__ hi4, uint4* __restrict__ lo4) {
    int idx = blockIdx.x * 256 + threadIdx.x;
    if (idx >= 288000) return;
    int l = (idx >= 224000) ? 4 : (idx >= 160000) ? 3 : (idx >= 96000) ? 2 : (idx >= 32000) ? 1 : 0;
    int local = idx - cWOFF[l];
    int T = l ? 2 : 1, C = l ? 64 : 32;
    int lane = local & 63;
    int blk = (local >> 6) & 3;
    int rest = local >> 8;
    int st = rest % T, s = rest / T;
    int q = lane >> 4, n = blk * 16 + (lane & 15);
    const float* W = WB.p[l];
    union { ushortT u[8]; uint4 v; } ph, pl;
#pragma unroll
    for (int j = 0; j < 8; j++) {
        int k = st * 32 + q * 8 + j;
        float wv = W[((size_t)s * C + k) * 64 + n];
        ushortT hh = f2bf(wv);
        ph.u[j] = hh;
        pl.u[j] = f2bf(wv - bf2f(hh));
    }
    hi4[idx] = ph.v;
    lo4[idx] = pl.v;
}

// ---------------- Conv A core: dst-ordered walk, register run-accumulate --------------
template<int C1>
__device__ __forceinline__ void conv_a_run(const float* __restrict__ x, const float* __restrict__ Wa,
                                           const int* __restrict__ cpos, const int* __restrict__ ssd_l,
                                           const float* __restrict__ sfx_l, const float* __restrict__ sfy_l,
                                           const float* __restrict__ sfz_l, const int* __restrict__ cot_l,
                                           int base, int nn, int lane, float* __restrict__ f1l) {
    float acc = 0.f;
    int cur = -1;
    for (int j = 0; j < nn; j++) {
        int cp = cpos[base + j];
        int sd = ssd_l[cp];
        int dst = sd >> 16, src = sd & 0xFFFF;
        if (dst != cur) {
            if (cur >= 0 && lane < C1) atomicAdd(&f1l[(size_t)cur * C1 + lane], acc);
            acc = 0.f; cur = dst;
        }
        int cell = cot_l[cp >> 6];
        float fx = sfx_l[cp], fy = sfy_l[cp], fz = sfz_l[cp];
        float xs = x[src];
        float gx = 1.f - fx, gy = 1.f - fy, gz = 1.f - fz;
        int cx = cell >> 4, cy = (cell >> 2) & 3, cz = cell & 3;
#pragma unroll
        for (int cor = 0; cor < 8; cor++) {
            int slot = (cx + (cor & 1)) * 25 + (cy + ((cor >> 1) & 1)) * 5 + (cz + ((cor >> 2) & 1));
            float wc = ((cor & 1) ? fx : gx) * (((cor >> 1) & 1) ? fy : gy) * (((cor >> 2) & 1) ? fz : gz);
            float wv = (lane < C1) ? Wa[slot * C1 + lane] : 0.f;
            acc = fmaf(wc * xs, wv, acc);
        }
    }
    if (cur >= 0 && lane < C1) atomicAdd(&f1l[(size_t)cur * C1 + lane], acc);
}

__launch_bounds__(256)
__global__ void conv_a1(const float* __restrict__ x, const float* __restrict__ Wa,
                        const int* __restrict__ cposA, const int* __restrict__ ssd,
                        const float* __restrict__ sfx, const float* __restrict__ sfy,
                        const float* __restrict__ sfz, const int* __restrict__ cot,
                        float* __restrict__ f1) {
    int lane = threadIdx.x & 63;
    int gid = blockIdx.x * 4 + (threadIdx.x >> 6);
    int base = gid * 32;
    if (base >= 320000) return;
    int nn = 320000 - base; if (nn > 32) nn = 32;
    conv_a_run<32>(x, Wa, cposA, ssd, sfx, sfy, sfz, cot, base, nn, lane, f1);
}

__launch_bounds__(256)
__global__ void conv_a2(P5f X, P5f WA, const int* __restrict__ cposA, const int* __restrict__ ssd,
                        const float* __restrict__ sfx, const float* __restrict__ sfy,
                        const float* __restrict__ sfz, const int* __restrict__ cot,
                        float* __restrict__ f1) {
    const int FE[5] = {0, 160000, 240000, 280000, 300000};
    int lane = threadIdx.x & 63;
    int gid = blockIdx.x * 4 + (threadIdx.x >> 6);
    int bf = gid * 32;
    if (bf >= 300000) return;
    int li = (bf >= 280000) ? 3 : (bf >= 240000) ? 2 : (bf >= 160000) ? 1 : 0;
    int l = li + 1;
    int base = bf - FE[li];
    int nn = cE[l] - base; if (nn > 32) nn = 32;
    conv_a_run<64>(X.p[l], WA.p[l], cposA + cEOFF[l], ssd + cSEOFF[l],
                   sfx + cSEOFF[l], sfy + cSEOFF[l], sfz + cSEOFF[l],
                   cot + cTILEOFF[l], base, nn, lane, f1 + cF1OFF[l]);
}

// ---------------- Conv A epilogue (all levels) ----------------
__global__ void k_node_a(P5f X, P5f RootA, P5f BiasA, const int* __restrict__ dcnt,
                         float* __restrict__ f1) {
    int i = blockIdx.x * 256 + threadIdx.x;
    if (i >= 1840000) return;
    int l = (i >= 1760000) ? 4 : (i >= 1600000) ? 3 : (i >= 1280000) ? 2 : (i >= 640000) ? 1 : 0;
    int local = i - cF1OFF[l];
    int node, ch;
    if (l == 0) { node = local >> 5; ch = local & 31; }
    else        { node = local >> 6; ch = local & 63; }
    int dv = dcnt[cNOFF[l] + node];
    float d = (float)(dv > 1 ? dv : 1);
    float o = f1[i] / d + X.p[l][node] * RootA.p[l][ch] + BiasA.p[l][ch];
    f1[i] = fmaxf(o, 0.f);
}

// ---------------- Conv B tile core (MFMA, stores fp16 P rows in dst order) ------------
template<int CIN>
__device__ __forceinline__ void conv_b_tile(
    const float* __restrict__ f1l, const int* __restrict__ ssd_l,
    const float* __restrict__ sfx_l, const float* __restrict__ sfy_l,
    const float* __restrict__ sfz_l, const int* __restrict__ c2d_l,
    const uint4* __restrict__ whiL, const uint4* __restrict__ wloL,
    int cell, int tb, int valid, __half* __restrict__ pout,
    ushortT* Ahi, ushortT* Alo, float* fxs, float* fys, float* fzs, int* d2s) {
    const int T = CIN / 32;
    const int SA = CIN + 8;
    int t = threadIdx.x;
    if (t < 64) {
        bool v = t < valid;
        fxs[t] = v ? sfx_l[tb + t] : 0.f;
        fys[t] = v ? sfy_l[tb + t] : 0.f;
        fzs[t] = v ? sfz_l[tb + t] : 0.f;
        d2s[t] = v ? c2d_l[tb + t] : 0;
    }
    {
        const int FPT = CIN / 16;
        int edge = t >> 2, seg = t & 3;
        ushortT* ah = &Ahi[edge * SA + seg * (CIN / 4)];
        ushortT* al = &Alo[edge * SA + seg * (CIN / 4)];
        if (edge < valid) {
            int src = ssd_l[tb + edge] & 0xFFFF;
            const float4* fp = (const float4*)(f1l + (size_t)src * CIN);
#pragma unroll
            for (int u = 0; u < FPT; u++) {
                float4 vv = fp[seg * FPT + u];
                float vals[4] = {vv.x, vv.y, vv.z, vv.w};
                ushort4 hh, ll;
                ushortT* hp = (ushortT*)&hh; ushortT* lp = (ushortT*)&ll;
#pragma unroll
                for (int c2 = 0; c2 < 4; c2++) {
                    ushortT h = f2bf(vals[c2]);
                    hp[c2] = h;
                    lp[c2] = f2bf(vals[c2] - bf2f(h));
                }
                *(ushort4*)(ah + u * 4) = hh;
                *(ushort4*)(al + u * 4) = ll;
            }
        } else {
            ushort4 z; ushortT* zp = (ushortT*)&z;
            zp[0] = zp[1] = zp[2] = zp[3] = 0;
#pragma unroll
            for (int u = 0; u < FPT; u++) {
                *(ushort4*)(ah + u * 4) = z;
                *(ushort4*)(al + u * 4) = z;
            }
        }
    }
    __syncthreads();

    int lane = t & 63, w = t >> 6;
    int q = lane >> 4, m = lane & 15;

    bf16x8 ahr[4][T], alr[4][T];
#pragma unroll
    for (int mt = 0; mt < 4; mt++)
#pragma unroll
        for (int st = 0; st < T; st++) {
            ahr[mt][st] = *(const bf16x8*)&Ahi[(16 * mt + m) * SA + st * 32 + q * 8];
            alr[mt][st] = *(const bf16x8*)&Alo[(16 * mt + m) * SA + st * 32 + q * 8];
        }
    float fxr[16], fyr[16], fzr[16];
#pragma unroll
    for (int mt = 0; mt < 4; mt++)
#pragma unroll
        for (int rr = 0; rr < 4; rr++) {
            int row = 16 * mt + q * 4 + rr;
            fxr[mt * 4 + rr] = fxs[row];
            fyr[mt * 4 + rr] = fys[row];
            fzr[mt * 4 + rr] = fzs[row];
        }
    int cx = cell >> 4, cy = (cell >> 2) & 3, cz = cell & 3;
    f32x4 acc[4];
#pragma unroll
    for (int mt = 0; mt < 4; mt++) acc[mt] = (f32x4){0.f, 0.f, 0.f, 0.f};

#pragma unroll
    for (int cor = 0; cor < 8; cor++) {
        const int bx = cor & 1, by = (cor >> 1) & 1, bz = (cor >> 2) & 1;
        int slot = (cx + bx) * 25 + (cy + by) * 5 + (cz + bz);
        f32x4 C[4];
#pragma unroll
        for (int mt = 0; mt < 4; mt++) C[mt] = (f32x4){0.f, 0.f, 0.f, 0.f};
#pragma unroll
        for (int st = 0; st < T; st++) {
            size_t fb = ((size_t)(slot * T + st) * 4 + w) * 64 + lane;
            bf16x8 bh = __builtin_bit_cast(bf16x8, whiL[fb]);
            bf16x8 bl = __builtin_bit_cast(bf16x8, wloL[fb]);
#pragma unroll
            for (int mt = 0; mt < 4; mt++) {
                C[mt] = __builtin_amdgcn_mfma_f32_16x16x32_bf16(ahr[mt][st], bh, C[mt], 0, 0, 0);
                C[mt] = __builtin_amdgcn_mfma_f32_16x16x32_bf16(alr[mt][st], bh, C[mt], 0, 0, 0);
                C[mt] = __builtin_amdgcn_mfma_f32_16x16x32_bf16(ahr[mt][st], bl, C[mt], 0, 0, 0);
            }
        }
#pragma unroll
        for (int mt = 0; mt < 4; mt++)
#pragma unroll
            for (int rr = 0; rr < 4; rr++) {
                int i16 = mt * 4 + rr;
                float wr = (bx ? fxr[i16] : 1.f - fxr[i16]) * (by ? fyr[i16] : 1.f - fyr[i16])
                         * (bz ? fzr[i16] : 1.f - fzr[i16]);
                acc[mt][rr] = fmaf(wr, C[mt][rr], acc[mt][rr]);
            }
    }
#pragma unroll
    for (int mt = 0; mt < 4; mt++)
#pragma unroll
        for (int rr = 0; rr < 4; rr++) {
            int row = 16 * mt + q * 4 + rr;
            if (row < valid)
                pout[(size_t)d2s[row] * 64 + 16 * w + m] = __float2half(acc[mt][rr]);
        }
}

__launch_bounds__(256)
__global__ void conv_b32(const float* __restrict__ f1, const int* __restrict__ ssd,
                         const float* __restrict__ sfx, const float* __restrict__ sfy,
                         const float* __restrict__ sfz, const int* __restrict__ c2d,
                         const uint4* __restrict__ whi, const uint4* __restrict__ wlo,
                         const int* __restrict__ cot, const int* __restrict__ csPad,
                         const int* __restrict__ cellTot, __half* __restrict__ Ph) {
    __shared__ alignas(16) ushortT Ahi[64 * 40];
    __shared__ alignas(16) ushortT Alo[64 * 40];
    __shared__ float fxs[64], fys[64], fzs[64];
    __shared__ int d2s[64];
    int tile = blockIdx.x;
    int cell = cot[tile];
    if (cell < 0) return;
    int tb = tile * 64;
    int valid = csPad[cell] + cellTot[cell] - tb;
    if (valid > 64) valid = 64;
    conv_b_tile<32>(f1, ssd, sfx, sfy, sfz, c2d, whi, wlo, cell, tb, valid, Ph,
                    Ahi, Alo, fxs, fys, fzs, d2s);
}

__launch_bounds__(256)
__global__ void conv_b64(const float* __restrict__ f1, const int* __restrict__ ssd,
                         const float* __restrict__ sfx, const float* __restrict__ sfy,
                         const float* __restrict__ sfz, const int* __restrict__ c2d,
                         const uint4* __restrict__ whi, const uint4* __restrict__ wlo,
                         const int* __restrict__ cot, const int* __restrict__ csPad,
                         const int* __restrict__ cellTot, __half* __restrict__ Ph) {
    __shared__ alignas(16) ushortT Ahi[64 * 72];
    __shared__ alignas(16) ushortT Alo[64 * 72];
    __shared__ float fxs[64], fys[64], fzs[64];
    __shared__ int d2s[64];
    const int TB2[4] = {0, 2564, 3878, 4567};
    const int PB2[4] = {0, 160000, 240000, 280000};
    int blk = blockIdx.x;
    int li = (blk >= 4567) ? 3 : (blk >= 3878) ? 2 : (blk >= 2564) ? 1 : 0;
    int l = li + 1;
    int tile = blk - TB2[li];
    int cell = cot[cTILEOFF[l] + tile];
    if (cell < 0) return;
    int tb = tile * 64;
    int valid = csPad[l * 64 + cell] + cellTot[l * 64 + cell] - tb;
    if (valid > 64) valid = 64;
    conv_b_tile<64>(f1 + cF1OFF[l], ssd + cSEOFF[l], sfx + cSEOFF[l], sfy + cSEOFF[l],
                    sfz + cSEOFF[l], c2d + cSEOFF[l], whi + cWOFF[l], wlo + cWOFF[l],
                    cell, tb, valid, Ph + (size_t)PB2[li] * 64,
                    Ahi, Alo, fxs, fys, fzs, d2s);
}

// ---------------- node gather: sum contiguous P rows + root + bias + relu -> f2 -------
template<int CIN>
__device__ __forceinline__ void node_b_node(const __half* __restrict__ Ph, int start, int deg,
                                            const float* __restrict__ f1l, int nodeLocal,
                                            const float* __restrict__ rootb, const float* __restrict__ biasb,
                                            float* __restrict__ f2row, int lane) {
    const __half* pr = Ph + (size_t)start * 64 + lane;
    float s0 = 0.f, s1 = 0.f;
    int j = 0;
    for (; j + 2 <= deg; j += 2) {
        s0 += __half2float(pr[(size_t)j * 64]);
        s1 += __half2float(pr[(size_t)(j + 1) * 64]);
    }
    if (j < deg) s0 += __half2float(pr[(size_t)j * 64]);
    float s = s0 + s1;
    int dv = deg > 1 ? deg : 1;
    s /= (float)dv;
    float fr = (lane < CIN) ? f1l[(size_t)nodeLocal * CIN + lane] : 0.f;
#pragma unroll 8
    for (int i = 0; i < CIN; i++) s = fmaf(__shfl(fr, i, 64), rootb[i * 64 + lane], s);
    s += biasb[lane];
    f2row[lane] = fmaxf(s, 0.f);
}

__launch_bounds__(256)
__global__ void node_b32(const __half* __restrict__ Ph, const int* __restrict__ dbase,
                         const int* __restrict__ boff, const int* __restrict__ dcnt,
                         const float* __restrict__ f1, const float* __restrict__ rootb,
                         const float* __restrict__ biasb, float* __restrict__ f2) {
    int lane = threadIdx.x & 63;
    int node = blockIdx.x * 4 + (threadIdx.x >> 6);
    if (node >= 20000) return;
    int start = dbase[node] + boff[node >> 8];
    int deg = dcnt[node];
    node_b_node<32>(Ph, start, deg, f1, node, rootb, biasb, f2 + (size_t)node * 64, lane);
}

__launch_bounds__(256)
__global__ void node_b64(const __half* __restrict__ Ph, const int* __restrict__ dbase,
                         const int* __restrict__ boff, const int* __restrict__ dcnt,
                         const float* __restrict__ f1, P5f RootB, P5f BiasB,
                         float* __restrict__ f2) {
    const int NB2[4] = {0, 2500, 3750, 4375};
    const int PB2[4] = {0, 160000, 240000, 280000};
    int lane = threadIdx.x & 63;
    int blk = blockIdx.x;
    int li = (blk >= 4375) ? 3 : (blk >= 3750) ? 2 : (blk >= 2500) ? 1 : 0;
    int l = li + 1;
    int node = (blk - NB2[li]) * 4 + (threadIdx.x >> 6);
    if (node >= cN[l]) return;
    int start = dbase[cNOFF[l] + node] + boff[cNBLKOFF[l] + (node >> 8)];
    int deg = dcnt[cNOFF[l] + node];
    node_b_node<64>(Ph + (size_t)PB2[li] * 64, start, deg, f1 + cF1OFF[l], node,
                    RootB.p[l], BiasB.p[l], f2 + (size_t)(cNOFF[l] + node) * 64, lane);
}

// ---------------- readout: run-accumulated graph mean sums ----------------
__launch_bounds__(256)
__global__ void k_read(const float* __restrict__ f2, P5i Batch,
                       float* __restrict__ hsum, float* __restrict__ gcnt) {
    const int RC[5] = {0, 1250, 1875, 2188, 2345};
    int t = threadIdx.x;
    int lane = t & 63;
    int w = blockIdx.x * 4 + (t >> 6);
    if (w >= 2424) return;
    int l = (w >= 2345) ? 4 : (w >= 2188) ? 3 : (w >= 1875) ? 2 : (w >= 1250) ? 1 : 0;
    int base = (w - RC[l]) * 16;
    int Nl = cN[l];
    int nn = Nl - base; if (nn > 16) nn = 16;
    const int* batch = Batch.p[l];
    const float* fb = f2 + (size_t)(cNOFF[l] + base) * 64;
    int curg = -1; float hacc = 0.f; int crun = 0;
    for (int j = 0; j < nn; j++) {
        int g = batch[base + j];
        if (g != curg) {
            if (curg >= 0) {
                atomicAdd(&hsum[curg * 320 + l * 64 + lane], hacc);
                if (lane == 0) atomicAdd(&gcnt[l * 64 + curg], (float)crun);
            }
            curg = g; hacc = 0.f; crun = 0;
        }
        hacc += fb[(size_t)j * 64 + lane];
        crun++;
    }
    if (curg >= 0) {
        atomicAdd(&hsum[curg * 320 + l * 64 + lane], hacc);
        if (lane == 0) atomicAdd(&gcnt[l * 64 + curg], (float)crun);
    }
}

// ---------------- FC + log_softmax ----------------
__global__ void fc_kernel(const float* __restrict__ hsum, const float* __restrict__ gcnt,
                          const float* __restrict__ fcw, const float* __restrict__ fcb,
                          float* __restrict__ out) {
    int g = threadIdx.x;
    if (g >= NUM_GRAPHS) return;
    float logit[10];
#pragma unroll
    for (int t = 0; t < 10; t++) logit[t] = fcb[t];
    for (int j = 0; j < 320; j++) {
        float c = fmaxf(gcnt[(j >> 6) * NUM_GRAPHS + g], 1.f);
        float h = hsum[g * 320 + j] / c;
#pragma unroll
        for (int t = 0; t < 10; t++) logit[t] = fmaf(h, fcw[j * 10 + t], logit[t]);
    }
    float m = logit[0];
#pragma unroll
    for (int t = 1; t < 10; t++) m = fmaxf(m, logit[t]);
    float sum = 0.f;
#pragma unroll
    for (int t = 0; t < 10; t++) sum += expf(logit[t] - m);
    float lse = m + logf(sum);
#pragma unroll
    for (int t = 0; t < 10; t++) out[g * 10 + t] = logit[t] - lse;
}

extern "C" void kernel_launch(void* const* d_in, const int* in_sizes, int n_in,
                              void* d_out, int out_size, void* d_ws, size_t ws_size,
                              hipStream_t stream) {
    int* wsI = (int*)d_ws;
    int*   dcnt  = wsI;                          // 38750
    int*   rank  = dcnt + 38750;                 // 38750
    float* hsum  = (float*)(rank + 38750);       // 20480
    float* gcnt  = hsum + 20480;                 // 320
    float* f1    = gcnt + 320;                   // 1,840,000 (compact per-level stride C1)
    float* f2    = f1 + 1840000;                 // 2,480,000 (38750*64)
    int*   dbase = (int*)(f2 + 2480000);         // 38750
    int*   bsum  = dbase + 38750;                // 160
    int*   boff  = bsum + 160;                   // 160
    int*   eposc = boff + 160;                   // 620000
    int*   cposA = eposc + 620000;               // 620000
    int*   c2d   = cposA + 620000;               // 640512
    int*   ssd   = c2d + 640512;                 // 640512
    float* sfx   = (float*)(ssd + 640512);
    float* sfy   = sfx + 640512;
    float* sfz   = sfy + 640512;
    int*   bb    = (int*)(sfz + 640512);         // 155136
    int*   csPad = bb + 155136;                  // 320
    int*   cellTot = csPad + 320;                // 320
    int*   cot   = cellTot + 320;                // 10008
    uint4* whi   = (uint4*)(((size_t)(cot + 10008) + 15) & ~(size_t)15);  // 288000
    uint4* wlo   = whi + 288000;                 // 288000
    __half* Ph   = (__half*)(wlo + 288000);      // 324096*64 halves (~41.5MB)

    // zero dcnt + rank + hsum + gcnt + f1 (contiguous)
    hipMemsetAsync(dcnt, 0, (size_t)(38750 * 2 + 20480 + 320 + 1840000) * sizeof(int), stream);

    P5f PS, X, WA, RootA, BiasA, WB, RootB, BiasB;
    P5i EI, Batch;
    for (int l = 0; l < 5; l++) {
        const int b = l * 10;
        X.p[l]     = (const float*)d_in[b + 0];
        PS.p[l]    = (const float*)d_in[b + 1];
        EI.p[l]    = (const int*)d_in[b + 2];
        Batch.p[l] = (const int*)d_in[b + 3];
        WA.p[l]    = (const float*)d_in[b + 4];
        RootA.p[l] = (const float*)d_in[b + 5];
        BiasA.p[l] = (const float*)d_in[b + 6];
        WB.p[l]    = (const float*)d_in[b + 7];
        RootB.p[l] = (const float*)d_in[b + 8];
        BiasB.p[l] = (const float*)d_in[b + 9];
    }

    // prep (all levels fused)
    k_hist<<<2424, 256, 0, stream>>>(PS, EI, dcnt, bb);
    k_cellscan<<<5, 64, 0, stream>>>(bb, csPad, cellTot, cot);
    k_cellscatter<<<2424, 256, 0, stream>>>(PS, EI, bb, csPad, ssd, sfx, sfy, sfz, eposc);
    k_nscan1<<<154, 256, 0, stream>>>(dcnt, dbase, bsum);
    k_nscan2<<<5, 64, 0, stream>>>(bsum, boff);
    k_dscatter<<<2424, 256, 0, stream>>>(EI, dbase, boff, rank, eposc, cposA, c2d);
    k_wswz<<<1125, 256, 0, stream>>>(WB, whi, wlo);

    // conv A + epilogue
    conv_a1<<<2500, 256, 0, stream>>>(X.p[0], WA.p[0], cposA, ssd, sfx, sfy, sfz, cot, f1);
    conv_a2<<<2344, 256, 0, stream>>>(X, WA, cposA, ssd, sfx, sfy, sfz, cot, f1);
    k_node_a<<<7188, 256, 0, stream>>>(X, RootA, BiasA, dcnt, f1);

    // conv B + node gather (P buffer reused between l1 and l2-5)
    conv_b32<<<5064, 256, 0, stream>>>(f1, ssd, sfx, sfy, sfz, c2d, whi, wlo,
                                       csPad /*unused-cot? no*/ == nullptr ? cot : cot, csPad, cellTot, Ph);
    node_b32<<<5000, 256, 0, stream>>>(Ph, dbase, boff, dcnt, f1, RootB.p[0], BiasB.p[0], f2);
    conv_b64<<<4944, 256, 0, stream>>>(f1, ssd, sfx, sfy, sfz, c2d, whi, wlo, cot, csPad, cellTot, Ph);
    node_b64<<<4688, 256, 0, stream>>>(Ph, dbase, boff, dcnt, f1, RootB, BiasB, f2);

    // readout + FC
    k_read<<<606, 256, 0, stream>>>(f2, Batch, hsum, gcnt);
    fc_kernel<<<1, 64, 0, stream>>>(hsum, gcnt, (const float*)d_in[50], (const float*)d_in[51],
                                    (float*)d_out);
}

// Round 6
// 625.278 us; speedup vs baseline: 1.6755x; 1.2204x over previous
//
#include <hip/hip_runtime.h>
#include <hip/hip_fp16.h>
#include <math.h>

#define NUM_GRAPHS 64

typedef unsigned short ushortT;
typedef __attribute__((ext_vector_type(8))) short bf16x8;
typedef __attribute__((ext_vector_type(4))) float f32x4;

// ---- static level tables ----
constexpr int cN[5]       = {20000, 10000, 5000, 2500, 1250};
constexpr int cE[5]       = {320000, 160000, 80000, 40000, 20000};
constexpr int cNOFF[6]    = {0, 20000, 30000, 35000, 37500, 38750};
constexpr int cEOFF[6]    = {0, 320000, 480000, 560000, 600000, 620000};
constexpr int cEBLKOFF[6] = {0, 1250, 1875, 2188, 2345, 2424};
constexpr int cNBLKOFF[6] = {0, 79, 119, 139, 149, 154};
constexpr int cMT[5]      = {5064, 2564, 1314, 689, 377};
constexpr int cTILEOFF[6] = {0, 5064, 7628, 8942, 9631, 10008};
constexpr int cSEOFF[6]   = {0, 324096, 488192, 572288, 616384, 640512};
constexpr int cF1OFF[6]   = {0, 640000, 1280000, 1600000, 1760000, 1840000};
constexpr int cWOFF[6]    = {0, 32000, 96000, 160000, 224000, 288000};
constexpr int cABLK[6]    = {0, 1250, 1875, 2188, 2345, 2424};  // ceil(N/16) prefix

struct P5f { const float* p[5]; };
struct P5i { const int* p[5]; };

__device__ __forceinline__ int lvl_e(int b) {
    return (b >= cEBLKOFF[4]) ? 4 : (b >= cEBLKOFF[3]) ? 3 : (b >= cEBLKOFF[2]) ? 2 : (b >= cEBLKOFF[1]) ? 1 : 0;
}
__device__ __forceinline__ int lvl_n(int b) {
    return (b >= cNBLKOFF[4]) ? 4 : (b >= cNBLKOFF[3]) ? 3 : (b >= cNBLKOFF[2]) ? 2 : (b >= cNBLKOFF[1]) ? 1 : 0;
}

__device__ __forceinline__ ushortT f2bf(float f) {
    union { float f; unsigned int u; } v; v.f = f;
    unsigned int r = (v.u + 0x7FFFu + ((v.u >> 16) & 1u)) >> 16;
    return (ushortT)r;
}
__device__ __forceinline__ float bf2f(ushortT h) {
    union { float f; unsigned int u; } v; v.u = ((unsigned int)h) << 16;
    return v.f;
}

// ---------------- prep: per-block cell histogram + dst degree count ----------------
__global__ void k_hist(P5f PS, P5i EI, int* __restrict__ dcnt, int* __restrict__ bb) {
    int b = blockIdx.x;
    int l = lvl_e(b);
    int lb = b - cEBLKOFF[l];
    int E = cE[l];
    __shared__ int h[64];
    int t = threadIdx.x;
    if (t < 64) h[t] = 0;
    __syncthreads();
    int e = lb * 256 + t;
    if (e < E) {
        atomicAdd(&dcnt[cNOFF[l] + EI.p[l][E + e]], 1);
        const float* ps = PS.p[l];
        int c = (int)floorf(ps[e * 3] * 4.f) * 16 + (int)floorf(ps[e * 3 + 1] * 4.f) * 4
              + (int)floorf(ps[e * 3 + 2] * 4.f);
        atomicAdd(&h[c], 1);
    }
    __syncthreads();
    if (t < 64) bb[(size_t)b * 64 + t] = h[t];
}

// ---------------- cell scan ----------------
__global__ void k_cellscan(int* __restrict__ bb_all, int* __restrict__ csPad,
                           int* __restrict__ cellTot, int* __restrict__ cot_all) {
    int l = blockIdx.x;
    int c = threadIdx.x;
    int* bb = bb_all + (size_t)cEBLKOFF[l] * 64;
    int nblk = cEBLKOFF[l + 1] - cEBLKOFF[l];
    int run = 0;
    int b = 0;
    for (; b + 16 <= nblk; b += 16) {
        int v[16];
#pragma unroll
        for (int u = 0; u < 16; u++) v[u] = bb[(b + u) * 64 + c];
#pragma unroll
        for (int u = 0; u < 16; u++) { bb[(b + u) * 64 + c] = run; run += v[u]; }
    }
    for (; b < nblk; b++) { int v = bb[b * 64 + c]; bb[b * 64 + c] = run; run += v; }
    int tot = run;
    cellTot[l * 64 + c] = tot;
    int tiles = (tot + 63) >> 6;
    int x = tiles;
#pragma unroll
    for (int off = 1; off < 64; off <<= 1) { int y = __shfl_up(x, off, 64); if (c >= off) x += y; }
    int tileBase = x - tiles;
    csPad[l * 64 + c] = tileBase * 64;
    int* cot = cot_all + cTILEOFF[l];
    for (int i = 0; i < tiles; i++) cot[tileBase + i] = c;
    int nT = __shfl(x, 63, 64);
    int mt = cMT[l];
    for (int i = nT + c; i < mt; i += 64) cot[i] = -1;
}

// ---------------- cell scatter ----------------
__global__ void k_cellscatter(P5f PS, P5i EI, const int* __restrict__ bb, const int* __restrict__ csPad,
                              int* __restrict__ ssd, float* __restrict__ sfx, float* __restrict__ sfy,
                              float* __restrict__ sfz, int* __restrict__ eposc) {
    int b = blockIdx.x;
    int l = lvl_e(b);
    int lb = b - cEBLKOFF[l];
    int E = cE[l];
    __shared__ int base[64];
    __shared__ int cnt[64];
    int t = threadIdx.x;
    if (t < 64) { base[t] = bb[(size_t)b * 64 + t] + csPad[l * 64 + t]; cnt[t] = 0; }
    __syncthreads();
    int e = lb * 256 + t;
    if (e < E) {
        const float* ps = PS.p[l];
        float v0 = ps[e * 3] * 4.f, v1 = ps[e * 3 + 1] * 4.f, v2 = ps[e * 3 + 2] * 4.f;
        float f0 = floorf(v0), f1v = floorf(v1), f2v = floorf(v2);
        int c = (int)f0 * 16 + (int)f1v * 4 + (int)f2v;
        int r = atomicAdd(&cnt[c], 1);
        int pos = base[c] + r;
        const int* ei = EI.p[l];
        ssd[cSEOFF[l] + pos] = ei[e] | (ei[E + e] << 16);
        sfx[cSEOFF[l] + pos] = v0 - f0;
        sfy[cSEOFF[l] + pos] = v1 - f1v;
        sfz[cSEOFF[l] + pos] = v2 - f2v;
        eposc[cEOFF[l] + e] = pos;
    }
}

// ---------------- node-degree scans ----------------
__global__ void k_nscan1(const int* __restrict__ dcnt, int* __restrict__ dbase, int* __restrict__ bsum) {
    int b = blockIdx.x;
    int l = lvl_n(b);
    int lb = b - cNBLKOFF[l];
    int n = cN[l];
    __shared__ int sh[256];
    int t = threadIdx.x;
    int i = lb * 256 + t;
    int v = (i < n) ? dcnt[cNOFF[l] + i] : 0;
    sh[t] = v;
    __syncthreads();
    for (int off = 1; off < 256; off <<= 1) {
        int y = (t >= off) ? sh[t - off] : 0;
        __syncthreads();
        sh[t] += y;
        __syncthreads();
    }
    if (i < n) dbase[cNOFF[l] + i] = sh[t] - v;
    if (t == 255) bsum[b] = sh[255];
}

__global__ void k_nscan2(const int* __restrict__ bsum, int* __restrict__ boff) {
    int l = blockIdx.x;
    int o = cNBLKOFF[l];
    int nb = cNBLKOFF[l + 1] - o;
    int t = threadIdx.x;
    int v = (t < nb) ? bsum[o + t] : 0;
    int s = v;
#pragma unroll
    for (int off = 1; off < 64; off <<= 1) { int y = __shfl_up(s, off, 64); if (t >= off) s += y; }
    int tot = __shfl(s, 63, 64);
    if (t < nb) boff[o + t] = s - v;
    int t2 = t + 64;
    int v2 = (t2 < nb) ? bsum[o + t2] : 0;
    int s2 = v2;
#pragma unroll
    for (int off = 1; off < 64; off <<= 1) { int y = __shfl_up(s2, off, 64); if (t >= off) s2 += y; }
    if (t2 < nb) boff[o + t2] = tot + s2 - v2;
}

// ---- dst scatter: build c2d (cell-pos -> dst-pos) + dst-ordered edge records --------
__global__ void k_dscatter(P5f PS, P5i EI, const int* __restrict__ dbase, const int* __restrict__ boff,
                           int* __restrict__ rank, const int* __restrict__ eposc,
                           int* __restrict__ c2d, int* __restrict__ dss, int* __restrict__ dcell,
                           float* __restrict__ dfx, float* __restrict__ dfy, float* __restrict__ dfz) {
    int b = blockIdx.x;
    int l = lvl_e(b);
    int lb = b - cEBLKOFF[l];
    int E = cE[l];
    int e = lb * 256 + threadIdx.x;
    if (e >= E) return;
    const int* ei = EI.p[l];
    int src = ei[e];
    int dst = ei[E + e];
    int p = dbase[cNOFF[l] + dst] + boff[cNBLKOFF[l] + (dst >> 8)]
          + atomicAdd(&rank[cNOFF[l] + dst], 1);
    int posc = eposc[cEOFF[l] + e];
    c2d[cSEOFF[l] + posc] = p;
    const float* ps = PS.p[l];
    float v0 = ps[e * 3] * 4.f, v1 = ps[e * 3 + 1] * 4.f, v2 = ps[e * 3 + 2] * 4.f;
    float f0 = floorf(v0), f1v = floorf(v1), f2v = floorf(v2);
    int cell = (int)f0 * 16 + (int)f1v * 4 + (int)f2v;
    int po = cEOFF[l] + p;
    dss[po] = src | (dst << 16);
    dcell[po] = cell;
    dfx[po] = v0 - f0;
    dfy[po] = v1 - f1v;
    dfz[po] = v2 - f2v;
}

// -------- W swizzle (all levels): Wb[125][CIN][64] fp32 -> MFMA B-frag bf16 hi/lo -----
__global__ void k_wswz(P5f WB, uint4* __restrict__ hi4, uint4* __restrict__ lo4) {
    int idx = blockIdx.x * 256 + threadIdx.x;
    if (idx >= 288000) return;
    int l = (idx >= 224000) ? 4 : (idx >= 160000) ? 3 : (idx >= 96000) ? 2 : (idx >= 32000) ? 1 : 0;
    int local = idx - cWOFF[l];
    int T = l ? 2 : 1, C = l ? 64 : 32;
    int lane = local & 63;
    int blk = (local >> 6) & 3;
    int rest = local >> 8;
    int st = rest % T, s = rest / T;
    int q = lane >> 4, n = blk * 16 + (lane & 15);
    const float* W = WB.p[l];
    union { ushortT u[8]; uint4 v; } ph, pl;
#pragma unroll
    for (int j = 0; j < 8; j++) {
        int k = st * 32 + q * 8 + j;
        float wv = W[((size_t)s * C + k) * 64 + n];
        ushortT hh = f2bf(wv);
        ph.u[j] = hh;
        pl.u[j] = f2bf(wv - bf2f(hh));
    }
    hi4[idx] = ph.v;
    lo4[idx] = pl.v;
}

// ---- Fused Conv A: block = 16 nodes, lane-parallel edges -> LDS S, then S@Wa --------
template<int C1>
__device__ __forceinline__ void conv_a_gemm(const float* __restrict__ S, const float* __restrict__ Wa,
                                            const float* __restrict__ x, const float* __restrict__ ra,
                                            const float* __restrict__ ba, const int* __restrict__ dcl,
                                            int node0, int nn, float* __restrict__ f1l, int t) {
    int ch = t % C1;
    int npp = 256 / C1;
    float bias = ba[ch];
    float root = ra[ch];
    for (int node = t / C1; node < nn; node += npp) {
        const float* Sr = S + node * 126;
        float s = 0.f;
#pragma unroll 5
        for (int k = 0; k < 125; k++) s = fmaf(Sr[k], Wa[k * C1 + ch], s);
        int gnode = node0 + node;
        int dv = dcl[gnode];
        float d = (float)(dv > 1 ? dv : 1);
        float o = s / d + x[gnode] * root + bias;
        f1l[(size_t)gnode * C1 + ch] = fmaxf(o, 0.f);
    }
}

__launch_bounds__(256)
__global__ void conv_a_fused(P5f X, P5f WA, P5f RootA, P5f BiasA,
                             const int* __restrict__ dss, const int* __restrict__ dcell,
                             const float* __restrict__ dfx, const float* __restrict__ dfy,
                             const float* __restrict__ dfz,
                             const int* __restrict__ dbase, const int* __restrict__ boff,
                             const int* __restrict__ dcnt, float* __restrict__ f1) {
    __shared__ float S[16 * 126];
    int b = blockIdx.x;
    int l = (b >= cABLK[4]) ? 4 : (b >= cABLK[3]) ? 3 : (b >= cABLK[2]) ? 2 : (b >= cABLK[1]) ? 1 : 0;
    int node0 = (b - cABLK[l]) * 16;
    int n = cN[l];
    int nn = n - node0; if (nn > 16) nn = 16;
    int t = threadIdx.x;
    for (int i = t; i < 16 * 126; i += 256) S[i] = 0.f;
    __syncthreads();
    const int* db = dbase + cNOFF[l];
    const int* bo = boff + cNBLKOFF[l];
    int estart = db[node0] + bo[node0 >> 8];
    int vend = node0 + nn;
    int eend = (vend >= n) ? cE[l] : (db[vend] + bo[vend >> 8]);
    const float* x = X.p[l];
    int eoff = cEOFF[l];
    for (int p = estart + t; p < eend; p += 256) {
        int sd = dss[eoff + p];
        int src = sd & 0xFFFF, dst = sd >> 16;
        int nl = dst - node0;
        int cell = dcell[eoff + p];
        float fx = dfx[eoff + p], fy = dfy[eoff + p], fz = dfz[eoff + p];
        float xs = x[src];
        float gx = 1.f - fx, gy = 1.f - fy, gz = 1.f - fz;
        int cx = cell >> 4, cy = (cell >> 2) & 3, cz = cell & 3;
        float* Sr = &S[nl * 126];
#pragma unroll
        for (int cor = 0; cor < 8; cor++) {
            int slot = (cx + (cor & 1)) * 25 + (cy + ((cor >> 1) & 1)) * 5 + (cz + ((cor >> 2) & 1));
            float wc = ((cor & 1) ? fx : gx) * (((cor >> 1) & 1) ? fy : gy) * (((cor >> 2) & 1) ? fz : gz);
            atomicAdd(&Sr[slot], wc * xs);
        }
    }
    __syncthreads();
    if (l == 0)
        conv_a_gemm<32>(S, WA.p[0], X.p[0], RootA.p[0], BiasA.p[0], dcnt + cNOFF[0],
                        node0, nn, f1 + cF1OFF[0], t);
    else
        conv_a_gemm<64>(S, WA.p[l], X.p[l], RootA.p[l], BiasA.p[l], dcnt + cNOFF[l],
                        node0, nn, f1 + cF1OFF[l], t);
}

// ---------------- Conv B tile core (MFMA, stores fp16 P rows in dst order) ------------
template<int CIN>
__device__ __forceinline__ void conv_b_tile(
    const float* __restrict__ f1l, const int* __restrict__ ssd_l,
    const float* __restrict__ sfx_l, const float* __restrict__ sfy_l,
    const float* __restrict__ sfz_l, const int* __restrict__ c2d_l,
    const uint4* __restrict__ whiL, const uint4* __restrict__ wloL,
    int cell, int tb, int valid, __half* __restrict__ pout,
    ushortT* Ahi, ushortT* Alo, float* fxs, float* fys, float* fzs, int* d2s) {
    const int T = CIN / 32;
    const int SA = CIN + 8;
    int t = threadIdx.x;
    if (t < 64) {
        bool v = t < valid;
        fxs[t] = v ? sfx_l[tb + t] : 0.f;
        fys[t] = v ? sfy_l[tb + t] : 0.f;
        fzs[t] = v ? sfz_l[tb + t] : 0.f;
        d2s[t] = v ? c2d_l[tb + t] : 0;
    }
    {
        const int FPT = CIN / 16;
        int edge = t >> 2, seg = t & 3;
        ushortT* ah = &Ahi[edge * SA + seg * (CIN / 4)];
        ushortT* al = &Alo[edge * SA + seg * (CIN / 4)];
        if (edge < valid) {
            int src = ssd_l[tb + edge] & 0xFFFF;
            const float4* fp = (const float4*)(f1l + (size_t)src * CIN);
#pragma unroll
            for (int u = 0; u < FPT; u++) {
                float4 vv = fp[seg * FPT + u];
                float vals[4] = {vv.x, vv.y, vv.z, vv.w};
                ushort4 hh, ll;
                ushortT* hp = (ushortT*)&hh; ushortT* lp = (ushortT*)&ll;
#pragma unroll
                for (int c2 = 0; c2 < 4; c2++) {
                    ushortT h = f2bf(vals[c2]);
                    hp[c2] = h;
                    lp[c2] = f2bf(vals[c2] - bf2f(h));
                }
                *(ushort4*)(ah + u * 4) = hh;
                *(ushort4*)(al + u * 4) = ll;
            }
        } else {
            ushort4 z; ushortT* zp = (ushortT*)&z;
            zp[0] = zp[1] = zp[2] = zp[3] = 0;
#pragma unroll
            for (int u = 0; u < FPT; u++) {
                *(ushort4*)(ah + u * 4) = z;
                *(ushort4*)(al + u * 4) = z;
            }
        }
    }
    __syncthreads();

    int lane = t & 63, w = t >> 6;
    int q = lane >> 4, m = lane & 15;

    bf16x8 ahr[4][T], alr[4][T];
#pragma unroll
    for (int mt = 0; mt < 4; mt++)
#pragma unroll
        for (int st = 0; st < T; st++) {
            ahr[mt][st] = *(const bf16x8*)&Ahi[(16 * mt + m) * SA + st * 32 + q * 8];
            alr[mt][st] = *(const bf16x8*)&Alo[(16 * mt + m) * SA + st * 32 + q * 8];
        }
    float fxr[16], fyr[16], fzr[16];
#pragma unroll
    for (int mt = 0; mt < 4; mt++)
#pragma unroll
        for (int rr = 0; rr < 4; rr++) {
            int row = 16 * mt + q * 4 + rr;
            fxr[mt * 4 + rr] = fxs[row];
            fyr[mt * 4 + rr] = fys[row];
            fzr[mt * 4 + rr] = fzs[row];
        }
    int cx = cell >> 4, cy = (cell >> 2) & 3, cz = cell & 3;
    f32x4 acc[4];
#pragma unroll
    for (int mt = 0; mt < 4; mt++) acc[mt] = (f32x4){0.f, 0.f, 0.f, 0.f};

#pragma unroll
    for (int cor = 0; cor < 8; cor++) {
        const int bx = cor & 1, by = (cor >> 1) & 1, bz = (cor >> 2) & 1;
        int slot = (cx + bx) * 25 + (cy + by) * 5 + (cz + bz);
        f32x4 C[4];
#pragma unroll
        for (int mt = 0; mt < 4; mt++) C[mt] = (f32x4){0.f, 0.f, 0.f, 0.f};
#pragma unroll
        for (int st = 0; st < T; st++) {
            size_t fb = ((size_t)(slot * T + st) * 4 + w) * 64 + lane;
            bf16x8 bh = __builtin_bit_cast(bf16x8, whiL[fb]);
            bf16x8 bl = __builtin_bit_cast(bf16x8, wloL[fb]);
#pragma unroll
            for (int mt = 0; mt < 4; mt++) {
                C[mt] = __builtin_amdgcn_mfma_f32_16x16x32_bf16(ahr[mt][st], bh, C[mt], 0, 0, 0);
                C[mt] = __builtin_amdgcn_mfma_f32_16x16x32_bf16(alr[mt][st], bh, C[mt], 0, 0, 0);
                C[mt] = __builtin_amdgcn_mfma_f32_16x16x32_bf16(ahr[mt][st], bl, C[mt], 0, 0, 0);
            }
        }
#pragma unroll
        for (int mt = 0; mt < 4; mt++)
#pragma unroll
            for (int rr = 0; rr < 4; rr++) {
                int i16 = mt * 4 + rr;
                float wr = (bx ? fxr[i16] : 1.f - fxr[i16]) * (by ? fyr[i16] : 1.f - fyr[i16])
                         * (bz ? fzr[i16] : 1.f - fzr[i16]);
                acc[mt][rr] = fmaf(wr, C[mt][rr], acc[mt][rr]);
            }
    }
#pragma unroll
    for (int mt = 0; mt < 4; mt++)
#pragma unroll
        for (int rr = 0; rr < 4; rr++) {
            int row = 16 * mt + q * 4 + rr;
            if (row < valid)
                pout[(size_t)d2s[row] * 64 + 16 * w + m] = __float2half(acc[mt][rr]);
        }
}

__launch_bounds__(256)
__global__ void conv_b32(const float* __restrict__ f1, const int* __restrict__ ssd,
                         const float* __restrict__ sfx, const float* __restrict__ sfy,
                         const float* __restrict__ sfz, const int* __restrict__ c2d,
                         const uint4* __restrict__ whi, const uint4* __restrict__ wlo,
                         const int* __restrict__ cot, const int* __restrict__ csPad,
                         const int* __restrict__ cellTot, __half* __restrict__ Ph) {
    __shared__ alignas(16) ushortT Ahi[64 * 40];
    __shared__ alignas(16) ushortT Alo[64 * 40];
    __shared__ float fxs[64], fys[64], fzs[64];
    __shared__ int d2s[64];
    int tile = blockIdx.x;
    int cell = cot[tile];
    if (cell < 0) return;
    int tb = tile * 64;
    int valid = csPad[cell] + cellTot[cell] - tb;
    if (valid > 64) valid = 64;
    conv_b_tile<32>(f1, ssd, sfx, sfy, sfz, c2d, whi, wlo, cell, tb, valid, Ph,
                    Ahi, Alo, fxs, fys, fzs, d2s);
}

__launch_bounds__(256)
__global__ void conv_b64(const float* __restrict__ f1, const int* __restrict__ ssd,
                         const float* __restrict__ sfx, const float* __restrict__ sfy,
                         const float* __restrict__ sfz, const int* __restrict__ c2d,
                         const uint4* __restrict__ whi, const uint4* __restrict__ wlo,
                         const int* __restrict__ cot, const int* __restrict__ csPad,
                         const int* __restrict__ cellTot, __half* __restrict__ Ph) {
    __shared__ alignas(16) ushortT Ahi[64 * 72];
    __shared__ alignas(16) ushortT Alo[64 * 72];
    __shared__ float fxs[64], fys[64], fzs[64];
    __shared__ int d2s[64];
    const int TB2[4] = {0, 2564, 3878, 4567};
    const int PB2[4] = {0, 160000, 240000, 280000};
    int blk = blockIdx.x;
    int li = (blk >= 4567) ? 3 : (blk >= 3878) ? 2 : (blk >= 2564) ? 1 : 0;
    int l = li + 1;
    int tile = blk - TB2[li];
    int cell = cot[cTILEOFF[l] + tile];
    if (cell < 0) return;
    int tb = tile * 64;
    int valid = csPad[l * 64 + cell] + cellTot[l * 64 + cell] - tb;
    if (valid > 64) valid = 64;
    conv_b_tile<64>(f1 + cF1OFF[l], ssd + cSEOFF[l], sfx + cSEOFF[l], sfy + cSEOFF[l],
                    sfz + cSEOFF[l], c2d + cSEOFF[l], whi + cWOFF[l], wlo + cWOFF[l],
                    cell, tb, valid, Ph + (size_t)PB2[li] * 64,
                    Ahi, Alo, fxs, fys, fzs, d2s);
}

// ---------------- node gather: sum contiguous P rows + root + bias + relu -> f2 -------
template<int CIN>
__device__ __forceinline__ void node_b_node(const __half* __restrict__ Ph, int start, int deg,
                                            const float* __restrict__ f1l, int nodeLocal,
                                            const float* __restrict__ rootb, const float* __restrict__ biasb,
                                            float* __restrict__ f2row, int lane) {
    const __half* pr = Ph + (size_t)start * 64 + lane;
    float s0 = 0.f, s1 = 0.f;
    int j = 0;
    for (; j + 2 <= deg; j += 2) {
        s0 += __half2float(pr[(size_t)j * 64]);
        s1 += __half2float(pr[(size_t)(j + 1) * 64]);
    }
    if (j < deg) s0 += __half2float(pr[(size_t)j * 64]);
    float s = s0 + s1;
    int dv = deg > 1 ? deg : 1;
    s /= (float)dv;
    float fr = (lane < CIN) ? f1l[(size_t)nodeLocal * CIN + lane] : 0.f;
#pragma unroll 8
    for (int i = 0; i < CIN; i++) s = fmaf(__shfl(fr, i, 64), rootb[i * 64 + lane], s);
    s += biasb[lane];
    f2row[lane] = fmaxf(s, 0.f);
}

__launch_bounds__(256)
__global__ void node_b32(const __half* __restrict__ Ph, const int* __restrict__ dbase,
                         const int* __restrict__ boff, const int* __restrict__ dcnt,
                         const float* __restrict__ f1, const float* __restrict__ rootb,
                         const float* __restrict__ biasb, float* __restrict__ f2) {
    int lane = threadIdx.x & 63;
    int node = blockIdx.x * 4 + (threadIdx.x >> 6);
    if (node >= 20000) return;
    int start = dbase[node] + boff[node >> 8];
    int deg = dcnt[node];
    node_b_node<32>(Ph, start, deg, f1, node, rootb, biasb, f2 + (size_t)node * 64, lane);
}

__launch_bounds__(256)
__global__ void node_b64(const __half* __restrict__ Ph, const int* __restrict__ dbase,
                         const int* __restrict__ boff, const int* __restrict__ dcnt,
                         const float* __restrict__ f1, P5f RootB, P5f BiasB,
                         float* __restrict__ f2) {
    const int NB2[4] = {0, 2500, 3750, 4375};
    const int PB2[4] = {0, 160000, 240000, 280000};
    int lane = threadIdx.x & 63;
    int blk = blockIdx.x;
    int li = (blk >= 4375) ? 3 : (blk >= 3750) ? 2 : (blk >= 2500) ? 1 : 0;
    int l = li + 1;
    int node = (blk - NB2[li]) * 4 + (threadIdx.x >> 6);
    if (node >= cN[l]) return;
    int start = dbase[cNOFF[l] + node] + boff[cNBLKOFF[l] + (node >> 8)];
    int deg = dcnt[cNOFF[l] + node];
    node_b_node<64>(Ph + (size_t)PB2[li] * 64, start, deg, f1 + cF1OFF[l], node,
                    RootB.p[l], BiasB.p[l], f2 + (size_t)(cNOFF[l] + node) * 64, lane);
}

// ---------------- readout: run-accumulated graph mean sums ----------------
__launch_bounds__(256)
__global__ void k_read(const float* __restrict__ f2, P5i Batch,
                       float* __restrict__ hsum, float* __restrict__ gcnt) {
    const int RC[5] = {0, 1250, 1875, 2188, 2345};
    int t = threadIdx.x;
    int lane = t & 63;
    int w = blockIdx.x * 4 + (t >> 6);
    if (w >= 2424) return;
    int l = (w >= 2345) ? 4 : (w >= 2188) ? 3 : (w >= 1875) ? 2 : (w >= 1250) ? 1 : 0;
    int base = (w - RC[l]) * 16;
    int Nl = cN[l];
    int nn = Nl - base; if (nn > 16) nn = 16;
    const int* batch = Batch.p[l];
    const float* fb = f2 + (size_t)(cNOFF[l] + base) * 64;
    int curg = -1; float hacc = 0.f; int crun = 0;
    for (int j = 0; j < nn; j++) {
        int g = batch[base + j];
        if (g != curg) {
            if (curg >= 0) {
                atomicAdd(&hsum[curg * 320 + l * 64 + lane], hacc);
                if (lane == 0) atomicAdd(&gcnt[l * 64 + curg], (float)crun);
            }
            curg = g; hacc = 0.f; crun = 0;
        }
        hacc += fb[(size_t)j * 64 + lane];
        crun++;
    }
    if (curg >= 0) {
        atomicAdd(&hsum[curg * 320 + l * 64 + lane], hacc);
        if (lane == 0) atomicAdd(&gcnt[l * 64 + curg], (float)crun);
    }
}

// ---------------- FC + log_softmax ----------------
__global__ void fc_kernel(const float* __restrict__ hsum, const float* __restrict__ gcnt,
                          const float* __restrict__ fcw, const float* __restrict__ fcb,
                          float* __restrict__ out) {
    int g = threadIdx.x;
    if (g >= NUM_GRAPHS) return;
    float logit[10];
#pragma unroll
    for (int t = 0; t < 10; t++) logit[t] = fcb[t];
    for (int j = 0; j < 320; j++) {
        float c = fmaxf(gcnt[(j >> 6) * NUM_GRAPHS + g], 1.f);
        float h = hsum[g * 320 + j] / c;
#pragma unroll
        for (int t = 0; t < 10; t++) logit[t] = fmaf(h, fcw[j * 10 + t], logit[t]);
    }
    float m = logit[0];
#pragma unroll
    for (int t = 1; t < 10; t++) m = fmaxf(m, logit[t]);
    float sum = 0.f;
#pragma unroll
    for (int t = 0; t < 10; t++) sum += expf(logit[t] - m);
    float lse = m + logf(sum);
#pragma unroll
    for (int t = 0; t < 10; t++) out[g * 10 + t] = logit[t] - lse;
}

extern "C" void kernel_launch(void* const* d_in, const int* in_sizes, int n_in,
                              void* d_out, int out_size, void* d_ws, size_t ws_size,
                              hipStream_t stream) {
    int* wsI = (int*)d_ws;
    int*   dcnt  = wsI;                          // 38750
    int*   rank  = dcnt + 38750;                 // 38750
    float* hsum  = (float*)(rank + 38750);       // 20480
    float* gcnt  = hsum + 20480;                 // 320
    float* f1    = gcnt + 320;                   // 1,840,000
    float* f2    = f1 + 1840000;                 // 2,480,000
    int*   dbase = (int*)(f2 + 2480000);         // 38750
    int*   bsum  = dbase + 38750;                // 160
    int*   boff  = bsum + 160;                   // 160
    int*   eposc = boff + 160;                   // 620000
    int*   c2d   = eposc + 620000;               // 640512
    int*   ssd   = c2d + 640512;                 // 640512
    float* sfx   = (float*)(ssd + 640512);
    float* sfy   = sfx + 640512;
    float* sfz   = sfy + 640512;
    int*   dss   = (int*)(sfz + 640512);         // 620000
    int*   dcell = dss + 620000;                 // 620000
    float* dfx   = (float*)(dcell + 620000);     // 620000
    float* dfy   = dfx + 620000;                 // 620000
    float* dfz   = dfy + 620000;                 // 620000
    int*   bb    = (int*)(dfz + 620000);         // 155136
    int*   csPad = bb + 155136;                  // 320
    int*   cellTot = csPad + 320;                // 320
    int*   cot   = cellTot + 320;                // 10008
    uint4* whi   = (uint4*)(((size_t)(cot + 10008) + 15) & ~(size_t)15);  // 288000
    uint4* wlo   = whi + 288000;                 // 288000
    __half* Ph   = (__half*)(wlo + 288000);      // 324096*64 halves (~41.5MB)

    // zero dcnt + rank + hsum + gcnt (contiguous); f1 no longer needs zeroing
    hipMemsetAsync(dcnt, 0, (size_t)(38750 * 2 + 20480 + 320) * sizeof(int), stream);

    P5f PS, X, WA, RootA, BiasA, WB, RootB, BiasB;
    P5i EI, Batch;
    for (int l = 0; l < 5; l++) {
        const int b = l * 10;
        X.p[l]     = (const float*)d_in[b + 0];
        PS.p[l]    = (const float*)d_in[b + 1];
        EI.p[l]    = (const int*)d_in[b + 2];
        Batch.p[l] = (const int*)d_in[b + 3];
        WA.p[l]    = (const float*)d_in[b + 4];
        RootA.p[l] = (const float*)d_in[b + 5];
        BiasA.p[l] = (const float*)d_in[b + 6];
        WB.p[l]    = (const float*)d_in[b + 7];
        RootB.p[l] = (const float*)d_in[b + 8];
        BiasB.p[l] = (const float*)d_in[b + 9];
    }

    // prep (all levels fused)
    k_hist<<<2424, 256, 0, stream>>>(PS, EI, dcnt, bb);
    k_cellscan<<<5, 64, 0, stream>>>(bb, csPad, cellTot, cot);
    k_cellscatter<<<2424, 256, 0, stream>>>(PS, EI, bb, csPad, ssd, sfx, sfy, sfz, eposc);
    k_nscan1<<<154, 256, 0, stream>>>(dcnt, dbase, bsum);
    k_nscan2<<<5, 64, 0, stream>>>(bsum, boff);
    k_dscatter<<<2424, 256, 0, stream>>>(PS, EI, dbase, boff, rank, eposc, c2d,
                                         dss, dcell, dfx, dfy, dfz);
    k_wswz<<<1125, 256, 0, stream>>>(WB, whi, wlo);

    // fused conv A (scatter to LDS S + S@Wa + epilogue), all levels
    conv_a_fused<<<2424, 256, 0, stream>>>(X, WA, RootA, BiasA, dss, dcell, dfx, dfy, dfz,
                                           dbase, boff, dcnt, f1);

    // conv B + node gather (P buffer reused between l1 and l2-5)
    conv_b32<<<5064, 256, 0, stream>>>(f1, ssd, sfx, sfy, sfz, c2d, whi, wlo,
                                       cot, csPad, cellTot, Ph);
    node_b32<<<5000, 256, 0, stream>>>(Ph, dbase, boff, dcnt, f1, RootB.p[0], BiasB.p[0], f2);
    conv_b64<<<4944, 256, 0, stream>>>(f1, ssd, sfx, sfy, sfz, c2d, whi, wlo, cot, csPad, cellTot, Ph);
    node_b64<<<4688, 256, 0, stream>>>(Ph, dbase, boff, dcnt, f1, RootB, BiasB, f2);

    // readout + FC
    k_read<<<606, 256, 0, stream>>>(f2, Batch, hsum, gcnt);
    fc_kernel<<<1, 64, 0, stream>>>(hsum, gcnt, (const float*)d_in[50], (const float*)d_in[51],
                                    (float*)d_out);
}

// Round 7
// 565.145 us; speedup vs baseline: 1.8538x; 1.1064x over previous
//
#include <hip/hip_runtime.h>
#include <hip/hip_fp16.h>
#include <math.h>

#define NUM_GRAPHS 64

typedef unsigned short ushortT;
typedef __attribute__((ext_vector_type(8))) short bf16x8;
typedef __attribute__((ext_vector_type(4))) float f32x4;

// ---- static level tables ----
constexpr int cN[5]       = {20000, 10000, 5000, 2500, 1250};
constexpr int cE[5]       = {320000, 160000, 80000, 40000, 20000};
constexpr int cNOFF[6]    = {0, 20000, 30000, 35000, 37500, 38750};
constexpr int cEOFF[6]    = {0, 320000, 480000, 560000, 600000, 620000};
constexpr int cEBLKOFF[6] = {0, 1250, 1875, 2188, 2345, 2424};
constexpr int cNBLKOFF[6] = {0, 79, 119, 139, 149, 154};
constexpr int cMT[5]      = {5064, 2564, 1314, 689, 377};
constexpr int cTILEOFF[6] = {0, 5064, 7628, 8942, 9631, 10008};
constexpr int cSEOFF[6]   = {0, 324096, 488192, 572288, 616384, 640512};
constexpr int cF1OFF[6]   = {0, 640000, 1280000, 1600000, 1760000, 1840000};
constexpr int cWOFF[6]    = {0, 32000, 96000, 160000, 224000, 288000};
constexpr int cABLK[6]    = {0, 1250, 1875, 2188, 2345, 2424};  // ceil(N/16) prefix

struct P5f { const float* p[5]; };
struct P5i { const int* p[5]; };

__device__ __forceinline__ int lvl_e(int b) {
    return (b >= cEBLKOFF[4]) ? 4 : (b >= cEBLKOFF[3]) ? 3 : (b >= cEBLKOFF[2]) ? 2 : (b >= cEBLKOFF[1]) ? 1 : 0;
}
__device__ __forceinline__ int lvl_n(int b) {
    return (b >= cNBLKOFF[4]) ? 4 : (b >= cNBLKOFF[3]) ? 3 : (b >= cNBLKOFF[2]) ? 2 : (b >= cNBLKOFF[1]) ? 1 : 0;
}

__device__ __forceinline__ ushortT f2bf(float f) {
    union { float f; unsigned int u; } v; v.f = f;
    unsigned int r = (v.u + 0x7FFFu + ((v.u >> 16) & 1u)) >> 16;
    return (ushortT)r;
}

// ---------------- prep: per-block cell histogram + dst degree count ----------------
__global__ void k_hist(P5f PS, P5i EI, int* __restrict__ dcnt, int* __restrict__ bb) {
    int b = blockIdx.x;
    int l = lvl_e(b);
    int lb = b - cEBLKOFF[l];
    int E = cE[l];
    __shared__ int h[64];
    int t = threadIdx.x;
    if (t < 64) h[t] = 0;
    __syncthreads();
    int e = lb * 256 + t;
    if (e < E) {
        atomicAdd(&dcnt[cNOFF[l] + EI.p[l][E + e]], 1);
        const float* ps = PS.p[l];
        int c = (int)floorf(ps[e * 3] * 4.f) * 16 + (int)floorf(ps[e * 3 + 1] * 4.f) * 4
              + (int)floorf(ps[e * 3 + 2] * 4.f);
        atomicAdd(&h[c], 1);
    }
    __syncthreads();
    if (t < 64) bb[(size_t)b * 64 + t] = h[t];
}

// ---------------- cell scan ----------------
__global__ void k_cellscan(int* __restrict__ bb_all, int* __restrict__ csPad,
                           int* __restrict__ cellTot, int* __restrict__ cot_all) {
    int l = blockIdx.x;
    int c = threadIdx.x;
    int* bb = bb_all + (size_t)cEBLKOFF[l] * 64;
    int nblk = cEBLKOFF[l + 1] - cEBLKOFF[l];
    int run = 0;
    int b = 0;
    for (; b + 16 <= nblk; b += 16) {
        int v[16];
#pragma unroll
        for (int u = 0; u < 16; u++) v[u] = bb[(b + u) * 64 + c];
#pragma unroll
        for (int u = 0; u < 16; u++) { bb[(b + u) * 64 + c] = run; run += v[u]; }
    }
    for (; b < nblk; b++) { int v = bb[b * 64 + c]; bb[b * 64 + c] = run; run += v; }
    int tot = run;
    cellTot[l * 64 + c] = tot;
    int tiles = (tot + 63) >> 6;
    int x = tiles;
#pragma unroll
    for (int off = 1; off < 64; off <<= 1) { int y = __shfl_up(x, off, 64); if (c >= off) x += y; }
    int tileBase = x - tiles;
    csPad[l * 64 + c] = tileBase * 64;
    int* cot = cot_all + cTILEOFF[l];
    for (int i = 0; i < tiles; i++) cot[tileBase + i] = c;
    int nT = __shfl(x, 63, 64);
    int mt = cMT[l];
    for (int i = nT + c; i < mt; i += 64) cot[i] = -1;
}

// ---------------- cell scatter ----------------
__global__ void k_cellscatter(P5f PS, P5i EI, const int* __restrict__ bb, const int* __restrict__ csPad,
                              int* __restrict__ ssd, float* __restrict__ sfx, float* __restrict__ sfy,
                              float* __restrict__ sfz, int* __restrict__ eposc) {
    int b = blockIdx.x;
    int l = lvl_e(b);
    int lb = b - cEBLKOFF[l];
    int E = cE[l];
    __shared__ int base[64];
    __shared__ int cnt[64];
    int t = threadIdx.x;
    if (t < 64) { base[t] = bb[(size_t)b * 64 + t] + csPad[l * 64 + t]; cnt[t] = 0; }
    __syncthreads();
    int e = lb * 256 + t;
    if (e < E) {
        const float* ps = PS.p[l];
        float v0 = ps[e * 3] * 4.f, v1 = ps[e * 3 + 1] * 4.f, v2 = ps[e * 3 + 2] * 4.f;
        float f0 = floorf(v0), f1v = floorf(v1), f2v = floorf(v2);
        int c = (int)f0 * 16 + (int)f1v * 4 + (int)f2v;
        int r = atomicAdd(&cnt[c], 1);
        int pos = base[c] + r;
        const int* ei = EI.p[l];
        ssd[cSEOFF[l] + pos] = ei[e] | (ei[E + e] << 16);
        sfx[cSEOFF[l] + pos] = v0 - f0;
        sfy[cSEOFF[l] + pos] = v1 - f1v;
        sfz[cSEOFF[l] + pos] = v2 - f2v;
        eposc[cEOFF[l] + e] = pos;
    }
}

// ---------------- node-degree scans ----------------
__global__ void k_nscan1(const int* __restrict__ dcnt, int* __restrict__ dbase, int* __restrict__ bsum) {
    int b = blockIdx.x;
    int l = lvl_n(b);
    int lb = b - cNBLKOFF[l];
    int n = cN[l];
    __shared__ int sh[256];
    int t = threadIdx.x;
    int i = lb * 256 + t;
    int v = (i < n) ? dcnt[cNOFF[l] + i] : 0;
    sh[t] = v;
    __syncthreads();
    for (int off = 1; off < 256; off <<= 1) {
        int y = (t >= off) ? sh[t - off] : 0;
        __syncthreads();
        sh[t] += y;
        __syncthreads();
    }
    if (i < n) dbase[cNOFF[l] + i] = sh[t] - v;
    if (t == 255) bsum[b] = sh[255];
}

__global__ void k_nscan2(const int* __restrict__ bsum, int* __restrict__ boff) {
    int l = blockIdx.x;
    int o = cNBLKOFF[l];
    int nb = cNBLKOFF[l + 1] - o;
    int t = threadIdx.x;
    int v = (t < nb) ? bsum[o + t] : 0;
    int s = v;
#pragma unroll
    for (int off = 1; off < 64; off <<= 1) { int y = __shfl_up(s, off, 64); if (t >= off) s += y; }
    int tot = __shfl(s, 63, 64);
    if (t < nb) boff[o + t] = s - v;
    int t2 = t + 64;
    int v2 = (t2 < nb) ? bsum[o + t2] : 0;
    int s2 = v2;
#pragma unroll
    for (int off = 1; off < 64; off <<= 1) { int y = __shfl_up(s2, off, 64); if (t >= off) s2 += y; }
    if (t2 < nb) boff[o + t2] = tot + s2 - v2;
}

// ---- dst scatter: build c2d (cell-pos -> dst-pos) + dst-ordered edge records --------
__global__ void k_dscatter(P5f PS, P5i EI, const int* __restrict__ dbase, const int* __restrict__ boff,
                           int* __restrict__ rank, const int* __restrict__ eposc,
                           int* __restrict__ c2d, int* __restrict__ dss, int* __restrict__ dcell,
                           float* __restrict__ dfx, float* __restrict__ dfy, float* __restrict__ dfz) {
    int b = blockIdx.x;
    int l = lvl_e(b);
    int lb = b - cEBLKOFF[l];
    int E = cE[l];
    int e = lb * 256 + threadIdx.x;
    if (e >= E) return;
    const int* ei = EI.p[l];
    int src = ei[e];
    int dst = ei[E + e];
    int p = dbase[cNOFF[l] + dst] + boff[cNBLKOFF[l] + (dst >> 8)]
          + atomicAdd(&rank[cNOFF[l] + dst], 1);
    int posc = eposc[cEOFF[l] + e];
    c2d[cSEOFF[l] + posc] = p;
    const float* ps = PS.p[l];
    float v0 = ps[e * 3] * 4.f, v1 = ps[e * 3 + 1] * 4.f, v2 = ps[e * 3 + 2] * 4.f;
    float f0 = floorf(v0), f1v = floorf(v1), f2v = floorf(v2);
    int cell = (int)f0 * 16 + (int)f1v * 4 + (int)f2v;
    int po = cEOFF[l] + p;
    dss[po] = src | (dst << 16);
    dcell[po] = cell;
    dfx[po] = v0 - f0;
    dfy[po] = v1 - f1v;
    dfz[po] = v2 - f2v;
}

// -------- W swizzle (all levels): Wb[125][CIN][64] fp32 -> MFMA B-frag bf16 ----------
__global__ void k_wswz(P5f WB, uint4* __restrict__ hi4) {
    int idx = blockIdx.x * 256 + threadIdx.x;
    if (idx >= 288000) return;
    int l = (idx >= 224000) ? 4 : (idx >= 160000) ? 3 : (idx >= 96000) ? 2 : (idx >= 32000) ? 1 : 0;
    int local = idx - cWOFF[l];
    int T = l ? 2 : 1, C = l ? 64 : 32;
    int lane = local & 63;
    int blk = (local >> 6) & 3;
    int rest = local >> 8;
    int st = rest % T, s = rest / T;
    int q = lane >> 4, n = blk * 16 + (lane & 15);
    const float* W = WB.p[l];
    union { ushortT u[8]; uint4 v; } ph;
#pragma unroll
    for (int j = 0; j < 8; j++) {
        int k = st * 32 + q * 8 + j;
        ph.u[j] = f2bf(W[((size_t)s * C + k) * 64 + n]);
    }
    hi4[idx] = ph.v;
}

// ---- Fused Conv A: block = 16 nodes, lane-parallel edges -> LDS S, then S@Wa --------
template<int C1>
__device__ __forceinline__ void conv_a_gemm(const float* __restrict__ S, const float* __restrict__ Wa,
                                            const float* __restrict__ x, const float* __restrict__ ra,
                                            const float* __restrict__ ba, const int* __restrict__ dcl,
                                            int node0, int nn, float* __restrict__ f1l,
                                            ushortT* __restrict__ f1bfl, int t) {
    int ch = t % C1;
    int npp = 256 / C1;
    float bias = ba[ch];
    float root = ra[ch];
    for (int node = t / C1; node < nn; node += npp) {
        const float* Sr = S + node * 126;
        float s = 0.f;
#pragma unroll 5
        for (int k = 0; k < 125; k++) s = fmaf(Sr[k], Wa[k * C1 + ch], s);
        int gnode = node0 + node;
        int dv = dcl[gnode];
        float d = (float)(dv > 1 ? dv : 1);
        float o = s / d + x[gnode] * root + bias;
        o = fmaxf(o, 0.f);
        f1l[(size_t)gnode * C1 + ch] = o;
        f1bfl[(size_t)gnode * C1 + ch] = f2bf(o);
    }
}

__launch_bounds__(256)
__global__ void conv_a_fused(P5f X, P5f WA, P5f RootA, P5f BiasA,
                             const int* __restrict__ dss, const int* __restrict__ dcell,
                             const float* __restrict__ dfx, const float* __restrict__ dfy,
                             const float* __restrict__ dfz,
                             const int* __restrict__ dbase, const int* __restrict__ boff,
                             const int* __restrict__ dcnt, float* __restrict__ f1,
                             ushortT* __restrict__ f1bf) {
    __shared__ float S[16 * 126];
    int b = blockIdx.x;
    int l = (b >= cABLK[4]) ? 4 : (b >= cABLK[3]) ? 3 : (b >= cABLK[2]) ? 2 : (b >= cABLK[1]) ? 1 : 0;
    int node0 = (b - cABLK[l]) * 16;
    int n = cN[l];
    int nn = n - node0; if (nn > 16) nn = 16;
    int t = threadIdx.x;
    for (int i = t; i < 16 * 126; i += 256) S[i] = 0.f;
    __syncthreads();
    const int* db = dbase + cNOFF[l];
    const int* bo = boff + cNBLKOFF[l];
    int estart = db[node0] + bo[node0 >> 8];
    int vend = node0 + nn;
    int eend = (vend >= n) ? cE[l] : (db[vend] + bo[vend >> 8]);
    const float* x = X.p[l];
    int eoff = cEOFF[l];
    for (int p = estart + t; p < eend; p += 256) {
        int sd = dss[eoff + p];
        int src = sd & 0xFFFF, dst = sd >> 16;
        int nl = dst - node0;
        int cell = dcell[eoff + p];
        float fx = dfx[eoff + p], fy = dfy[eoff + p], fz = dfz[eoff + p];
        float xs = x[src];
        float gx = 1.f - fx, gy = 1.f - fy, gz = 1.f - fz;
        int cx = cell >> 4, cy = (cell >> 2) & 3, cz = cell & 3;
        float* Sr = &S[nl * 126];
#pragma unroll
        for (int cor = 0; cor < 8; cor++) {
            int slot = (cx + (cor & 1)) * 25 + (cy + ((cor >> 1) & 1)) * 5 + (cz + ((cor >> 2) & 1));
            float wc = ((cor & 1) ? fx : gx) * (((cor >> 1) & 1) ? fy : gy) * (((cor >> 2) & 1) ? fz : gz);
            atomicAdd(&Sr[slot], wc * xs);
        }
    }
    __syncthreads();
    if (l == 0)
        conv_a_gemm<32>(S, WA.p[0], X.p[0], RootA.p[0], BiasA.p[0], dcnt + cNOFF[0],
                        node0, nn, f1 + cF1OFF[0], f1bf + cF1OFF[0], t);
    else
        conv_a_gemm<64>(S, WA.p[l], X.p[l], RootA.p[l], BiasA.p[l], dcnt + cNOFF[l],
                        node0, nn, f1 + cF1OFF[l], f1bf + cF1OFF[l], t);
}

// ---- Conv B tile core: A-frags direct from global bf16, single-bf16 MFMA ------------
template<int CIN>
__device__ __forceinline__ void conv_b_tile(
    const ushortT* __restrict__ f1bfl, const int* __restrict__ ssd_l,
    const float* __restrict__ sfx_l, const float* __restrict__ sfy_l,
    const float* __restrict__ sfz_l, const int* __restrict__ c2d_l,
    const uint4* __restrict__ whiL,
    int cell, int tb, int valid, __half* __restrict__ pout,
    float* fxs, float* fys, float* fzs, int* d2s, int* srcs) {
    const int T = CIN / 32;
    int t = threadIdx.x;
    if (t < 64) {
        bool v = t < valid;
        int sd = v ? ssd_l[tb + t] : 0;
        srcs[t] = v ? (sd & 0xFFFF) : 0;
        d2s[t] = v ? c2d_l[tb + t] : 0;
        fxs[t] = v ? sfx_l[tb + t] : 0.f;
        fys[t] = v ? sfy_l[tb + t] : 0.f;
        fzs[t] = v ? sfz_l[tb + t] : 0.f;
    }
    __syncthreads();

    int lane = t & 63, w = t >> 6;
    int q = lane >> 4, m = lane & 15;

    // A fragments: 16B vector loads straight from global bf16 f1
    bf16x8 ahr[4][T];
#pragma unroll
    for (int mt = 0; mt < 4; mt++) {
        int src = srcs[16 * mt + m];
#pragma unroll
        for (int st = 0; st < T; st++)
            ahr[mt][st] = *(const bf16x8*)&f1bfl[(size_t)src * CIN + st * 32 + q * 8];
    }
    float fxr[16], fyr[16], fzr[16];
#pragma unroll
    for (int mt = 0; mt < 4; mt++)
#pragma unroll
        for (int rr = 0; rr < 4; rr++) {
            int row = 16 * mt + q * 4 + rr;
            fxr[mt * 4 + rr] = fxs[row];
            fyr[mt * 4 + rr] = fys[row];
            fzr[mt * 4 + rr] = fzs[row];
        }
    int cx = cell >> 4, cy = (cell >> 2) & 3, cz = cell & 3;
    f32x4 acc[4];
#pragma unroll
    for (int mt = 0; mt < 4; mt++) acc[mt] = (f32x4){0.f, 0.f, 0.f, 0.f};

#pragma unroll
    for (int cor = 0; cor < 8; cor++) {
        const int bx = cor & 1, by = (cor >> 1) & 1, bz = (cor >> 2) & 1;
        int slot = (cx + bx) * 25 + (cy + by) * 5 + (cz + bz);
        f32x4 C[4];
#pragma unroll
        for (int mt = 0; mt < 4; mt++) C[mt] = (f32x4){0.f, 0.f, 0.f, 0.f};
#pragma unroll
        for (int st = 0; st < T; st++) {
            bf16x8 bh = __builtin_bit_cast(bf16x8, whiL[((size_t)(slot * T + st) * 4 + w) * 64 + lane]);
#pragma unroll
            for (int mt = 0; mt < 4; mt++)
                C[mt] = __builtin_amdgcn_mfma_f32_16x16x32_bf16(ahr[mt][st], bh, C[mt], 0, 0, 0);
        }
#pragma unroll
        for (int mt = 0; mt < 4; mt++)
#pragma unroll
            for (int rr = 0; rr < 4; rr++) {
                int i16 = mt * 4 + rr;
                float wr = (bx ? fxr[i16] : 1.f - fxr[i16]) * (by ? fyr[i16] : 1.f - fyr[i16])
                         * (bz ? fzr[i16] : 1.f - fzr[i16]);
                acc[mt][rr] = fmaf(wr, C[mt][rr], acc[mt][rr]);
            }
    }
#pragma unroll
    for (int mt = 0; mt < 4; mt++)
#pragma unroll
        for (int rr = 0; rr < 4; rr++) {
            int row = 16 * mt + q * 4 + rr;
            if (row < valid)
                pout[(size_t)d2s[row] * 64 + 16 * w + m] = __float2half(acc[mt][rr]);
        }
}

__launch_bounds__(256)
__global__ void conv_b32(const ushortT* __restrict__ f1bf, const int* __restrict__ ssd,
                         const float* __restrict__ sfx, const float* __restrict__ sfy,
                         const float* __restrict__ sfz, const int* __restrict__ c2d,
                         const uint4* __restrict__ whi,
                         const int* __restrict__ cot, const int* __restrict__ csPad,
                         const int* __restrict__ cellTot, __half* __restrict__ Ph) {
    __shared__ float fxs[64], fys[64], fzs[64];
    __shared__ int d2s[64], srcs[64];
    int tile = blockIdx.x;
    int cell = cot[tile];
    if (cell < 0) return;
    int tb = tile * 64;
    int valid = csPad[cell] + cellTot[cell] - tb;
    if (valid > 64) valid = 64;
    conv_b_tile<32>(f1bf, ssd, sfx, sfy, sfz, c2d, whi, cell, tb, valid, Ph,
                    fxs, fys, fzs, d2s, srcs);
}

__launch_bounds__(256)
__global__ void conv_b64(const ushortT* __restrict__ f1bf, const int* __restrict__ ssd,
                         const float* __restrict__ sfx, const float* __restrict__ sfy,
                         const float* __restrict__ sfz, const int* __restrict__ c2d,
                         const uint4* __restrict__ whi,
                         const int* __restrict__ cot, const int* __restrict__ csPad,
                         const int* __restrict__ cellTot, __half* __restrict__ Ph) {
    __shared__ float fxs[64], fys[64], fzs[64];
    __shared__ int d2s[64], srcs[64];
    const int TB2[4] = {0, 2564, 3878, 4567};
    const int PB2[4] = {0, 160000, 240000, 280000};
    int blk = blockIdx.x;
    int li = (blk >= 4567) ? 3 : (blk >= 3878) ? 2 : (blk >= 2564) ? 1 : 0;
    int l = li + 1;
    int tile = blk - TB2[li];
    int cell = cot[cTILEOFF[l] + tile];
    if (cell < 0) return;
    int tb = tile * 64;
    int valid = csPad[l * 64 + cell] + cellTot[l * 64 + cell] - tb;
    if (valid > 64) valid = 64;
    conv_b_tile<64>(f1bf + cF1OFF[l], ssd + cSEOFF[l], sfx + cSEOFF[l], sfy + cSEOFF[l],
                    sfz + cSEOFF[l], c2d + cSEOFF[l], whi + cWOFF[l],
                    cell, tb, valid, Ph + (size_t)PB2[li] * 64,
                    fxs, fys, fzs, d2s, srcs);
}

// ---------------- node gather: sum contiguous P rows + root + bias + relu -> f2 -------
template<int CIN>
__device__ __forceinline__ void node_b_node(const __half* __restrict__ Ph, int start, int deg,
                                            const float* __restrict__ f1l, int nodeLocal,
                                            const float* __restrict__ rootb, const float* __restrict__ biasb,
                                            float* __restrict__ f2row, int lane) {
    const __half* pr = Ph + (size_t)start * 64 + lane;
    float s0 = 0.f, s1 = 0.f;
    int j = 0;
    for (; j + 2 <= deg; j += 2) {
        s0 += __half2float(pr[(size_t)j * 64]);
        s1 += __half2float(pr[(size_t)(j + 1) * 64]);
    }
    if (j < deg) s0 += __half2float(pr[(size_t)j * 64]);
    float s = s0 + s1;
    int dv = deg > 1 ? deg : 1;
    s /= (float)dv;
    float fr = (lane < CIN) ? f1l[(size_t)nodeLocal * CIN + lane] : 0.f;
#pragma unroll 8
    for (int i = 0; i < CIN; i++) s = fmaf(__shfl(fr, i, 64), rootb[i * 64 + lane], s);
    s += biasb[lane];
    f2row[lane] = fmaxf(s, 0.f);
}

__launch_bounds__(256)
__global__ void node_b32(const __half* __restrict__ Ph, const int* __restrict__ dbase,
                         const int* __restrict__ boff, const int* __restrict__ dcnt,
                         const float* __restrict__ f1, const float* __restrict__ rootb,
                         const float* __restrict__ biasb, float* __restrict__ f2) {
    int lane = threadIdx.x & 63;
    int node = blockIdx.x * 4 + (threadIdx.x >> 6);
    if (node >= 20000) return;
    int start = dbase[node] + boff[node >> 8];
    int deg = dcnt[node];
    node_b_node<32>(Ph, start, deg, f1, node, rootb, biasb, f2 + (size_t)node * 64, lane);
}

__launch_bounds__(256)
__global__ void node_b64(const __half* __restrict__ Ph, const int* __restrict__ dbase,
                         const int* __restrict__ boff, const int* __restrict__ dcnt,
                         const float* __restrict__ f1, P5f RootB, P5f BiasB,
                         float* __restrict__ f2) {
    const int NB2[4] = {0, 2500, 3750, 4375};
    const int PB2[4] = {0, 160000, 240000, 280000};
    int lane = threadIdx.x & 63;
    int blk = blockIdx.x;
    int li = (blk >= 4375) ? 3 : (blk >= 3750) ? 2 : (blk >= 2500) ? 1 : 0;
    int l = li + 1;
    int node = (blk - NB2[li]) * 4 + (threadIdx.x >> 6);
    if (node >= cN[l]) return;
    int start = dbase[cNOFF[l] + node] + boff[cNBLKOFF[l] + (node >> 8)];
    int deg = dcnt[cNOFF[l] + node];
    node_b_node<64>(Ph + (size_t)PB2[li] * 64, start, deg, f1 + cF1OFF[l], node,
                    RootB.p[l], BiasB.p[l], f2 + (size_t)(cNOFF[l] + node) * 64, lane);
}

// ---------------- readout: run-accumulated graph mean sums ----------------
__launch_bounds__(256)
__global__ void k_read(const float* __restrict__ f2, P5i Batch,
                       float* __restrict__ hsum, float* __restrict__ gcnt) {
    const int RC[5] = {0, 1250, 1875, 2188, 2345};
    int t = threadIdx.x;
    int lane = t & 63;
    int w = blockIdx.x * 4 + (t >> 6);
    if (w >= 2424) return;
    int l = (w >= 2345) ? 4 : (w >= 2188) ? 3 : (w >= 1875) ? 2 : (w >= 1250) ? 1 : 0;
    int base = (w - RC[l]) * 16;
    int Nl = cN[l];
    int nn = Nl - base; if (nn > 16) nn = 16;
    const int* batch = Batch.p[l];
    const float* fb = f2 + (size_t)(cNOFF[l] + base) * 64;
    int curg = -1; float hacc = 0.f; int crun = 0;
    for (int j = 0; j < nn; j++) {
        int g = batch[base + j];
        if (g != curg) {
            if (curg >= 0) {
                atomicAdd(&hsum[curg * 320 + l * 64 + lane], hacc);
                if (lane == 0) atomicAdd(&gcnt[l * 64 + curg], (float)crun);
            }
            curg = g; hacc = 0.f; crun = 0;
        }
        hacc += fb[(size_t)j * 64 + lane];
        crun++;
    }
    if (curg >= 0) {
        atomicAdd(&hsum[curg * 320 + l * 64 + lane], hacc);
        if (lane == 0) atomicAdd(&gcnt[l * 64 + curg], (float)crun);
    }
}

// ---------------- FC + log_softmax ----------------
__global__ void fc_kernel(const float* __restrict__ hsum, const float* __restrict__ gcnt,
                          const float* __restrict__ fcw, const float* __restrict__ fcb,
                          float* __restrict__ out) {
    int g = threadIdx.x;
    if (g >= NUM_GRAPHS) return;
    float logit[10];
#pragma unroll
    for (int t = 0; t < 10; t++) logit[t] = fcb[t];
    for (int j = 0; j < 320; j++) {
        float c = fmaxf(gcnt[(j >> 6) * NUM_GRAPHS + g], 1.f);
        float h = hsum[g * 320 + j] / c;
#pragma unroll
        for (int t = 0; t < 10; t++) logit[t] = fmaf(h, fcw[j * 10 + t], logit[t]);
    }
    float m = logit[0];
#pragma unroll
    for (int t = 1; t < 10; t++) m = fmaxf(m, logit[t]);
    float sum = 0.f;
#pragma unroll
    for (int t = 0; t < 10; t++) sum += expf(logit[t] - m);
    float lse = m + logf(sum);
#pragma unroll
    for (int t = 0; t < 10; t++) out[g * 10 + t] = logit[t] - lse;
}

extern "C" void kernel_launch(void* const* d_in, const int* in_sizes, int n_in,
                              void* d_out, int out_size, void* d_ws, size_t ws_size,
                              hipStream_t stream) {
    int* wsI = (int*)d_ws;
    int*   dcnt  = wsI;                          // 38750
    int*   rank  = dcnt + 38750;                 // 38750
    float* hsum  = (float*)(rank + 38750);       // 20480
    float* gcnt  = hsum + 20480;                 // 320
    float* f1    = gcnt + 320;                   // 1,840,000
    float* f2    = f1 + 1840000;                 // 2,480,000
    int*   dbase = (int*)(f2 + 2480000);         // 38750
    int*   bsum  = dbase + 38750;                // 160
    int*   boff  = bsum + 160;                   // 160
    int*   eposc = boff + 160;                   // 620000
    int*   c2d   = eposc + 620000;               // 640512
    int*   ssd   = c2d + 640512;                 // 640512
    float* sfx   = (float*)(ssd + 640512);
    float* sfy   = sfx + 640512;
    float* sfz   = sfy + 640512;
    int*   dss   = (int*)(sfz + 640512);         // 620000
    int*   dcell = dss + 620000;                 // 620000
    float* dfx   = (float*)(dcell + 620000);     // 620000
    float* dfy   = dfx + 620000;                 // 620000
    float* dfz   = dfy + 620000;                 // 620000
    int*   bb    = (int*)(dfz + 620000);         // 155136
    int*   csPad = bb + 155136;                  // 320
    int*   cellTot = csPad + 320;                // 320
    int*   cot   = cellTot + 320;                // 10008
    ushortT* f1bf = (ushortT*)(((size_t)(cot + 10008) + 15) & ~(size_t)15);  // 1,840,000 ushorts
    uint4* whi   = (uint4*)(((size_t)(f1bf + 1840000) + 15) & ~(size_t)15);  // 288000
    __half* Ph   = (__half*)(whi + 288000);      // 324096*64 halves (~41.5MB)

    // zero dcnt + rank + hsum + gcnt (contiguous)
    hipMemsetAsync(dcnt, 0, (size_t)(38750 * 2 + 20480 + 320) * sizeof(int), stream);

    P5f PS, X, WA, RootA, BiasA, WB, RootB, BiasB;
    P5i EI, Batch;
    for (int l = 0; l < 5; l++) {
        const int b = l * 10;
        X.p[l]     = (const float*)d_in[b + 0];
        PS.p[l]    = (const float*)d_in[b + 1];
        EI.p[l]    = (const int*)d_in[b + 2];
        Batch.p[l] = (const int*)d_in[b + 3];
        WA.p[l]    = (const float*)d_in[b + 4];
        RootA.p[l] = (const float*)d_in[b + 5];
        BiasA.p[l] = (const float*)d_in[b + 6];
        WB.p[l]    = (const float*)d_in[b + 7];
        RootB.p[l] = (const float*)d_in[b + 8];
        BiasB.p[l] = (const float*)d_in[b + 9];
    }

    // prep (all levels fused)
    k_hist<<<2424, 256, 0, stream>>>(PS, EI, dcnt, bb);
    k_cellscan<<<5, 64, 0, stream>>>(bb, csPad, cellTot, cot);
    k_cellscatter<<<2424, 256, 0, stream>>>(PS, EI, bb, csPad, ssd, sfx, sfy, sfz, eposc);
    k_nscan1<<<154, 256, 0, stream>>>(dcnt, dbase, bsum);
    k_nscan2<<<5, 64, 0, stream>>>(bsum, boff);
    k_dscatter<<<2424, 256, 0, stream>>>(PS, EI, dbase, boff, rank, eposc, c2d,
                                         dss, dcell, dfx, dfy, dfz);
    k_wswz<<<1125, 256, 0, stream>>>(WB, whi);

    // fused conv A (scatter to LDS S + S@Wa + epilogue), all levels
    conv_a_fused<<<2424, 256, 0, stream>>>(X, WA, RootA, BiasA, dss, dcell, dfx, dfy, dfz,
                                           dbase, boff, dcnt, f1, f1bf);

    // conv B + node gather (P buffer reused between l1 and l2-5)
    conv_b32<<<5064, 256, 0, stream>>>(f1bf, ssd, sfx, sfy, sfz, c2d, whi,
                                       cot, csPad, cellTot, Ph);
    node_b32<<<5000, 256, 0, stream>>>(Ph, dbase, boff, dcnt, f1, RootB.p[0], BiasB.p[0], f2);
    conv_b64<<<4944, 256, 0, stream>>>(f1bf, ssd, sfx, sfy, sfz, c2d, whi, cot, csPad, cellTot, Ph);
    node_b64<<<4688, 256, 0, stream>>>(Ph, dbase, boff, dcnt, f1, RootB, BiasB, f2);

    // readout + FC
    k_read<<<606, 256, 0, stream>>>(f2, Batch, hsum, gcnt);
    fc_kernel<<<1, 64, 0, stream>>>(hsum, gcnt, (const float*)d_in[50], (const float*)d_in[51],
                                    (float*)d_out);
}

// Round 8
// 501.220 us; speedup vs baseline: 2.0903x; 1.1275x over previous
//
#include <hip/hip_runtime.h>
#include <hip/hip_fp16.h>
#include <math.h>

#define NUM_GRAPHS 64

typedef unsigned short ushortT;
typedef __attribute__((ext_vector_type(8))) short bf16x8;
typedef __attribute__((ext_vector_type(4))) float f32x4;

// ---- static level tables ----
constexpr int cN[5]       = {20000, 10000, 5000, 2500, 1250};
constexpr int cE[5]       = {320000, 160000, 80000, 40000, 20000};
constexpr int cNOFF[6]    = {0, 20000, 30000, 35000, 37500, 38750};
constexpr int cEOFF[6]    = {0, 320000, 480000, 560000, 600000, 620000};
constexpr int cEBLKOFF[6] = {0, 1250, 1875, 2188, 2345, 2424};
constexpr int cNBLKOFF[6] = {0, 79, 119, 139, 149, 154};
constexpr int cMT[5]      = {5064, 2564, 1314, 689, 377};
constexpr int cTILEOFF[6] = {0, 5064, 7628, 8942, 9631, 10008};
constexpr int cSEOFF[6]   = {0, 324096, 488192, 572288, 616384, 640512};
constexpr int cF1OFF[6]   = {0, 640000, 1280000, 1600000, 1760000, 1840000};
constexpr int cWOFF[6]    = {0, 32000, 96000, 160000, 224000, 288000};
constexpr int cABLK[6]    = {0, 1250, 1875, 2188, 2345, 2424};  // ceil(N/16) prefix

struct P5f { const float* p[5]; };
struct P5i { const int* p[5]; };

__device__ __forceinline__ int lvl_e(int b) {
    return (b >= cEBLKOFF[4]) ? 4 : (b >= cEBLKOFF[3]) ? 3 : (b >= cEBLKOFF[2]) ? 2 : (b >= cEBLKOFF[1]) ? 1 : 0;
}
__device__ __forceinline__ int lvl_n(int b) {
    return (b >= cNBLKOFF[4]) ? 4 : (b >= cNBLKOFF[3]) ? 3 : (b >= cNBLKOFF[2]) ? 2 : (b >= cNBLKOFF[1]) ? 1 : 0;
}

__device__ __forceinline__ ushortT f2bf(float f) {
    union { float f; unsigned int u; } v; v.f = f;
    unsigned int r = (v.u + 0x7FFFu + ((v.u >> 16) & 1u)) >> 16;
    return (ushortT)r;
}
__device__ __forceinline__ float h2f_lo(unsigned int u) {
    return __half2float(__ushort_as_half((ushortT)(u & 0xFFFFu)));
}
__device__ __forceinline__ float h2f_hi(unsigned int u) {
    return __half2float(__ushort_as_half((ushortT)(u >> 16)));
}

// ---------------- prep: per-block cell histogram + dst degree count ----------------
__global__ void k_hist(P5f PS, P5i EI, int* __restrict__ dcnt, int* __restrict__ bb) {
    int b = blockIdx.x;
    int l = lvl_e(b);
    int lb = b - cEBLKOFF[l];
    int E = cE[l];
    __shared__ int h[64];
    int t = threadIdx.x;
    if (t < 64) h[t] = 0;
    __syncthreads();
    int e = lb * 256 + t;
    if (e < E) {
        atomicAdd(&dcnt[cNOFF[l] + EI.p[l][E + e]], 1);
        const float* ps = PS.p[l];
        int c = (int)floorf(ps[e * 3] * 4.f) * 16 + (int)floorf(ps[e * 3 + 1] * 4.f) * 4
              + (int)floorf(ps[e * 3 + 2] * 4.f);
        atomicAdd(&h[c], 1);
    }
    __syncthreads();
    if (t < 64) bb[(size_t)b * 64 + t] = h[t];
}

// ---------------- cell scan ----------------
__global__ void k_cellscan(int* __restrict__ bb_all, int* __restrict__ csPad,
                           int* __restrict__ cellTot, int* __restrict__ cot_all) {
    int l = blockIdx.x;
    int c = threadIdx.x;
    int* bb = bb_all + (size_t)cEBLKOFF[l] * 64;
    int nblk = cEBLKOFF[l + 1] - cEBLKOFF[l];
    int run = 0;
    int b = 0;
    for (; b + 16 <= nblk; b += 16) {
        int v[16];
#pragma unroll
        for (int u = 0; u < 16; u++) v[u] = bb[(b + u) * 64 + c];
#pragma unroll
        for (int u = 0; u < 16; u++) { bb[(b + u) * 64 + c] = run; run += v[u]; }
    }
    for (; b < nblk; b++) { int v = bb[b * 64 + c]; bb[b * 64 + c] = run; run += v; }
    int tot = run;
    cellTot[l * 64 + c] = tot;
    int tiles = (tot + 63) >> 6;
    int x = tiles;
#pragma unroll
    for (int off = 1; off < 64; off <<= 1) { int y = __shfl_up(x, off, 64); if (c >= off) x += y; }
    int tileBase = x - tiles;
    csPad[l * 64 + c] = tileBase * 64;
    int* cot = cot_all + cTILEOFF[l];
    for (int i = 0; i < tiles; i++) cot[tileBase + i] = c;
    int nT = __shfl(x, 63, 64);
    int mt = cMT[l];
    for (int i = nT + c; i < mt; i += 64) cot[i] = -1;
}

// ---------------- cell scatter: packed cbrec {src, 0, fx|fy, fz} ----------------
__global__ void k_cellscatter(P5f PS, P5i EI, const int* __restrict__ bb, const int* __restrict__ csPad,
                              int4* __restrict__ cbrec, int* __restrict__ eposc) {
    int b = blockIdx.x;
    int l = lvl_e(b);
    int lb = b - cEBLKOFF[l];
    int E = cE[l];
    __shared__ int base[64];
    __shared__ int cnt[64];
    int t = threadIdx.x;
    if (t < 64) { base[t] = bb[(size_t)b * 64 + t] + csPad[l * 64 + t]; cnt[t] = 0; }
    __syncthreads();
    int e = lb * 256 + t;
    if (e < E) {
        const float* ps = PS.p[l];
        float v0 = ps[e * 3] * 4.f, v1 = ps[e * 3 + 1] * 4.f, v2 = ps[e * 3 + 2] * 4.f;
        float f0 = floorf(v0), f1v = floorf(v1), f2v = floorf(v2);
        int c = (int)f0 * 16 + (int)f1v * 4 + (int)f2v;
        int r = atomicAdd(&cnt[c], 1);
        int pos = base[c] + r;
        unsigned int fxfy = (unsigned int)__half_as_ushort(__float2half(v0 - f0))
                          | ((unsigned int)__half_as_ushort(__float2half(v1 - f1v)) << 16);
        unsigned int fzp  = (unsigned int)__half_as_ushort(__float2half(v2 - f2v));
        int4 rec;
        rec.x = EI.p[l][e];
        rec.y = 0;
        rec.z = (int)fxfy;
        rec.w = (int)fzp;
        cbrec[cSEOFF[l] + pos] = rec;
        eposc[cEOFF[l] + e] = pos;
    }
}

// ---------------- node-degree scans ----------------
__global__ void k_nscan1(const int* __restrict__ dcnt, int* __restrict__ dbase, int* __restrict__ bsum) {
    int b = blockIdx.x;
    int l = lvl_n(b);
    int lb = b - cNBLKOFF[l];
    int n = cN[l];
    __shared__ int sh[256];
    int t = threadIdx.x;
    int i = lb * 256 + t;
    int v = (i < n) ? dcnt[cNOFF[l] + i] : 0;
    sh[t] = v;
    __syncthreads();
    for (int off = 1; off < 256; off <<= 1) {
        int y = (t >= off) ? sh[t - off] : 0;
        __syncthreads();
        sh[t] += y;
        __syncthreads();
    }
    if (i < n) dbase[cNOFF[l] + i] = sh[t] - v;
    if (t == 255) bsum[b] = sh[255];
}

__global__ void k_nscan2(const int* __restrict__ bsum, int* __restrict__ boff) {
    int l = blockIdx.x;
    int o = cNBLKOFF[l];
    int nb = cNBLKOFF[l + 1] - o;
    int t = threadIdx.x;
    int v = (t < nb) ? bsum[o + t] : 0;
    int s = v;
#pragma unroll
    for (int off = 1; off < 64; off <<= 1) { int y = __shfl_up(s, off, 64); if (t >= off) s += y; }
    int tot = __shfl(s, 63, 64);
    if (t < nb) boff[o + t] = s - v;
    int t2 = t + 64;
    int v2 = (t2 < nb) ? bsum[o + t2] : 0;
    int s2 = v2;
#pragma unroll
    for (int off = 1; off < 64; off <<= 1) { int y = __shfl_up(s2, off, 64); if (t >= off) s2 += y; }
    if (t2 < nb) boff[o + t2] = tot + s2 - v2;
}

// ---- dst scatter: patch c2d into cbrec + write dst-ordered darec ----------------
__global__ void k_dscatter(P5f PS, P5i EI, const int* __restrict__ dbase, const int* __restrict__ boff,
                           int* __restrict__ rank, const int* __restrict__ eposc,
                           int* __restrict__ cbrec_i, int4* __restrict__ darec) {
    int b = blockIdx.x;
    int l = lvl_e(b);
    int lb = b - cEBLKOFF[l];
    int E = cE[l];
    int e = lb * 256 + threadIdx.x;
    if (e >= E) return;
    const int* ei = EI.p[l];
    int src = ei[e];
    int dst = ei[E + e];
    int p = dbase[cNOFF[l] + dst] + boff[cNBLKOFF[l] + (dst >> 8)]
          + atomicAdd(&rank[cNOFF[l] + dst], 1);
    int posc = eposc[cEOFF[l] + e];
    cbrec_i[(size_t)(cSEOFF[l] + posc) * 4 + 1] = p;  // patch .y = c2d
    const float* ps = PS.p[l];
    float v0 = ps[e * 3] * 4.f, v1 = ps[e * 3 + 1] * 4.f, v2 = ps[e * 3 + 2] * 4.f;
    float f0 = floorf(v0), f1v = floorf(v1), f2v = floorf(v2);
    int cell = (int)f0 * 16 + (int)f1v * 4 + (int)f2v;
    unsigned int fxfy = (unsigned int)__half_as_ushort(__float2half(v0 - f0))
                      | ((unsigned int)__half_as_ushort(__float2half(v1 - f1v)) << 16);
    unsigned int fzp  = (unsigned int)__half_as_ushort(__float2half(v2 - f2v));
    int4 rec;
    rec.x = src | (dst << 16);
    rec.y = cell;
    rec.z = (int)fxfy;
    rec.w = (int)fzp;
    darec[cEOFF[l] + p] = rec;
}

// -------- W swizzle (all levels): Wb[125][CIN][64] fp32 -> MFMA B-frag bf16 ----------
__global__ void k_wswz(P5f WB, uint4* __restrict__ hi4) {
    int idx = blockIdx.x * 256 + threadIdx.x;
    if (idx >= 288000) return;
    int l = (idx >= 224000) ? 4 : (idx >= 160000) ? 3 : (idx >= 96000) ? 2 : (idx >= 32000) ? 1 : 0;
    int local = idx - cWOFF[l];
    int T = l ? 2 : 1, C = l ? 64 : 32;
    int lane = local & 63;
    int blk = (local >> 6) & 3;
    int rest = local >> 8;
    int st = rest % T, s = rest / T;
    int q = lane >> 4, n = blk * 16 + (lane & 15);
    const float* W = WB.p[l];
    union { ushortT u[8]; uint4 v; } ph;
#pragma unroll
    for (int j = 0; j < 8; j++) {
        int k = st * 32 + q * 8 + j;
        ph.u[j] = f2bf(W[((size_t)s * C + k) * 64 + n]);
    }
    hi4[idx] = ph.v;
}

// ---- Fused Conv A: block = 16 nodes, corner-parallel edges -> LDS S, then S@Wa ------
template<int C1>
__device__ __forceinline__ void conv_a_gemm(const float* __restrict__ S, const float* __restrict__ Wa,
                                            const float* __restrict__ x, const float* __restrict__ ra,
                                            const float* __restrict__ ba, const int* __restrict__ dcl,
                                            int node0, int nn, float* __restrict__ f1l,
                                            ushortT* __restrict__ f1bfl, int t) {
    int ch = t % C1;
    int npp = 256 / C1;
    float bias = ba[ch];
    float root = ra[ch];
    for (int node = t / C1; node < nn; node += npp) {
        const float* Sr = S + node * 126;
        float s = 0.f;
#pragma unroll 5
        for (int k = 0; k < 125; k++) s = fmaf(Sr[k], Wa[k * C1 + ch], s);
        int gnode = node0 + node;
        int dv = dcl[gnode];
        float d = (float)(dv > 1 ? dv : 1);
        float o = s / d + x[gnode] * root + bias;
        o = fmaxf(o, 0.f);
        f1l[(size_t)gnode * C1 + ch] = o;
        f1bfl[(size_t)gnode * C1 + ch] = f2bf(o);
    }
}

__launch_bounds__(256)
__global__ void conv_a_fused(P5f X, P5f WA, P5f RootA, P5f BiasA,
                             const int4* __restrict__ darec,
                             const int* __restrict__ dbase, const int* __restrict__ boff,
                             const int* __restrict__ dcnt, float* __restrict__ f1,
                             ushortT* __restrict__ f1bf) {
    __shared__ float S[16 * 126];
    int b = blockIdx.x;
    int l = (b >= cABLK[4]) ? 4 : (b >= cABLK[3]) ? 3 : (b >= cABLK[2]) ? 2 : (b >= cABLK[1]) ? 1 : 0;
    int node0 = (b - cABLK[l]) * 16;
    int n = cN[l];
    int nn = n - node0; if (nn > 16) nn = 16;
    int t = threadIdx.x;
    for (int i = t; i < 16 * 126; i += 256) S[i] = 0.f;
    __syncthreads();
    const int* db = dbase + cNOFF[l];
    const int* bo = boff + cNBLKOFF[l];
    int estart = db[node0] + bo[node0 >> 8];
    int vend = node0 + nn;
    int eend = (vend >= n) ? cE[l] : (db[vend] + bo[vend >> 8]);
    const float* x = X.p[l];
    const int4* dr = darec + cEOFF[l];
    const int bx = t & 1, by = (t >> 1) & 1, bz = (t >> 2) & 1;
    for (int p = estart + (t >> 3); p < eend; p += 32) {
        int4 r = dr[p];
        int src = r.x & 0xFFFF, dst = ((unsigned int)r.x) >> 16;
        int cell = r.y;
        unsigned int uz = (unsigned int)r.z;
        float fx = h2f_lo(uz), fy = h2f_hi(uz), fz = h2f_lo((unsigned int)r.w);
        float xs = x[src];
        int cx = cell >> 4, cy = (cell >> 2) & 3, cz = cell & 3;
        int slot = (cx + bx) * 25 + (cy + by) * 5 + (cz + bz);
        float wc = (bx ? fx : 1.f - fx) * (by ? fy : 1.f - fy) * (bz ? fz : 1.f - fz);
        atomicAdd(&S[(dst - node0) * 126 + slot], wc * xs);
    }
    __syncthreads();
    if (l == 0)
        conv_a_gemm<32>(S, WA.p[0], X.p[0], RootA.p[0], BiasA.p[0], dcnt + cNOFF[0],
                        node0, nn, f1 + cF1OFF[0], f1bf + cF1OFF[0], t);
    else
        conv_a_gemm<64>(S, WA.p[l], X.p[l], RootA.p[l], BiasA.p[l], dcnt + cNOFF[l],
                        node0, nn, f1 + cF1OFF[l], f1bf + cF1OFF[l], t);
}

// ---- Conv B tile core: A-frags direct from global bf16, single-bf16 MFMA ------------
template<int CIN>
__device__ __forceinline__ void conv_b_tile(
    const ushortT* __restrict__ f1bfl, const int4* __restrict__ cbrec_l,
    const uint4* __restrict__ whiL,
    int cell, int tb, int valid, __half* __restrict__ pout,
    float* fxs, float* fys, float* fzs, int* d2s, int* srcs) {
    const int T = CIN / 32;
    int t = threadIdx.x;
    if (t < 64) {
        bool v = t < valid;
        int4 r;
        if (v) r = cbrec_l[tb + t]; else { r.x = 0; r.y = 0; r.z = 0; r.w = 0; }
        srcs[t] = r.x;
        d2s[t] = r.y;
        unsigned int uz = (unsigned int)r.z;
        fxs[t] = h2f_lo(uz);
        fys[t] = h2f_hi(uz);
        fzs[t] = h2f_lo((unsigned int)r.w);
    }
    __syncthreads();

    int lane = t & 63, w = t >> 6;
    int q = lane >> 4, m = lane & 15;

    bf16x8 ahr[4][T];
#pragma unroll
    for (int mt = 0; mt < 4; mt++) {
        int src = srcs[16 * mt + m];
#pragma unroll
        for (int st = 0; st < T; st++)
            ahr[mt][st] = *(const bf16x8*)&f1bfl[(size_t)src * CIN + st * 32 + q * 8];
    }
    float fxr[16], fyr[16], fzr[16];
#pragma unroll
    for (int mt = 0; mt < 4; mt++)
#pragma unroll
        for (int rr = 0; rr < 4; rr++) {
            int row = 16 * mt + q * 4 + rr;
            fxr[mt * 4 + rr] = fxs[row];
            fyr[mt * 4 + rr] = fys[row];
            fzr[mt * 4 + rr] = fzs[row];
        }
    int cx = cell >> 4, cy = (cell >> 2) & 3, cz = cell & 3;
    f32x4 acc[4];
#pragma unroll
    for (int mt = 0; mt < 4; mt++) acc[mt] = (f32x4){0.f, 0.f, 0.f, 0.f};

#pragma unroll
    for (int cor = 0; cor < 8; cor++) {
        const int bx = cor & 1, by = (cor >> 1) & 1, bz = (cor >> 2) & 1;
        int slot = (cx + bx) * 25 + (cy + by) * 5 + (cz + bz);
        f32x4 C[4];
#pragma unroll
        for (int mt = 0; mt < 4; mt++) C[mt] = (f32x4){0.f, 0.f, 0.f, 0.f};
#pragma unroll
        for (int st = 0; st < T; st++) {
            bf16x8 bh = __builtin_bit_cast(bf16x8, whiL[((size_t)(slot * T + st) * 4 + w) * 64 + lane]);
#pragma unroll
            for (int mt = 0; mt < 4; mt++)
                C[mt] = __builtin_amdgcn_mfma_f32_16x16x32_bf16(ahr[mt][st], bh, C[mt], 0, 0, 0);
        }
#pragma unroll
        for (int mt = 0; mt < 4; mt++)
#pragma unroll
            for (int rr = 0; rr < 4; rr++) {
                int i16 = mt * 4 + rr;
                float wr = (bx ? fxr[i16] : 1.f - fxr[i16]) * (by ? fyr[i16] : 1.f - fyr[i16])
                         * (bz ? fzr[i16] : 1.f - fzr[i16]);
                acc[mt][rr] = fmaf(wr, C[mt][rr], acc[mt][rr]);
            }
    }
#pragma unroll
    for (int mt = 0; mt < 4; mt++)
#pragma unroll
        for (int rr = 0; rr < 4; rr++) {
            int row = 16 * mt + q * 4 + rr;
            if (row < valid)
                pout[(size_t)d2s[row] * 64 + 16 * w + m] = __float2half(acc[mt][rr]);
        }
}

__launch_bounds__(256)
__global__ void conv_b32(const ushortT* __restrict__ f1bf, const int4* __restrict__ cbrec,
                         const uint4* __restrict__ whi,
                         const int* __restrict__ cot, const int* __restrict__ csPad,
                         const int* __restrict__ cellTot, __half* __restrict__ Ph) {
    __shared__ float fxs[64], fys[64], fzs[64];
    __shared__ int d2s[64], srcs[64];
    int tile = blockIdx.x;
    int cell = cot[tile];
    if (cell < 0) return;
    int tb = tile * 64;
    int valid = csPad[cell] + cellTot[cell] - tb;
    if (valid > 64) valid = 64;
    conv_b_tile<32>(f1bf, cbrec, whi, cell, tb, valid, Ph, fxs, fys, fzs, d2s, srcs);
}

__launch_bounds__(256)
__global__ void conv_b64(const ushortT* __restrict__ f1bf, const int4* __restrict__ cbrec,
                         const uint4* __restrict__ whi,
                         const int* __restrict__ cot, const int* __restrict__ csPad,
                         const int* __restrict__ cellTot, __half* __restrict__ Ph) {
    __shared__ float fxs[64], fys[64], fzs[64];
    __shared__ int d2s[64], srcs[64];
    const int TB2[4] = {0, 2564, 3878, 4567};
    const int PB2[4] = {0, 160000, 240000, 280000};
    int blk = blockIdx.x;
    int li = (blk >= 4567) ? 3 : (blk >= 3878) ? 2 : (blk >= 2564) ? 1 : 0;
    int l = li + 1;
    int tile = blk - TB2[li];
    int cell = cot[cTILEOFF[l] + tile];
    if (cell < 0) return;
    int tb = tile * 64;
    int valid = csPad[l * 64 + cell] + cellTot[l * 64 + cell] - tb;
    if (valid > 64) valid = 64;
    conv_b_tile<64>(f1bf + cF1OFF[l], cbrec + cSEOFF[l], whi + cWOFF[l],
                    cell, tb, valid, Ph + (size_t)PB2[li] * 64, fxs, fys, fzs, d2s, srcs);
}

// ---------------- node gather: sum contiguous P rows + root + bias + relu -> f2 -------
template<int CIN>
__device__ __forceinline__ void node_b_node(const __half* __restrict__ Ph, int start, int deg,
                                            const float* __restrict__ f1l, int nodeLocal,
                                            const float* __restrict__ rootb, const float* __restrict__ biasb,
                                            float* __restrict__ f2row, int lane) {
    const __half* pr = Ph + (size_t)start * 64 + lane;
    float s0 = 0.f, s1 = 0.f;
    int j = 0;
    for (; j + 2 <= deg; j += 2) {
        s0 += __half2float(pr[(size_t)j * 64]);
        s1 += __half2float(pr[(size_t)(j + 1) * 64]);
    }
    if (j < deg) s0 += __half2float(pr[(size_t)j * 64]);
    float s = s0 + s1;
    int dv = deg > 1 ? deg : 1;
    s /= (float)dv;
    float fr = (lane < CIN) ? f1l[(size_t)nodeLocal * CIN + lane] : 0.f;
#pragma unroll 8
    for (int i = 0; i < CIN; i++) s = fmaf(__shfl(fr, i, 64), rootb[i * 64 + lane], s);
    s += biasb[lane];
    f2row[lane] = fmaxf(s, 0.f);
}

__launch_bounds__(256)
__global__ void node_b32(const __half* __restrict__ Ph, const int* __restrict__ dbase,
                         const int* __restrict__ boff, const int* __restrict__ dcnt,
                         const float* __restrict__ f1, const float* __restrict__ rootb,
                         const float* __restrict__ biasb, float* __restrict__ f2) {
    int lane = threadIdx.x & 63;
    int node = blockIdx.x * 4 + (threadIdx.x >> 6);
    if (node >= 20000) return;
    int start = dbase[node] + boff[node >> 8];
    int deg = dcnt[node];
    node_b_node<32>(Ph, start, deg, f1, node, rootb, biasb, f2 + (size_t)node * 64, lane);
}

__launch_bounds__(256)
__global__ void node_b64(const __half* __restrict__ Ph, const int* __restrict__ dbase,
                         const int* __restrict__ boff, const int* __restrict__ dcnt,
                         const float* __restrict__ f1, P5f RootB, P5f BiasB,
                         float* __restrict__ f2) {
    const int NB2[4] = {0, 2500, 3750, 4375};
    const int PB2[4] = {0, 160000, 240000, 280000};
    int lane = threadIdx.x & 63;
    int blk = blockIdx.x;
    int li = (blk >= 4375) ? 3 : (blk >= 3750) ? 2 : (blk >= 2500) ? 1 : 0;
    int l = li + 1;
    int node = (blk - NB2[li]) * 4 + (threadIdx.x >> 6);
    if (node >= cN[l]) return;
    int start = dbase[cNOFF[l] + node] + boff[cNBLKOFF[l] + (node >> 8)];
    int deg = dcnt[cNOFF[l] + node];
    node_b_node<64>(Ph + (size_t)PB2[li] * 64, start, deg, f1 + cF1OFF[l], node,
                    RootB.p[l], BiasB.p[l], f2 + (size_t)(cNOFF[l] + node) * 64, lane);
}

// ---------------- readout: run-accumulated graph mean sums ----------------
__launch_bounds__(256)
__global__ void k_read(const float* __restrict__ f2, P5i Batch,
                       float* __restrict__ hsum, float* __restrict__ gcnt) {
    const int RC[5] = {0, 1250, 1875, 2188, 2345};
    int t = threadIdx.x;
    int lane = t & 63;
    int w = blockIdx.x * 4 + (t >> 6);
    if (w >= 2424) return;
    int l = (w >= 2345) ? 4 : (w >= 2188) ? 3 : (w >= 1875) ? 2 : (w >= 1250) ? 1 : 0;
    int base = (w - RC[l]) * 16;
    int Nl = cN[l];
    int nn = Nl - base; if (nn > 16) nn = 16;
    const int* batch = Batch.p[l];
    const float* fb = f2 + (size_t)(cNOFF[l] + base) * 64;
    int curg = -1; float hacc = 0.f; int crun = 0;
    for (int j = 0; j < nn; j++) {
        int g = batch[base + j];
        if (g != curg) {
            if (curg >= 0) {
                atomicAdd(&hsum[curg * 320 + l * 64 + lane], hacc);
                if (lane == 0) atomicAdd(&gcnt[l * 64 + curg], (float)crun);
            }
            curg = g; hacc = 0.f; crun = 0;
        }
        hacc += fb[(size_t)j * 64 + lane];
        crun++;
    }
    if (curg >= 0) {
        atomicAdd(&hsum[curg * 320 + l * 64 + lane], hacc);
        if (lane == 0) atomicAdd(&gcnt[l * 64 + curg], (float)crun);
    }
}

// ---------------- FC + log_softmax: one block per graph, wave-parallel ----------------
__global__ void fc_kernel(const float* __restrict__ hsum, const float* __restrict__ gcnt,
                          const float* __restrict__ fcw, const float* __restrict__ fcb,
                          float* __restrict__ out) {
    int g = blockIdx.x;
    int lane = threadIdx.x;  // 64
    float partial[10];
#pragma unroll
    for (int t = 0; t < 10; t++) partial[t] = 0.f;
#pragma unroll
    for (int k = 0; k < 5; k++) {
        int j = k * 64 + lane;
        float c = fmaxf(gcnt[k * 64 + g], 1.f);
        float h = hsum[g * 320 + j] / c;
        const float* fw = fcw + j * 10;
#pragma unroll
        for (int t = 0; t < 10; t++) partial[t] = fmaf(h, fw[t], partial[t]);
    }
#pragma unroll
    for (int off = 32; off >= 1; off >>= 1)
#pragma unroll
        for (int t = 0; t < 10; t++) partial[t] += __shfl_xor(partial[t], off, 64);
    if (lane == 0) {
        float logit[10];
#pragma unroll
        for (int t = 0; t < 10; t++) logit[t] = partial[t] + fcb[t];
        float m = logit[0];
#pragma unroll
        for (int t = 1; t < 10; t++) m = fmaxf(m, logit[t]);
        float sum = 0.f;
#pragma unroll
        for (int t = 0; t < 10; t++) sum += expf(logit[t] - m);
        float lse = m + logf(sum);
#pragma unroll
        for (int t = 0; t < 10; t++) out[g * 10 + t] = logit[t] - lse;
    }
}

extern "C" void kernel_launch(void* const* d_in, const int* in_sizes, int n_in,
                              void* d_out, int out_size, void* d_ws, size_t ws_size,
                              hipStream_t stream) {
    int* wsI = (int*)d_ws;
    int*   dcnt  = wsI;                          // 38750
    int*   rank  = dcnt + 38750;                 // 38750
    float* hsum  = (float*)(rank + 38750);       // 20480
    float* gcnt  = hsum + 20480;                 // 320
    float* f1    = gcnt + 320;                   // 1,840,000
    float* f2    = f1 + 1840000;                 // 2,480,000
    int*   dbase = (int*)(f2 + 2480000);         // 38750
    int*   bsum  = dbase + 38750;                // 160
    int*   boff  = bsum + 160;                   // 160
    int*   eposc = boff + 160;                   // 620000
    int*   bb    = eposc + 620000;               // 155136
    int*   csPad = bb + 155136;                  // 320
    int*   cellTot = csPad + 320;                // 320
    int*   cot   = cellTot + 320;                // 10008
    int4*  cbrec = (int4*)(((size_t)(cot + 10008) + 15) & ~(size_t)15);   // 640512 recs
    int4*  darec = cbrec + 640512;               // 620000 recs
    ushortT* f1bf = (ushortT*)(darec + 620000);  // 1,840,000 ushorts
    uint4* whi   = (uint4*)(((size_t)(f1bf + 1840000) + 15) & ~(size_t)15);  // 288000
    __half* Ph   = (__half*)(whi + 288000);      // 324096*64 halves (~41.5MB)

    // zero dcnt + rank + hsum + gcnt (contiguous)
    hipMemsetAsync(dcnt, 0, (size_t)(38750 * 2 + 20480 + 320) * sizeof(int), stream);

    P5f PS, X, WA, RootA, BiasA, WB, RootB, BiasB;
    P5i EI, Batch;
    for (int l = 0; l < 5; l++) {
        const int b = l * 10;
        X.p[l]     = (const float*)d_in[b + 0];
        PS.p[l]    = (const float*)d_in[b + 1];
        EI.p[l]    = (const int*)d_in[b + 2];
        Batch.p[l] = (const int*)d_in[b + 3];
        WA.p[l]    = (const float*)d_in[b + 4];
        RootA.p[l] = (const float*)d_in[b + 5];
        BiasA.p[l] = (const float*)d_in[b + 6];
        WB.p[l]    = (const float*)d_in[b + 7];
        RootB.p[l] = (const float*)d_in[b + 8];
        BiasB.p[l] = (const float*)d_in[b + 9];
    }

    // prep (all levels fused)
    k_hist<<<2424, 256, 0, stream>>>(PS, EI, dcnt, bb);
    k_cellscan<<<5, 64, 0, stream>>>(bb, csPad, cellTot, cot);
    k_cellscatter<<<2424, 256, 0, stream>>>(PS, EI, bb, csPad, cbrec, eposc);
    k_nscan1<<<154, 256, 0, stream>>>(dcnt, dbase, bsum);
    k_nscan2<<<5, 64, 0, stream>>>(bsum, boff);
    k_dscatter<<<2424, 256, 0, stream>>>(PS, EI, dbase, boff, rank, eposc, (int*)cbrec, darec);
    k_wswz<<<1125, 256, 0, stream>>>(WB, whi);

    // fused conv A (corner-parallel LDS scatter + S@Wa + epilogue), all levels
    conv_a_fused<<<2424, 256, 0, stream>>>(X, WA, RootA, BiasA, darec,
                                           dbase, boff, dcnt, f1, f1bf);

    // conv B + node gather (P buffer reused between l1 and l2-5)
    conv_b32<<<5064, 256, 0, stream>>>(f1bf, cbrec, whi, cot, csPad, cellTot, Ph);
    node_b32<<<5000, 256, 0, stream>>>(Ph, dbase, boff, dcnt, f1, RootB.p[0], BiasB.p[0], f2);
    conv_b64<<<4944, 256, 0, stream>>>(f1bf, cbrec, whi, cot, csPad, cellTot, Ph);
    node_b64<<<4688, 256, 0, stream>>>(Ph, dbase, boff, dcnt, f1, RootB, BiasB, f2);

    // readout + FC
    k_read<<<606, 256, 0, stream>>>(f2, Batch, hsum, gcnt);
    fc_kernel<<<64, 64, 0, stream>>>(hsum, gcnt, (const float*)d_in[50], (const float*)d_in[51],
                                     (float*)d_out);
}

// Round 9
// 498.164 us; speedup vs baseline: 2.1031x; 1.0061x over previous
//
#include <hip/hip_runtime.h>
#include <hip/hip_fp16.h>
#include <math.h>

#define NUM_GRAPHS 64

typedef unsigned short ushortT;
typedef __attribute__((ext_vector_type(8))) short bf16x8;
typedef __attribute__((ext_vector_type(4))) float f32x4;

// ---- static level tables ----
constexpr int cN[5]       = {20000, 10000, 5000, 2500, 1250};
constexpr int cE[5]       = {320000, 160000, 80000, 40000, 20000};
constexpr int cNOFF[6]    = {0, 20000, 30000, 35000, 37500, 38750};
constexpr int cEOFF[6]    = {0, 320000, 480000, 560000, 600000, 620000};
constexpr int cEBLKOFF[6] = {0, 1250, 1875, 2188, 2345, 2424};
constexpr int cNBLKOFF[6] = {0, 79, 119, 139, 149, 154};
constexpr int cMT[5]      = {5064, 2564, 1314, 689, 377};
constexpr int cTILEOFF[6] = {0, 5064, 7628, 8942, 9631, 10008};
constexpr int cSEOFF[6]   = {0, 324096, 488192, 572288, 616384, 640512};
constexpr int cF1OFF[6]   = {0, 640000, 1280000, 1600000, 1760000, 1840000};
constexpr int cWOFF[6]    = {0, 32000, 96000, 160000, 224000, 288000};
constexpr int cABLK[6]    = {0, 1250, 1875, 2188, 2345, 2424};   // ceil(N/16) prefix
constexpr int cRBOFF[5]   = {0, 256, 768, 1280, 1792};           // rootb swizzle uint4 offsets
constexpr int cRGB[6]     = {0, 313, 470, 549, 589, 609};        // ceil(N/64) prefix

struct P5f { const float* p[5]; };
struct P5i { const int* p[5]; };

__device__ __forceinline__ int lvl_e(int b) {
    return (b >= cEBLKOFF[4]) ? 4 : (b >= cEBLKOFF[3]) ? 3 : (b >= cEBLKOFF[2]) ? 2 : (b >= cEBLKOFF[1]) ? 1 : 0;
}
__device__ __forceinline__ int lvl_n(int b) {
    return (b >= cNBLKOFF[4]) ? 4 : (b >= cNBLKOFF[3]) ? 3 : (b >= cNBLKOFF[2]) ? 2 : (b >= cNBLKOFF[1]) ? 1 : 0;
}

__device__ __forceinline__ ushortT f2bf(float f) {
    union { float f; unsigned int u; } v; v.f = f;
    unsigned int r = (v.u + 0x7FFFu + ((v.u >> 16) & 1u)) >> 16;
    return (ushortT)r;
}
__device__ __forceinline__ float h2f_lo(unsigned int u) {
    return __half2float(__ushort_as_half((ushortT)(u & 0xFFFFu)));
}
__device__ __forceinline__ float h2f_hi(unsigned int u) {
    return __half2float(__ushort_as_half((ushortT)(u >> 16)));
}

// ---------------- prep: per-block cell histogram + dst degree count ----------------
__global__ void k_hist(P5f PS, P5i EI, int* __restrict__ dcnt, int* __restrict__ bb) {
    int b = blockIdx.x;
    int l = lvl_e(b);
    int lb = b - cEBLKOFF[l];
    int E = cE[l];
    __shared__ int h[64];
    int t = threadIdx.x;
    if (t < 64) h[t] = 0;
    __syncthreads();
    int e = lb * 256 + t;
    if (e < E) {
        atomicAdd(&dcnt[cNOFF[l] + EI.p[l][E + e]], 1);
        const float* ps = PS.p[l];
        int c = (int)floorf(ps[e * 3] * 4.f) * 16 + (int)floorf(ps[e * 3 + 1] * 4.f) * 4
              + (int)floorf(ps[e * 3 + 2] * 4.f);
        atomicAdd(&h[c], 1);
    }
    __syncthreads();
    if (t < 64) bb[(size_t)b * 64 + t] = h[t];
}

// ---------------- cell scan ----------------
__global__ void k_cellscan(int* __restrict__ bb_all, int* __restrict__ csPad,
                           int* __restrict__ cellTot, int* __restrict__ cot_all) {
    int l = blockIdx.x;
    int c = threadIdx.x;
    int* bb = bb_all + (size_t)cEBLKOFF[l] * 64;
    int nblk = cEBLKOFF[l + 1] - cEBLKOFF[l];
    int run = 0;
    int b = 0;
    for (; b + 16 <= nblk; b += 16) {
        int v[16];
#pragma unroll
        for (int u = 0; u < 16; u++) v[u] = bb[(b + u) * 64 + c];
#pragma unroll
        for (int u = 0; u < 16; u++) { bb[(b + u) * 64 + c] = run; run += v[u]; }
    }
    for (; b < nblk; b++) { int v = bb[b * 64 + c]; bb[b * 64 + c] = run; run += v; }
    int tot = run;
    cellTot[l * 64 + c] = tot;
    int tiles = (tot + 63) >> 6;
    int x = tiles;
#pragma unroll
    for (int off = 1; off < 64; off <<= 1) { int y = __shfl_up(x, off, 64); if (c >= off) x += y; }
    int tileBase = x - tiles;
    csPad[l * 64 + c] = tileBase * 64;
    int* cot = cot_all + cTILEOFF[l];
    for (int i = 0; i < tiles; i++) cot[tileBase + i] = c;
    int nT = __shfl(x, 63, 64);
    int mt = cMT[l];
    for (int i = nT + c; i < mt; i += 64) cot[i] = -1;
}

// ---------------- cell scatter: packed cbrec {src, 0, fx|fy, fz} ----------------
__global__ void k_cellscatter(P5f PS, P5i EI, const int* __restrict__ bb, const int* __restrict__ csPad,
                              int4* __restrict__ cbrec, int* __restrict__ eposc) {
    int b = blockIdx.x;
    int l = lvl_e(b);
    int lb = b - cEBLKOFF[l];
    int E = cE[l];
    __shared__ int base[64];
    __shared__ int cnt[64];
    int t = threadIdx.x;
    if (t < 64) { base[t] = bb[(size_t)b * 64 + t] + csPad[l * 64 + t]; cnt[t] = 0; }
    __syncthreads();
    int e = lb * 256 + t;
    if (e < E) {
        const float* ps = PS.p[l];
        float v0 = ps[e * 3] * 4.f, v1 = ps[e * 3 + 1] * 4.f, v2 = ps[e * 3 + 2] * 4.f;
        float f0 = floorf(v0), f1v = floorf(v1), f2v = floorf(v2);
        int c = (int)f0 * 16 + (int)f1v * 4 + (int)f2v;
        int r = atomicAdd(&cnt[c], 1);
        int pos = base[c] + r;
        unsigned int fxfy = (unsigned int)__half_as_ushort(__float2half(v0 - f0))
                          | ((unsigned int)__half_as_ushort(__float2half(v1 - f1v)) << 16);
        unsigned int fzp  = (unsigned int)__half_as_ushort(__float2half(v2 - f2v));
        int4 rec;
        rec.x = EI.p[l][e];
        rec.y = 0;
        rec.z = (int)fxfy;
        rec.w = (int)fzp;
        cbrec[cSEOFF[l] + pos] = rec;
        eposc[cEOFF[l] + e] = pos;
    }
}

// ---------------- node-degree scans ----------------
__global__ void k_nscan1(const int* __restrict__ dcnt, int* __restrict__ dbase, int* __restrict__ bsum) {
    int b = blockIdx.x;
    int l = lvl_n(b);
    int lb = b - cNBLKOFF[l];
    int n = cN[l];
    __shared__ int sh[256];
    int t = threadIdx.x;
    int i = lb * 256 + t;
    int v = (i < n) ? dcnt[cNOFF[l] + i] : 0;
    sh[t] = v;
    __syncthreads();
    for (int off = 1; off < 256; off <<= 1) {
        int y = (t >= off) ? sh[t - off] : 0;
        __syncthreads();
        sh[t] += y;
        __syncthreads();
    }
    if (i < n) dbase[cNOFF[l] + i] = sh[t] - v;
    if (t == 255) bsum[b] = sh[255];
}

__global__ void k_nscan2(const int* __restrict__ bsum, int* __restrict__ boff) {
    int l = blockIdx.x;
    int o = cNBLKOFF[l];
    int nb = cNBLKOFF[l + 1] - o;
    int t = threadIdx.x;
    int v = (t < nb) ? bsum[o + t] : 0;
    int s = v;
#pragma unroll
    for (int off = 1; off < 64; off <<= 1) { int y = __shfl_up(s, off, 64); if (t >= off) s += y; }
    int tot = __shfl(s, 63, 64);
    if (t < nb) boff[o + t] = s - v;
    int t2 = t + 64;
    int v2 = (t2 < nb) ? bsum[o + t2] : 0;
    int s2 = v2;
#pragma unroll
    for (int off = 1; off < 64; off <<= 1) { int y = __shfl_up(s2, off, 64); if (t >= off) s2 += y; }
    if (t2 < nb) boff[o + t2] = tot + s2 - v2;
}

// ---- dst scatter: cpos (dst-pos -> cell-pos) + dst-ordered darec ----------------
__global__ void k_dscatter(P5f PS, P5i EI, const int* __restrict__ dbase, const int* __restrict__ boff,
                           int* __restrict__ rank, const int* __restrict__ eposc,
                           int* __restrict__ cpos, int4* __restrict__ darec) {
    int b = blockIdx.x;
    int l = lvl_e(b);
    int lb = b - cEBLKOFF[l];
    int E = cE[l];
    int e = lb * 256 + threadIdx.x;
    if (e >= E) return;
    const int* ei = EI.p[l];
    int src = ei[e];
    int dst = ei[E + e];
    int p = dbase[cNOFF[l] + dst] + boff[cNBLKOFF[l] + (dst >> 8)]
          + atomicAdd(&rank[cNOFF[l] + dst], 1);
    cpos[cEOFF[l] + p] = eposc[cEOFF[l] + e];
    const float* ps = PS.p[l];
    float v0 = ps[e * 3] * 4.f, v1 = ps[e * 3 + 1] * 4.f, v2 = ps[e * 3 + 2] * 4.f;
    float f0 = floorf(v0), f1v = floorf(v1), f2v = floorf(v2);
    int cell = (int)f0 * 16 + (int)f1v * 4 + (int)f2v;
    unsigned int fxfy = (unsigned int)__half_as_ushort(__float2half(v0 - f0))
                      | ((unsigned int)__half_as_ushort(__float2half(v1 - f1v)) << 16);
    unsigned int fzp  = (unsigned int)__half_as_ushort(__float2half(v2 - f2v));
    int4 rec;
    rec.x = src | (dst << 16);
    rec.y = cell;
    rec.z = (int)fxfy;
    rec.w = (int)fzp;
    darec[cEOFF[l] + p] = rec;
}

// -------- W swizzle: Wb[125][CIN][64] fp32 -> MFMA B-frag bf16 ----------
__global__ void k_wswz(P5f WB, uint4* __restrict__ hi4) {
    int idx = blockIdx.x * 256 + threadIdx.x;
    if (idx >= 288000) return;
    int l = (idx >= 224000) ? 4 : (idx >= 160000) ? 3 : (idx >= 96000) ? 2 : (idx >= 32000) ? 1 : 0;
    int local = idx - cWOFF[l];
    int T = l ? 2 : 1, C = l ? 64 : 32;
    int lane = local & 63;
    int blk = (local >> 6) & 3;
    int rest = local >> 8;
    int st = rest % T, s = rest / T;
    int q = lane >> 4, n = blk * 16 + (lane & 15);
    const float* W = WB.p[l];
    union { ushortT u[8]; uint4 v; } ph;
#pragma unroll
    for (int j = 0; j < 8; j++) {
        int k = st * 32 + q * 8 + j;
        ph.u[j] = f2bf(W[((size_t)s * C + k) * 64 + n]);
    }
    hi4[idx] = ph.v;
}

// -------- rootb swizzle: RootB[CIN][64] -> B-frag bf16 (2304 uint4 total) -----------
__global__ void k_rswz(P5f RootB, uint4* __restrict__ rb) {
    int idx = blockIdx.x * 256 + threadIdx.x;
    if (idx >= 2304) return;
    int l = (idx >= 1792) ? 4 : (idx >= 1280) ? 3 : (idx >= 768) ? 2 : (idx >= 256) ? 1 : 0;
    int local = idx - cRBOFF[l];
    int lane = local & 63;
    int w = (local >> 6) & 3;
    int st = local >> 8;
    int q = lane >> 4, n = w * 16 + (lane & 15);
    const float* R = RootB.p[l];
    union { ushortT u[8]; uint4 v; } ph;
#pragma unroll
    for (int j = 0; j < 8; j++) {
        int k = st * 32 + q * 8 + j;
        ph.u[j] = f2bf(R[k * 64 + n]);
    }
    rb[idx] = ph.v;
}

// ---- Fused Conv A: LDS-staged edges, corner-parallel, ILP'd S@Wa tail ---------------
template<int C1>
__device__ __forceinline__ void conv_a_gemm(const float* __restrict__ S, const float* __restrict__ Wa,
                                            const float* __restrict__ x, const float* __restrict__ ra,
                                            const float* __restrict__ ba, const int* __restrict__ dcl,
                                            int node0, int nn, float* __restrict__ f1l,
                                            ushortT* __restrict__ f1bfl, int t) {
    int ch = t % C1;
    int npp = 256 / C1;
    float bias = ba[ch];
    float root = ra[ch];
    for (int node = t / C1; node < nn; node += npp) {
        const float* Sr = S + node * 126;
        float s0 = 0.f, s1 = 0.f, s2 = 0.f, s3 = 0.f;
#pragma unroll
        for (int k = 0; k < 124; k += 4) {
            s0 = fmaf(Sr[k],     Wa[k * C1 + ch],       s0);
            s1 = fmaf(Sr[k + 1], Wa[(k + 1) * C1 + ch], s1);
            s2 = fmaf(Sr[k + 2], Wa[(k + 2) * C1 + ch], s2);
            s3 = fmaf(Sr[k + 3], Wa[(k + 3) * C1 + ch], s3);
        }
        float s = ((s0 + s1) + (s2 + s3)) + Sr[124] * Wa[124 * C1 + ch];
        int gnode = node0 + node;
        int dv = dcl[gnode];
        float d = (float)(dv > 1 ? dv : 1);
        float o = s / d + x[gnode] * root + bias;
        o = fmaxf(o, 0.f);
        f1l[(size_t)gnode * C1 + ch] = o;
        f1bfl[(size_t)gnode * C1 + ch] = f2bf(o);
    }
}

__launch_bounds__(256)
__global__ void conv_a_fused(P5f X, P5f WA, P5f RootA, P5f BiasA,
                             const int4* __restrict__ darec,
                             const int* __restrict__ dbase, const int* __restrict__ boff,
                             const int* __restrict__ dcnt, float* __restrict__ f1,
                             ushortT* __restrict__ f1bf) {
    __shared__ float S[16 * 126];
    __shared__ int infoS[256];
    __shared__ unsigned int fxyS[256];
    __shared__ unsigned int fzS[256];
    __shared__ float xsS[256];
    int b = blockIdx.x;
    int l = (b >= cABLK[4]) ? 4 : (b >= cABLK[3]) ? 3 : (b >= cABLK[2]) ? 2 : (b >= cABLK[1]) ? 1 : 0;
    int node0 = (b - cABLK[l]) * 16;
    int n = cN[l];
    int nn = n - node0; if (nn > 16) nn = 16;
    int t = threadIdx.x;
    for (int i = t; i < 16 * 126; i += 256) S[i] = 0.f;
    const int* db = dbase + cNOFF[l];
    const int* bo = boff + cNBLKOFF[l];
    int estart = db[node0] + bo[node0 >> 8];
    int vend = node0 + nn;
    int eend = (vend >= n) ? cE[l] : (db[vend] + bo[vend >> 8]);
    const float* x = X.p[l];
    const int4* dr = darec + cEOFF[l];
    const int bx = t & 1, by = (t >> 1) & 1, bz = (t >> 2) & 1;
    for (int cs = estart; cs < eend; cs += 256) {
        int p = cs + t;
        if (p < eend) {
            int4 r = dr[p];
            infoS[t] = ((((unsigned int)r.x) >> 16) - node0) * 64 + r.y;
            fxyS[t] = (unsigned int)r.z;
            fzS[t] = (unsigned int)r.w;
            xsS[t] = x[r.x & 0xFFFF];
        }
        __syncthreads();
        int ne = eend - cs; if (ne > 256) ne = 256;
        for (int j = (t >> 3); j < ne; j += 32) {
            int info = infoS[j];
            int nl = info >> 6, cell = info & 63;
            unsigned int uz = fxyS[j];
            float fx = h2f_lo(uz), fy = h2f_hi(uz), fz = h2f_lo(fzS[j]);
            float xs = xsS[j];
            int cx = cell >> 4, cy = (cell >> 2) & 3, cz = cell & 3;
            int slot = (cx + bx) * 25 + (cy + by) * 5 + (cz + bz);
            float wc = (bx ? fx : 1.f - fx) * (by ? fy : 1.f - fy) * (bz ? fz : 1.f - fz);
            atomicAdd(&S[nl * 126 + slot], wc * xs);
        }
        __syncthreads();
    }
    if (l == 0)
        conv_a_gemm<32>(S, WA.p[0], X.p[0], RootA.p[0], BiasA.p[0], dcnt + cNOFF[0],
                        node0, nn, f1 + cF1OFF[0], f1bf + cF1OFF[0], t);
    else
        conv_a_gemm<64>(S, WA.p[l], X.p[l], RootA.p[l], BiasA.p[l], dcnt + cNOFF[l],
                        node0, nn, f1 + cF1OFF[l], f1bf + cF1OFF[l], t);
}

// ---- R-gemm: f2 = f1bf @ rootb (bf16 MFMA), per-64-node tiles -----------------------
__launch_bounds__(256)
__global__ void k_rgemm(const ushortT* __restrict__ f1bf, const uint4* __restrict__ rb,
                        float* __restrict__ f2) {
    int b = blockIdx.x;
    int l = (b >= cRGB[4]) ? 4 : (b >= cRGB[3]) ? 3 : (b >= cRGB[2]) ? 2 : (b >= cRGB[1]) ? 1 : 0;
    int node0 = (b - cRGB[l]) * 64;
    int n = cN[l];
    int nn = n - node0; if (nn > 64) nn = 64;
    int t = threadIdx.x;
    int lane = t & 63, w = t >> 6;
    int q = lane >> 4, m = lane & 15;
    const int CIN = l ? 64 : 32;
    const int T = l ? 2 : 1;
    const ushortT* fl = f1bf + cF1OFF[l];
    const uint4* rbl = rb + cRBOFF[l];
    f32x4 C[4];
#pragma unroll
    for (int mt = 0; mt < 4; mt++) C[mt] = (f32x4){0.f, 0.f, 0.f, 0.f};
    for (int st = 0; st < T; st++) {
        bf16x8 bh = __builtin_bit_cast(bf16x8, rbl[(st * 4 + w) * 64 + lane]);
#pragma unroll
        for (int mt = 0; mt < 4; mt++) {
            int row = 16 * mt + m;
            int nr = node0 + row; if (nr > n - 1) nr = n - 1;
            bf16x8 a = *(const bf16x8*)&fl[(size_t)nr * CIN + st * 32 + q * 8];
            C[mt] = __builtin_amdgcn_mfma_f32_16x16x32_bf16(a, bh, C[mt], 0, 0, 0);
        }
    }
#pragma unroll
    for (int mt = 0; mt < 4; mt++)
#pragma unroll
        for (int rr = 0; rr < 4; rr++) {
            int row = 16 * mt + q * 4 + rr;
            if (row < nn)
                f2[(size_t)(cNOFF[l] + node0 + row) * 64 + 16 * w + m] = C[mt][rr];
        }
}

// ---- Conv B tile: A-frags from global bf16, Ph written in CELL order (coalesced) ----
template<int CIN>
__device__ __forceinline__ void conv_b_tile(
    const ushortT* __restrict__ f1bfl, const int4* __restrict__ cbrec_l,
    const uint4* __restrict__ whiL,
    int cell, int tb, int valid, __half* __restrict__ pout,
    float* fxs, float* fys, float* fzs, int* srcs) {
    const int T = CIN / 32;
    int t = threadIdx.x;
    if (t < 64) {
        bool v = t < valid;
        int4 r;
        if (v) r = cbrec_l[tb + t]; else { r.x = 0; r.y = 0; r.z = 0; r.w = 0; }
        srcs[t] = r.x;
        unsigned int uz = (unsigned int)r.z;
        fxs[t] = h2f_lo(uz);
        fys[t] = h2f_hi(uz);
        fzs[t] = h2f_lo((unsigned int)r.w);
    }
    __syncthreads();

    int lane = t & 63, w = t >> 6;
    int q = lane >> 4, m = lane & 15;

    bf16x8 ahr[4][T];
#pragma unroll
    for (int mt = 0; mt < 4; mt++) {
        int src = srcs[16 * mt + m];
#pragma unroll
        for (int st = 0; st < T; st++)
            ahr[mt][st] = *(const bf16x8*)&f1bfl[(size_t)src * CIN + st * 32 + q * 8];
    }
    float fxr[16], fyr[16], fzr[16];
#pragma unroll
    for (int mt = 0; mt < 4; mt++)
#pragma unroll
        for (int rr = 0; rr < 4; rr++) {
            int row = 16 * mt + q * 4 + rr;
            fxr[mt * 4 + rr] = fxs[row];
            fyr[mt * 4 + rr] = fys[row];
            fzr[mt * 4 + rr] = fzs[row];
        }
    int cx = cell >> 4, cy = (cell >> 2) & 3, cz = cell & 3;
    f32x4 acc[4];
#pragma unroll
    for (int mt = 0; mt < 4; mt++) acc[mt] = (f32x4){0.f, 0.f, 0.f, 0.f};

#pragma unroll
    for (int cor = 0; cor < 8; cor++) {
        const int bx = cor & 1, by = (cor >> 1) & 1, bz = (cor >> 2) & 1;
        int slot = (cx + bx) * 25 + (cy + by) * 5 + (cz + bz);
        f32x4 C[4];
#pragma unroll
        for (int mt = 0; mt < 4; mt++) C[mt] = (f32x4){0.f, 0.f, 0.f, 0.f};
#pragma unroll
        for (int st = 0; st < T; st++) {
            bf16x8 bh = __builtin_bit_cast(bf16x8, whiL[((size_t)(slot * T + st) * 4 + w) * 64 + lane]);
#pragma unroll
            for (int mt = 0; mt < 4; mt++)
                C[mt] = __builtin_amdgcn_mfma_f32_16x16x32_bf16(ahr[mt][st], bh, C[mt], 0, 0, 0);
        }
#pragma unroll
        for (int mt = 0; mt < 4; mt++)
#pragma unroll
            for (int rr = 0; rr < 4; rr++) {
                int i16 = mt * 4 + rr;
                float wr = (bx ? fxr[i16] : 1.f - fxr[i16]) * (by ? fyr[i16] : 1.f - fyr[i16])
                         * (bz ? fzr[i16] : 1.f - fzr[i16]);
                acc[mt][rr] = fmaf(wr, C[mt][rr], acc[mt][rr]);
            }
    }
    // coalesced cell-order store
#pragma unroll
    for (int mt = 0; mt < 4; mt++)
#pragma unroll
        for (int rr = 0; rr < 4; rr++) {
            int row = 16 * mt + q * 4 + rr;
            pout[(size_t)(tb + row) * 64 + 16 * w + m] = __float2half(acc[mt][rr]);
        }
}

__launch_bounds__(256)
__global__ void conv_b32(const ushortT* __restrict__ f1bf, const int4* __restrict__ cbrec,
                         const uint4* __restrict__ whi,
                         const int* __restrict__ cot, const int* __restrict__ csPad,
                         const int* __restrict__ cellTot, __half* __restrict__ Ph) {
    __shared__ float fxs[64], fys[64], fzs[64];
    __shared__ int srcs[64];
    int tile = blockIdx.x;
    int cell = cot[tile];
    if (cell < 0) return;
    int tb = tile * 64;
    int valid = csPad[cell] + cellTot[cell] - tb;
    if (valid > 64) valid = 64;
    conv_b_tile<32>(f1bf, cbrec, whi, cell, tb, valid, Ph, fxs, fys, fzs, srcs);
}

__launch_bounds__(256)
__global__ void conv_b64(const ushortT* __restrict__ f1bf, const int4* __restrict__ cbrec,
                         const uint4* __restrict__ whi,
                         const int* __restrict__ cot, const int* __restrict__ csPad,
                         const int* __restrict__ cellTot, __half* __restrict__ Ph) {
    __shared__ float fxs[64], fys[64], fzs[64];
    __shared__ int srcs[64];
    const int TB2[4] = {0, 2564, 3878, 4567};
    int blk = blockIdx.x;
    int li = (blk >= 4567) ? 3 : (blk >= 3878) ? 2 : (blk >= 2564) ? 1 : 0;
    int l = li + 1;
    int tile = blk - TB2[li];
    int cell = cot[cTILEOFF[l] + tile];
    if (cell < 0) return;
    int tb = tile * 64;
    int valid = csPad[l * 64 + cell] + cellTot[l * 64 + cell] - tb;
    if (valid > 64) valid = 64;
    conv_b_tile<64>(f1bf + cF1OFF[l], cbrec + cSEOFF[l], whi + cWOFF[l],
                    cell, tb, valid, Ph + (size_t)(cSEOFF[l] - 324096) * 64,
                    fxs, fys, fzs, srcs);
}

// ---- node_b: gather cell-order Ph rows via cpos, + R (in f2) + bias, relu -----------
__device__ __forceinline__ void node_b_core(const __half* __restrict__ PhL,
                                            const int* __restrict__ cposL,
                                            int start, int deg, float* __restrict__ f2row,
                                            const float* __restrict__ biasb, int lane) {
    float s0 = 0.f, s1 = 0.f;
    int j = 0;
    for (; j + 2 <= deg; j += 2) {
        int r0 = cposL[start + j];
        int r1 = cposL[start + j + 1];
        s0 += __half2float(PhL[(size_t)r0 * 64 + lane]);
        s1 += __half2float(PhL[(size_t)r1 * 64 + lane]);
    }
    if (j < deg) s0 += __half2float(PhL[(size_t)cposL[start + j] * 64 + lane]);
    float s = s0 + s1;
    int dv = deg > 1 ? deg : 1;
    s /= (float)dv;
    s += f2row[lane] + biasb[lane];
    f2row[lane] = fmaxf(s, 0.f);
}

__launch_bounds__(256)
__global__ void node_b32(const __half* __restrict__ Ph, const int* __restrict__ cpos,
                         const int* __restrict__ dbase, const int* __restrict__ boff,
                         const int* __restrict__ dcnt, const float* __restrict__ biasb,
                         float* __restrict__ f2) {
    int lane = threadIdx.x & 63;
    int node = blockIdx.x * 4 + (threadIdx.x >> 6);
    if (node >= 20000) return;
    int start = dbase[node] + boff[node >> 8];
    int deg = dcnt[node];
    node_b_core(Ph, cpos, start, deg, f2 + (size_t)node * 64, biasb, lane);
}

__launch_bounds__(256)
__global__ void node_b64(const __half* __restrict__ Ph, const int* __restrict__ cpos,
                         const int* __restrict__ dbase, const int* __restrict__ boff,
                         const int* __restrict__ dcnt, P5f BiasB, float* __restrict__ f2) {
    const int NB2[4] = {0, 2500, 3750, 4375};
    int lane = threadIdx.x & 63;
    int blk = blockIdx.x;
    int li = (blk >= 4375) ? 3 : (blk >= 3750) ? 2 : (blk >= 2500) ? 1 : 0;
    int l = li + 1;
    int node = (blk - NB2[li]) * 4 + (threadIdx.x >> 6);
    if (node >= cN[l]) return;
    int start = dbase[cNOFF[l] + node] + boff[cNBLKOFF[l] + (node >> 8)];
    int deg = dcnt[cNOFF[l] + node];
    node_b_core(Ph + (size_t)(cSEOFF[l] - 324096) * 64, cpos + cEOFF[l], start, deg,
                f2 + (size_t)(cNOFF[l] + node) * 64, BiasB.p[l], lane);
}

// ---------------- readout: run-accumulated graph mean sums ----------------
__launch_bounds__(256)
__global__ void k_read(const float* __restrict__ f2, P5i Batch,
                       float* __restrict__ hsum, float* __restrict__ gcnt) {
    const int RC[5] = {0, 1250, 1875, 2188, 2345};
    int t = threadIdx.x;
    int lane = t & 63;
    int w = blockIdx.x * 4 + (t >> 6);
    if (w >= 2424) return;
    int l = (w >= 2345) ? 4 : (w >= 2188) ? 3 : (w >= 1875) ? 2 : (w >= 1250) ? 1 : 0;
    int base = (w - RC[l]) * 16;
    int Nl = cN[l];
    int nn = Nl - base; if (nn > 16) nn = 16;
    const int* batch = Batch.p[l];
    const float* fb = f2 + (size_t)(cNOFF[l] + base) * 64;
    int curg = -1; float hacc = 0.f; int crun = 0;
    for (int j = 0; j < nn; j++) {
        int g = batch[base + j];
        if (g != curg) {
            if (curg >= 0) {
                atomicAdd(&hsum[curg * 320 + l * 64 + lane], hacc);
                if (lane == 0) atomicAdd(&gcnt[l * 64 + curg], (float)crun);
            }
            curg = g; hacc = 0.f; crun = 0;
        }
        hacc += fb[(size_t)j * 64 + lane];
        crun++;
    }
    if (curg >= 0) {
        atomicAdd(&hsum[curg * 320 + l * 64 + lane], hacc);
        if (lane == 0) atomicAdd(&gcnt[l * 64 + curg], (float)crun);
    }
}

// ---------------- FC + log_softmax: one block per graph ----------------
__global__ void fc_kernel(const float* __restrict__ hsum, const float* __restrict__ gcnt,
                          const float* __restrict__ fcw, const float* __restrict__ fcb,
                          float* __restrict__ out) {
    int g = blockIdx.x;
    int lane = threadIdx.x;  // 64
    float partial[10];
#pragma unroll
    for (int t = 0; t < 10; t++) partial[t] = 0.f;
#pragma unroll
    for (int k = 0; k < 5; k++) {
        int j = k * 64 + lane;
        float c = fmaxf(gcnt[k * 64 + g], 1.f);
        float h = hsum[g * 320 + j] / c;
        const float* fw = fcw + j * 10;
#pragma unroll
        for (int t = 0; t < 10; t++) partial[t] = fmaf(h, fw[t], partial[t]);
    }
#pragma unroll
    for (int off = 32; off >= 1; off >>= 1)
#pragma unroll
        for (int t = 0; t < 10; t++) partial[t] += __shfl_xor(partial[t], off, 64);
    if (lane == 0) {
        float logit[10];
#pragma unroll
        for (int t = 0; t < 10; t++) logit[t] = partial[t] + fcb[t];
        float m = logit[0];
#pragma unroll
        for (int t = 1; t < 10; t++) m = fmaxf(m, logit[t]);
        float sum = 0.f;
#pragma unroll
        for (int t = 0; t < 10; t++) sum += expf(logit[t] - m);
        float lse = m + logf(sum);
#pragma unroll
        for (int t = 0; t < 10; t++) out[g * 10 + t] = logit[t] - lse;
    }
}

extern "C" void kernel_launch(void* const* d_in, const int* in_sizes, int n_in,
                              void* d_out, int out_size, void* d_ws, size_t ws_size,
                              hipStream_t stream) {
    int* wsI = (int*)d_ws;
    int*   dcnt  = wsI;                          // 38750
    int*   rank  = dcnt + 38750;                 // 38750
    float* hsum  = (float*)(rank + 38750);       // 20480
    float* gcnt  = hsum + 20480;                 // 320
    float* f1    = gcnt + 320;                   // 1,840,000
    float* f2    = f1 + 1840000;                 // 2,480,000 (also holds R pre-node_b)
    int*   dbase = (int*)(f2 + 2480000);         // 38750
    int*   bsum  = dbase + 38750;                // 160
    int*   boff  = bsum + 160;                   // 160
    int*   eposc = boff + 160;                   // 620000
    int*   cpos  = eposc + 620000;               // 620000
    int*   bb    = cpos + 620000;                // 155136
    int*   csPad = bb + 155136;                  // 320
    int*   cellTot = csPad + 320;                // 320
    int*   cot   = cellTot + 320;                // 10008
    int4*  cbrec = (int4*)(((size_t)(cot + 10008) + 15) & ~(size_t)15);   // 640512 recs
    int4*  darec = cbrec + 640512;               // 620000 recs
    ushortT* f1bf = (ushortT*)(darec + 620000);  // 1,840,000 ushorts
    uint4* whi   = (uint4*)(((size_t)(f1bf + 1840000) + 15) & ~(size_t)15);  // 288000
    uint4* rbsw  = whi + 288000;                 // 2304
    __half* Ph   = (__half*)(rbsw + 2304);       // 324096 rows of 64 (~41.5MB, reused)

    hipMemsetAsync(dcnt, 0, (size_t)(38750 * 2 + 20480 + 320) * sizeof(int), stream);

    P5f PS, X, WA, RootA, BiasA, WB, RootB, BiasB;
    P5i EI, Batch;
    for (int l = 0; l < 5; l++) {
        const int b = l * 10;
        X.p[l]     = (const float*)d_in[b + 0];
        PS.p[l]    = (const float*)d_in[b + 1];
        EI.p[l]    = (const int*)d_in[b + 2];
        Batch.p[l] = (const int*)d_in[b + 3];
        WA.p[l]    = (const float*)d_in[b + 4];
        RootA.p[l] = (const float*)d_in[b + 5];
        BiasA.p[l] = (const float*)d_in[b + 6];
        WB.p[l]    = (const float*)d_in[b + 7];
        RootB.p[l] = (const float*)d_in[b + 8];
        BiasB.p[l] = (const float*)d_in[b + 9];
    }

    // prep (all levels fused)
    k_hist<<<2424, 256, 0, stream>>>(PS, EI, dcnt, bb);
    k_cellscan<<<5, 64, 0, stream>>>(bb, csPad, cellTot, cot);
    k_cellscatter<<<2424, 256, 0, stream>>>(PS, EI, bb, csPad, cbrec, eposc);
    k_nscan1<<<154, 256, 0, stream>>>(dcnt, dbase, bsum);
    k_nscan2<<<5, 64, 0, stream>>>(bsum, boff);
    k_dscatter<<<2424, 256, 0, stream>>>(PS, EI, dbase, boff, rank, eposc, cpos, darec);
    k_wswz<<<1125, 256, 0, stream>>>(WB, whi);
    k_rswz<<<9, 256, 0, stream>>>(RootB, rbsw);

    // conv A (LDS-staged edges + corner-parallel + ILP'd tail), all levels
    conv_a_fused<<<2424, 256, 0, stream>>>(X, WA, RootA, BiasA, darec,
                                           dbase, boff, dcnt, f1, f1bf);

    // R = f1 @ rootb into f2 (MFMA)
    k_rgemm<<<609, 256, 0, stream>>>(f1bf, rbsw, f2);

    // conv B (cell-order Ph) + node gather (Ph reused l0 vs l1-4)
    conv_b32<<<5064, 256, 0, stream>>>(f1bf, cbrec, whi, cot, csPad, cellTot, Ph);
    node_b32<<<5000, 256, 0, stream>>>(Ph, cpos, dbase, boff, dcnt, BiasB.p[0], f2);
    conv_b64<<<4944, 256, 0, stream>>>(f1bf, cbrec, whi, cot, csPad, cellTot, Ph);
    node_b64<<<4688, 256, 0, stream>>>(Ph, cpos, dbase, boff, dcnt, BiasB, f2);

    // readout + FC
    k_read<<<606, 256, 0, stream>>>(f2, Batch, hsum, gcnt);
    fc_kernel<<<64, 64, 0, stream>>>(hsum, gcnt, (const float*)d_in[50], (const float*)d_in[51],
                                     (float*)d_out);
}

// Round 10
// 494.159 us; speedup vs baseline: 2.1201x; 1.0081x over previous
//
#include <hip/hip_runtime.h>
#include <hip/hip_fp16.h>
#include <math.h>

#define NUM_GRAPHS 64

typedef unsigned short ushortT;
typedef __attribute__((ext_vector_type(8))) short bf16x8;
typedef __attribute__((ext_vector_type(4))) float f32x4;

// ---- static level tables ----
constexpr int cN[5]       = {20000, 10000, 5000, 2500, 1250};
constexpr int cE[5]       = {320000, 160000, 80000, 40000, 20000};
constexpr int cNOFF[6]    = {0, 20000, 30000, 35000, 37500, 38750};
constexpr int cEOFF[6]    = {0, 320000, 480000, 560000, 600000, 620000};
constexpr int cEBLKOFF[6] = {0, 1250, 1875, 2188, 2345, 2424};
constexpr int cNBLKOFF[6] = {0, 79, 119, 139, 149, 154};
constexpr int cMT[5]      = {5064, 2564, 1314, 689, 377};
constexpr int cTILEOFF[6] = {0, 5064, 7628, 8942, 9631, 10008};
constexpr int cSEOFF[6]   = {0, 324096, 488192, 572288, 616384, 640512};
constexpr int cF1OFF[6]   = {0, 640000, 1280000, 1600000, 1760000, 1840000};
constexpr int cWOFF[6]    = {0, 32000, 96000, 160000, 224000, 288000};
constexpr int cABLK[6]    = {0, 1250, 1875, 2188, 2345, 2424};   // ceil(N/16) prefix
constexpr int cRBOFF[5]   = {0, 256, 768, 1280, 1792};           // rootb swizzle uint4 offsets
constexpr int cRGB[6]     = {0, 313, 470, 549, 589, 609};        // ceil(N/64) prefix

struct P5f { const float* p[5]; };
struct P5i { const int* p[5]; };

__device__ __forceinline__ int lvl_e(int b) {
    return (b >= cEBLKOFF[4]) ? 4 : (b >= cEBLKOFF[3]) ? 3 : (b >= cEBLKOFF[2]) ? 2 : (b >= cEBLKOFF[1]) ? 1 : 0;
}
__device__ __forceinline__ int lvl_n(int b) {
    return (b >= cNBLKOFF[4]) ? 4 : (b >= cNBLKOFF[3]) ? 3 : (b >= cNBLKOFF[2]) ? 2 : (b >= cNBLKOFF[1]) ? 1 : 0;
}

__device__ __forceinline__ ushortT f2bf(float f) {
    union { float f; unsigned int u; } v; v.f = f;
    unsigned int r = (v.u + 0x7FFFu + ((v.u >> 16) & 1u)) >> 16;
    return (ushortT)r;
}
__device__ __forceinline__ float h2f_lo(unsigned int u) {
    return __half2float(__ushort_as_half((ushortT)(u & 0xFFFFu)));
}
__device__ __forceinline__ float h2f_hi(unsigned int u) {
    return __half2float(__ushort_as_half((ushortT)(u >> 16)));
}

// ---------------- prep: per-block cell histogram + dst degree count ----------------
__global__ void k_hist(P5f PS, P5i EI, int* __restrict__ dcnt, int* __restrict__ bb) {
    int b = blockIdx.x;
    int l = lvl_e(b);
    int lb = b - cEBLKOFF[l];
    int E = cE[l];
    __shared__ int h[64];
    int t = threadIdx.x;
    if (t < 64) h[t] = 0;
    __syncthreads();
    int e = lb * 256 + t;
    if (e < E) {
        atomicAdd(&dcnt[cNOFF[l] + EI.p[l][E + e]], 1);
        const float* ps = PS.p[l];
        int c = (int)floorf(ps[e * 3] * 4.f) * 16 + (int)floorf(ps[e * 3 + 1] * 4.f) * 4
              + (int)floorf(ps[e * 3 + 2] * 4.f);
        atomicAdd(&h[c], 1);
    }
    __syncthreads();
    if (t < 64) bb[(size_t)b * 64 + t] = h[t];
}

// ---------------- cell scan ----------------
__global__ void k_cellscan(int* __restrict__ bb_all, int* __restrict__ csPad,
                           int* __restrict__ cellTot, int* __restrict__ cot_all) {
    int l = blockIdx.x;
    int c = threadIdx.x;
    int* bb = bb_all + (size_t)cEBLKOFF[l] * 64;
    int nblk = cEBLKOFF[l + 1] - cEBLKOFF[l];
    int run = 0;
    int b = 0;
    for (; b + 16 <= nblk; b += 16) {
        int v[16];
#pragma unroll
        for (int u = 0; u < 16; u++) v[u] = bb[(b + u) * 64 + c];
#pragma unroll
        for (int u = 0; u < 16; u++) { bb[(b + u) * 64 + c] = run; run += v[u]; }
    }
    for (; b < nblk; b++) { int v = bb[b * 64 + c]; bb[b * 64 + c] = run; run += v; }
    int tot = run;
    cellTot[l * 64 + c] = tot;
    int tiles = (tot + 63) >> 6;
    int x = tiles;
#pragma unroll
    for (int off = 1; off < 64; off <<= 1) { int y = __shfl_up(x, off, 64); if (c >= off) x += y; }
    int tileBase = x - tiles;
    csPad[l * 64 + c] = tileBase * 64;
    int* cot = cot_all + cTILEOFF[l];
    for (int i = 0; i < tiles; i++) cot[tileBase + i] = c;
    int nT = __shfl(x, 63, 64);
    int mt = cMT[l];
    for (int i = nT + c; i < mt; i += 64) cot[i] = -1;
}

// ---------------- node-degree scans ----------------
__global__ void k_nscan1(const int* __restrict__ dcnt, int* __restrict__ dbase, int* __restrict__ bsum) {
    int b = blockIdx.x;
    int l = lvl_n(b);
    int lb = b - cNBLKOFF[l];
    int n = cN[l];
    __shared__ int sh[256];
    int t = threadIdx.x;
    int i = lb * 256 + t;
    int v = (i < n) ? dcnt[cNOFF[l] + i] : 0;
    sh[t] = v;
    __syncthreads();
    for (int off = 1; off < 256; off <<= 1) {
        int y = (t >= off) ? sh[t - off] : 0;
        __syncthreads();
        sh[t] += y;
        __syncthreads();
    }
    if (i < n) dbase[cNOFF[l] + i] = sh[t] - v;
    if (t == 255) bsum[b] = sh[255];
}

__global__ void k_nscan2(const int* __restrict__ bsum, int* __restrict__ boff) {
    int l = blockIdx.x;
    int o = cNBLKOFF[l];
    int nb = cNBLKOFF[l + 1] - o;
    int t = threadIdx.x;
    int v = (t < nb) ? bsum[o + t] : 0;
    int s = v;
#pragma unroll
    for (int off = 1; off < 64; off <<= 1) { int y = __shfl_up(s, off, 64); if (t >= off) s += y; }
    int tot = __shfl(s, 63, 64);
    if (t < nb) boff[o + t] = s - v;
    int t2 = t + 64;
    int v2 = (t2 < nb) ? bsum[o + t2] : 0;
    int s2 = v2;
#pragma unroll
    for (int off = 1; off < 64; off <<= 1) { int y = __shfl_up(s2, off, 64); if (t >= off) s2 += y; }
    if (t2 < nb) boff[o + t2] = tot + s2 - v2;
}

// ---- merged scatter: one edge pass -> cbrec (cell order), darec (dst order), cpos ----
__global__ void k_scatter(P5f PS, P5i EI, const int* __restrict__ bb, const int* __restrict__ csPad,
                          const int* __restrict__ dbase, const int* __restrict__ boff,
                          int* __restrict__ rank,
                          int4* __restrict__ cbrec, int4* __restrict__ darec,
                          int* __restrict__ cpos) {
    int b = blockIdx.x;
    int l = lvl_e(b);
    int lb = b - cEBLKOFF[l];
    int E = cE[l];
    __shared__ int base[64];
    __shared__ int cnt[64];
    int t = threadIdx.x;
    if (t < 64) { base[t] = bb[(size_t)b * 64 + t] + csPad[l * 64 + t]; cnt[t] = 0; }
    __syncthreads();
    int e = lb * 256 + t;
    if (e >= E) return;
    const float* ps = PS.p[l];
    float v0 = ps[e * 3] * 4.f, v1 = ps[e * 3 + 1] * 4.f, v2 = ps[e * 3 + 2] * 4.f;
    float f0 = floorf(v0), f1v = floorf(v1), f2v = floorf(v2);
    int c = (int)f0 * 16 + (int)f1v * 4 + (int)f2v;
    int r = atomicAdd(&cnt[c], 1);
    int posc = base[c] + r;
    const int* ei = EI.p[l];
    int src = ei[e];
    int dst = ei[E + e];
    int posd = dbase[cNOFF[l] + dst] + boff[cNBLKOFF[l] + (dst >> 8)]
             + atomicAdd(&rank[cNOFF[l] + dst], 1);
    unsigned int fxfy = (unsigned int)__half_as_ushort(__float2half(v0 - f0))
                      | ((unsigned int)__half_as_ushort(__float2half(v1 - f1v)) << 16);
    unsigned int fzp  = (unsigned int)__half_as_ushort(__float2half(v2 - f2v));
    int4 rc;
    rc.x = src; rc.y = 0; rc.z = (int)fxfy; rc.w = (int)fzp;
    cbrec[cSEOFF[l] + posc] = rc;
    int4 rd;
    rd.x = src | (dst << 16); rd.y = c; rd.z = (int)fxfy; rd.w = (int)fzp;
    darec[cEOFF[l] + posd] = rd;
    cpos[cEOFF[l] + posd] = posc;
}

// -------- W + rootb swizzle (fused): fp32 -> MFMA B-frag bf16 ----------
__global__ void k_wswz(P5f WB, P5f RootB, uint4* __restrict__ hi4, uint4* __restrict__ rb) {
    int idx = blockIdx.x * 256 + threadIdx.x;
    if (idx >= 290304) return;
    if (idx < 288000) {
        int l = (idx >= 224000) ? 4 : (idx >= 160000) ? 3 : (idx >= 96000) ? 2 : (idx >= 32000) ? 1 : 0;
        int local = idx - cWOFF[l];
        int T = l ? 2 : 1, C = l ? 64 : 32;
        int lane = local & 63;
        int blk = (local >> 6) & 3;
        int rest = local >> 8;
        int st = rest % T, s = rest / T;
        int q = lane >> 4, n = blk * 16 + (lane & 15);
        const float* W = WB.p[l];
        union { ushortT u[8]; uint4 v; } ph;
#pragma unroll
        for (int j = 0; j < 8; j++) {
            int k = st * 32 + q * 8 + j;
            ph.u[j] = f2bf(W[((size_t)s * C + k) * 64 + n]);
        }
        hi4[idx] = ph.v;
    } else {
        int id2 = idx - 288000;
        int l = (id2 >= 1792) ? 4 : (id2 >= 1280) ? 3 : (id2 >= 768) ? 2 : (id2 >= 256) ? 1 : 0;
        int local = id2 - cRBOFF[l];
        int lane = local & 63;
        int w = (local >> 6) & 3;
        int st = local >> 8;
        int q = lane >> 4, n = w * 16 + (lane & 15);
        const float* R = RootB.p[l];
        union { ushortT u[8]; uint4 v; } ph;
#pragma unroll
        for (int j = 0; j < 8; j++) {
            int k = st * 32 + q * 8 + j;
            ph.u[j] = f2bf(R[k * 64 + n]);
        }
        rb[id2] = ph.v;
    }
}

// ---- Fused Conv A: LDS-staged edges, corner-parallel, ILP'd S@Wa tail ---------------
template<int C1>
__device__ __forceinline__ void conv_a_gemm(const float* __restrict__ S, const float* __restrict__ Wa,
                                            const float* __restrict__ x, const float* __restrict__ ra,
                                            const float* __restrict__ ba, const int* __restrict__ dcl,
                                            int node0, int nn, float* __restrict__ f1l,
                                            ushortT* __restrict__ f1bfl, int t) {
    int ch = t % C1;
    int npp = 256 / C1;
    float bias = ba[ch];
    float root = ra[ch];
    for (int node = t / C1; node < nn; node += npp) {
        const float* Sr = S + node * 126;
        float s0 = 0.f, s1 = 0.f, s2 = 0.f, s3 = 0.f;
#pragma unroll
        for (int k = 0; k < 124; k += 4) {
            s0 = fmaf(Sr[k],     Wa[k * C1 + ch],       s0);
            s1 = fmaf(Sr[k + 1], Wa[(k + 1) * C1 + ch], s1);
            s2 = fmaf(Sr[k + 2], Wa[(k + 2) * C1 + ch], s2);
            s3 = fmaf(Sr[k + 3], Wa[(k + 3) * C1 + ch], s3);
        }
        float s = ((s0 + s1) + (s2 + s3)) + Sr[124] * Wa[124 * C1 + ch];
        int gnode = node0 + node;
        int dv = dcl[gnode];
        float d = (float)(dv > 1 ? dv : 1);
        float o = s / d + x[gnode] * root + bias;
        o = fmaxf(o, 0.f);
        f1l[(size_t)gnode * C1 + ch] = o;
        f1bfl[(size_t)gnode * C1 + ch] = f2bf(o);
    }
}

__launch_bounds__(256)
__global__ void conv_a_fused(P5f X, P5f WA, P5f RootA, P5f BiasA,
                             const int4* __restrict__ darec,
                             const int* __restrict__ dbase, const int* __restrict__ boff,
                             const int* __restrict__ dcnt, float* __restrict__ f1,
                             ushortT* __restrict__ f1bf) {
    __shared__ float S[16 * 126];
    __shared__ int infoS[256];
    __shared__ unsigned int fxyS[256];
    __shared__ unsigned int fzS[256];
    __shared__ float xsS[256];
    int b = blockIdx.x;
    int l = (b >= cABLK[4]) ? 4 : (b >= cABLK[3]) ? 3 : (b >= cABLK[2]) ? 2 : (b >= cABLK[1]) ? 1 : 0;
    int node0 = (b - cABLK[l]) * 16;
    int n = cN[l];
    int nn = n - node0; if (nn > 16) nn = 16;
    int t = threadIdx.x;
    for (int i = t; i < 16 * 126; i += 256) S[i] = 0.f;
    const int* db = dbase + cNOFF[l];
    const int* bo = boff + cNBLKOFF[l];
    int estart = db[node0] + bo[node0 >> 8];
    int vend = node0 + nn;
    int eend = (vend >= n) ? cE[l] : (db[vend] + bo[vend >> 8]);
    const float* x = X.p[l];
    const int4* dr = darec + cEOFF[l];
    const int bx = t & 1, by = (t >> 1) & 1, bz = (t >> 2) & 1;
    for (int cs = estart; cs < eend; cs += 256) {
        int p = cs + t;
        if (p < eend) {
            int4 r = dr[p];
            infoS[t] = ((((unsigned int)r.x) >> 16) - node0) * 64 + r.y;
            fxyS[t] = (unsigned int)r.z;
            fzS[t] = (unsigned int)r.w;
            xsS[t] = x[r.x & 0xFFFF];
        }
        __syncthreads();
        int ne = eend - cs; if (ne > 256) ne = 256;
        for (int j = (t >> 3); j < ne; j += 32) {
            int info = infoS[j];
            int nl = info >> 6, cell = info & 63;
            unsigned int uz = fxyS[j];
            float fx = h2f_lo(uz), fy = h2f_hi(uz), fz = h2f_lo(fzS[j]);
            float xs = xsS[j];
            int cx = cell >> 4, cy = (cell >> 2) & 3, cz = cell & 3;
            int slot = (cx + bx) * 25 + (cy + by) * 5 + (cz + bz);
            float wc = (bx ? fx : 1.f - fx) * (by ? fy : 1.f - fy) * (bz ? fz : 1.f - fz);
            atomicAdd(&S[nl * 126 + slot], wc * xs);
        }
        __syncthreads();
    }
    if (l == 0)
        conv_a_gemm<32>(S, WA.p[0], X.p[0], RootA.p[0], BiasA.p[0], dcnt + cNOFF[0],
                        node0, nn, f1 + cF1OFF[0], f1bf + cF1OFF[0], t);
    else
        conv_a_gemm<64>(S, WA.p[l], X.p[l], RootA.p[l], BiasA.p[l], dcnt + cNOFF[l],
                        node0, nn, f1 + cF1OFF[l], f1bf + cF1OFF[l], t);
}

// ---- R-gemm: f2 = f1bf @ rootb (bf16 MFMA), per-64-node tiles -----------------------
__launch_bounds__(256)
__global__ void k_rgemm(const ushortT* __restrict__ f1bf, const uint4* __restrict__ rb,
                        float* __restrict__ f2) {
    int b = blockIdx.x;
    int l = (b >= cRGB[4]) ? 4 : (b >= cRGB[3]) ? 3 : (b >= cRGB[2]) ? 2 : (b >= cRGB[1]) ? 1 : 0;
    int node0 = (b - cRGB[l]) * 64;
    int n = cN[l];
    int nn = n - node0; if (nn > 64) nn = 64;
    int t = threadIdx.x;
    int lane = t & 63, w = t >> 6;
    int q = lane >> 4, m = lane & 15;
    const int CIN = l ? 64 : 32;
    const int T = l ? 2 : 1;
    const ushortT* fl = f1bf + cF1OFF[l];
    const uint4* rbl = rb + cRBOFF[l];
    f32x4 C[4];
#pragma unroll
    for (int mt = 0; mt < 4; mt++) C[mt] = (f32x4){0.f, 0.f, 0.f, 0.f};
    for (int st = 0; st < T; st++) {
        bf16x8 bh = __builtin_bit_cast(bf16x8, rbl[(st * 4 + w) * 64 + lane]);
#pragma unroll
        for (int mt = 0; mt < 4; mt++) {
            int row = 16 * mt + m;
            int nr = node0 + row; if (nr > n - 1) nr = n - 1;
            bf16x8 a = *(const bf16x8*)&fl[(size_t)nr * CIN + st * 32 + q * 8];
            C[mt] = __builtin_amdgcn_mfma_f32_16x16x32_bf16(a, bh, C[mt], 0, 0, 0);
        }
    }
#pragma unroll
    for (int mt = 0; mt < 4; mt++)
#pragma unroll
        for (int rr = 0; rr < 4; rr++) {
            int row = 16 * mt + q * 4 + rr;
            if (row < nn)
                f2[(size_t)(cNOFF[l] + node0 + row) * 64 + 16 * w + m] = C[mt][rr];
        }
}

// ---- Conv B tile: A-frags from global bf16, z-paired epilogue, cell-order store -----
template<int CIN>
__device__ __forceinline__ void conv_b_tile(
    const ushortT* __restrict__ f1bfl, const int4* __restrict__ cbrec_l,
    const uint4* __restrict__ whiL,
    int cell, int tb, int valid, __half* __restrict__ pout,
    float* fxs, float* fys, float* fzs, int* srcs) {
    const int T = CIN / 32;
    int t = threadIdx.x;
    if (t < 64) {
        bool v = t < valid;
        int4 r;
        if (v) r = cbrec_l[tb + t]; else { r.x = 0; r.y = 0; r.z = 0; r.w = 0; }
        srcs[t] = r.x;
        unsigned int uz = (unsigned int)r.z;
        fxs[t] = h2f_lo(uz);
        fys[t] = h2f_hi(uz);
        fzs[t] = h2f_lo((unsigned int)r.w);
    }
    __syncthreads();

    int lane = t & 63, w = t >> 6;
    int q = lane >> 4, m = lane & 15;

    bf16x8 ahr[4][T];
#pragma unroll
    for (int mt = 0; mt < 4; mt++) {
        int src = srcs[16 * mt + m];
#pragma unroll
        for (int st = 0; st < T; st++)
            ahr[mt][st] = *(const bf16x8*)&f1bfl[(size_t)src * CIN + st * 32 + q * 8];
    }
    float fxr[16], fyr[16], fzr[16], gzr[16];
#pragma unroll
    for (int mt = 0; mt < 4; mt++)
#pragma unroll
        for (int rr = 0; rr < 4; rr++) {
            int row = 16 * mt + q * 4 + rr;
            fxr[mt * 4 + rr] = fxs[row];
            fyr[mt * 4 + rr] = fys[row];
            float fz = fzs[row];
            fzr[mt * 4 + rr] = fz;
            gzr[mt * 4 + rr] = 1.f - fz;
        }
    int cx = cell >> 4, cy = (cell >> 2) & 3, cz = cell & 3;
    f32x4 acc[4];
#pragma unroll
    for (int mt = 0; mt < 4; mt++) acc[mt] = (f32x4){0.f, 0.f, 0.f, 0.f};

#pragma unroll
    for (int xy = 0; xy < 4; xy++) {
        const int bx = xy & 1, by = xy >> 1;
        int slot0 = (cx + bx) * 25 + (cy + by) * 5 + cz;  // bz=0; bz=1 is slot0+1
        f32x4 C0[4], C1[4];
#pragma unroll
        for (int mt = 0; mt < 4; mt++) {
            C0[mt] = (f32x4){0.f, 0.f, 0.f, 0.f};
            C1[mt] = (f32x4){0.f, 0.f, 0.f, 0.f};
        }
#pragma unroll
        for (int st = 0; st < T; st++) {
            bf16x8 b0 = __builtin_bit_cast(bf16x8, whiL[((size_t)(slot0 * T + st) * 4 + w) * 64 + lane]);
            bf16x8 b1 = __builtin_bit_cast(bf16x8, whiL[((size_t)((slot0 + 1) * T + st) * 4 + w) * 64 + lane]);
#pragma unroll
            for (int mt = 0; mt < 4; mt++) {
                C0[mt] = __builtin_amdgcn_mfma_f32_16x16x32_bf16(ahr[mt][st], b0, C0[mt], 0, 0, 0);
                C1[mt] = __builtin_amdgcn_mfma_f32_16x16x32_bf16(ahr[mt][st], b1, C1[mt], 0, 0, 0);
            }
        }
#pragma unroll
        for (int mt = 0; mt < 4; mt++)
#pragma unroll
            for (int rr = 0; rr < 4; rr++) {
                int i16 = mt * 4 + rr;
                float wxy = (bx ? fxr[i16] : 1.f - fxr[i16]) * (by ? fyr[i16] : 1.f - fyr[i16]);
                float tt = fmaf(fzr[i16], C1[mt][rr], gzr[i16] * C0[mt][rr]);
                acc[mt][rr] = fmaf(wxy, tt, acc[mt][rr]);
            }
    }
    // coalesced cell-order store
#pragma unroll
    for (int mt = 0; mt < 4; mt++)
#pragma unroll
        for (int rr = 0; rr < 4; rr++) {
            int row = 16 * mt + q * 4 + rr;
            pout[(size_t)(tb + row) * 64 + 16 * w + m] = __float2half(acc[mt][rr]);
        }
}

__launch_bounds__(256)
__global__ void conv_b32(const ushortT* __restrict__ f1bf, const int4* __restrict__ cbrec,
                         const uint4* __restrict__ whi,
                         const int* __restrict__ cot, const int* __restrict__ csPad,
                         const int* __restrict__ cellTot, __half* __restrict__ Ph) {
    __shared__ float fxs[64], fys[64], fzs[64];
    __shared__ int srcs[64];
    int tile = blockIdx.x;
    int cell = cot[tile];
    if (cell < 0) return;
    int tb = tile * 64;
    int valid = csPad[cell] + cellTot[cell] - tb;
    if (valid > 64) valid = 64;
    conv_b_tile<32>(f1bf, cbrec, whi, cell, tb, valid, Ph, fxs, fys, fzs, srcs);
}

__launch_bounds__(256)
__global__ void conv_b64(const ushortT* __restrict__ f1bf, const int4* __restrict__ cbrec,
                         const uint4* __restrict__ whi,
                         const int* __restrict__ cot, const int* __restrict__ csPad,
                         const int* __restrict__ cellTot, __half* __restrict__ Ph) {
    __shared__ float fxs[64], fys[64], fzs[64];
    __shared__ int srcs[64];
    const int TB2[4] = {0, 2564, 3878, 4567};
    int blk = blockIdx.x;
    int li = (blk >= 4567) ? 3 : (blk >= 3878) ? 2 : (blk >= 2564) ? 1 : 0;
    int l = li + 1;
    int tile = blk - TB2[li];
    int cell = cot[cTILEOFF[l] + tile];
    if (cell < 0) return;
    int tb = tile * 64;
    int valid = csPad[l * 64 + cell] + cellTot[l * 64 + cell] - tb;
    if (valid > 64) valid = 64;
    conv_b_tile<64>(f1bf + cF1OFF[l], cbrec + cSEOFF[l], whi + cWOFF[l],
                    cell, tb, valid, Ph + (size_t)(cSEOFF[l] - 324096) * 64,
                    fxs, fys, fzs, srcs);
}

// ---- node_b: gather cell-order Ph rows via cpos, + R (in f2) + bias, relu -----------
__device__ __forceinline__ void node_b_core(const __half* __restrict__ PhL,
                                            const int* __restrict__ cposL,
                                            int start, int deg, float* __restrict__ f2row,
                                            const float* __restrict__ biasb, int lane) {
    float s0 = 0.f, s1 = 0.f;
    int j = 0;
    for (; j + 2 <= deg; j += 2) {
        int r0 = cposL[start + j];
        int r1 = cposL[start + j + 1];
        s0 += __half2float(PhL[(size_t)r0 * 64 + lane]);
        s1 += __half2float(PhL[(size_t)r1 * 64 + lane]);
    }
    if (j < deg) s0 += __half2float(PhL[(size_t)cposL[start + j] * 64 + lane]);
    float s = s0 + s1;
    int dv = deg > 1 ? deg : 1;
    s /= (float)dv;
    s += f2row[lane] + biasb[lane];
    f2row[lane] = fmaxf(s, 0.f);
}

__launch_bounds__(256)
__global__ void node_b32(const __half* __restrict__ Ph, const int* __restrict__ cpos,
                         const int* __restrict__ dbase, const int* __restrict__ boff,
                         const int* __restrict__ dcnt, const float* __restrict__ biasb,
                         float* __restrict__ f2) {
    int lane = threadIdx.x & 63;
    int node = blockIdx.x * 4 + (threadIdx.x >> 6);
    if (node >= 20000) return;
    int start = dbase[node] + boff[node >> 8];
    int deg = dcnt[node];
    node_b_core(Ph, cpos, start, deg, f2 + (size_t)node * 64, biasb, lane);
}

__launch_bounds__(256)
__global__ void node_b64(const __half* __restrict__ Ph, const int* __restrict__ cpos,
                         const int* __restrict__ dbase, const int* __restrict__ boff,
                         const int* __restrict__ dcnt, P5f BiasB, float* __restrict__ f2) {
    const int NB2[4] = {0, 2500, 3750, 4375};
    int lane = threadIdx.x & 63;
    int blk = blockIdx.x;
    int li = (blk >= 4375) ? 3 : (blk >= 3750) ? 2 : (blk >= 2500) ? 1 : 0;
    int l = li + 1;
    int node = (blk - NB2[li]) * 4 + (threadIdx.x >> 6);
    if (node >= cN[l]) return;
    int start = dbase[cNOFF[l] + node] + boff[cNBLKOFF[l] + (node >> 8)];
    int deg = dcnt[cNOFF[l] + node];
    node_b_core(Ph + (size_t)(cSEOFF[l] - 324096) * 64, cpos + cEOFF[l], start, deg,
                f2 + (size_t)(cNOFF[l] + node) * 64, BiasB.p[l], lane);
}

// ---------------- readout: run-accumulated graph mean sums ----------------
__launch_bounds__(256)
__global__ void k_read(const float* __restrict__ f2, P5i Batch,
                       float* __restrict__ hsum, float* __restrict__ gcnt) {
    const int RC[5] = {0, 1250, 1875, 2188, 2345};
    int t = threadIdx.x;
    int lane = t & 63;
    int w = blockIdx.x * 4 + (t >> 6);
    if (w >= 2424) return;
    int l = (w >= 2345) ? 4 : (w >= 2188) ? 3 : (w >= 1875) ? 2 : (w >= 1250) ? 1 : 0;
    int base = (w - RC[l]) * 16;
    int Nl = cN[l];
    int nn = Nl - base; if (nn > 16) nn = 16;
    const int* batch = Batch.p[l];
    const float* fb = f2 + (size_t)(cNOFF[l] + base) * 64;
    int curg = -1; float hacc = 0.f; int crun = 0;
    for (int j = 0; j < nn; j++) {
        int g = batch[base + j];
        if (g != curg) {
            if (curg >= 0) {
                atomicAdd(&hsum[curg * 320 + l * 64 + lane], hacc);
                if (lane == 0) atomicAdd(&gcnt[l * 64 + curg], (float)crun);
            }
            curg = g; hacc = 0.f; crun = 0;
        }
        hacc += fb[(size_t)j * 64 + lane];
        crun++;
    }
    if (curg >= 0) {
        atomicAdd(&hsum[curg * 320 + l * 64 + lane], hacc);
        if (lane == 0) atomicAdd(&gcnt[l * 64 + curg], (float)crun);
    }
}

// ---------------- FC + log_softmax: one block per graph ----------------
__global__ void fc_kernel(const float* __restrict__ hsum, const float* __restrict__ gcnt,
                          const float* __restrict__ fcw, const float* __restrict__ fcb,
                          float* __restrict__ out) {
    int g = blockIdx.x;
    int lane = threadIdx.x;  // 64
    float partial[10];
#pragma unroll
    for (int t = 0; t < 10; t++) partial[t] = 0.f;
#pragma unroll
    for (int k = 0; k < 5; k++) {
        int j = k * 64 + lane;
        float c = fmaxf(gcnt[k * 64 + g], 1.f);
        float h = hsum[g * 320 + j] / c;
        const float* fw = fcw + j * 10;
#pragma unroll
        for (int t = 0; t < 10; t++) partial[t] = fmaf(h, fw[t], partial[t]);
    }
#pragma unroll
    for (int off = 32; off >= 1; off >>= 1)
#pragma unroll
        for (int t = 0; t < 10; t++) partial[t] += __shfl_xor(partial[t], off, 64);
    if (lane == 0) {
        float logit[10];
#pragma unroll
        for (int t = 0; t < 10; t++) logit[t] = partial[t] + fcb[t];
        float m = logit[0];
#pragma unroll
        for (int t = 1; t < 10; t++) m = fmaxf(m, logit[t]);
        float sum = 0.f;
#pragma unroll
        for (int t = 0; t < 10; t++) sum += expf(logit[t] - m);
        float lse = m + logf(sum);
#pragma unroll
        for (int t = 0; t < 10; t++) out[g * 10 + t] = logit[t] - lse;
    }
}

extern "C" void kernel_launch(void* const* d_in, const int* in_sizes, int n_in,
                              void* d_out, int out_size, void* d_ws, size_t ws_size,
                              hipStream_t stream) {
    int* wsI = (int*)d_ws;
    int*   dcnt  = wsI;                          // 38750
    int*   rank  = dcnt + 38750;                 // 38750
    float* hsum  = (float*)(rank + 38750);       // 20480
    float* gcnt  = hsum + 20480;                 // 320
    float* f1    = gcnt + 320;                   // 1,840,000
    float* f2    = f1 + 1840000;                 // 2,480,000 (holds R pre-node_b)
    int*   dbase = (int*)(f2 + 2480000);         // 38750
    int*   bsum  = dbase + 38750;                // 160
    int*   boff  = bsum + 160;                   // 160
    int*   cpos  = boff + 160;                   // 620000
    int*   bb    = cpos + 620000;                // 155136
    int*   csPad = bb + 155136;                  // 320
    int*   cellTot = csPad + 320;                // 320
    int*   cot   = cellTot + 320;                // 10008
    int4*  cbrec = (int4*)(((size_t)(cot + 10008) + 15) & ~(size_t)15);   // 640512 recs
    int4*  darec = cbrec + 640512;               // 620000 recs
    ushortT* f1bf = (ushortT*)(darec + 620000);  // 1,840,000 ushorts
    uint4* whi   = (uint4*)(((size_t)(f1bf + 1840000) + 15) & ~(size_t)15);  // 288000
    uint4* rbsw  = whi + 288000;                 // 2304
    __half* Ph   = (__half*)(rbsw + 2304);       // 324096 rows of 64 (~41.5MB, reused)

    hipMemsetAsync(dcnt, 0, (size_t)(38750 * 2 + 20480 + 320) * sizeof(int), stream);

    P5f PS, X, WA, RootA, BiasA, WB, RootB, BiasB;
    P5i EI, Batch;
    for (int l = 0; l < 5; l++) {
        const int b = l * 10;
        X.p[l]     = (const float*)d_in[b + 0];
        PS.p[l]    = (const float*)d_in[b + 1];
        EI.p[l]    = (const int*)d_in[b + 2];
        Batch.p[l] = (const int*)d_in[b + 3];
        WA.p[l]    = (const float*)d_in[b + 4];
        RootA.p[l] = (const float*)d_in[b + 5];
        BiasA.p[l] = (const float*)d_in[b + 6];
        WB.p[l]    = (const float*)d_in[b + 7];
        RootB.p[l] = (const float*)d_in[b + 8];
        BiasB.p[l] = (const float*)d_in[b + 9];
    }

    // prep
    k_hist<<<2424, 256, 0, stream>>>(PS, EI, dcnt, bb);
    k_cellscan<<<5, 64, 0, stream>>>(bb, csPad, cellTot, cot);
    k_nscan1<<<154, 256, 0, stream>>>(dcnt, dbase, bsum);
    k_nscan2<<<5, 64, 0, stream>>>(bsum, boff);
    k_scatter<<<2424, 256, 0, stream>>>(PS, EI, bb, csPad, dbase, boff, rank,
                                        cbrec, darec, cpos);
    k_wswz<<<1134, 256, 0, stream>>>(WB, RootB, whi, rbsw);

    // conv A (LDS-staged edges + corner-parallel + ILP'd tail), all levels
    conv_a_fused<<<2424, 256, 0, stream>>>(X, WA, RootA, BiasA, darec,
                                           dbase, boff, dcnt, f1, f1bf);

    // R = f1 @ rootb into f2 (MFMA)
    k_rgemm<<<609, 256, 0, stream>>>(f1bf, rbsw, f2);

    // conv B (cell-order Ph) + node gather (Ph reused l0 vs l1-4)
    conv_b32<<<5064, 256, 0, stream>>>(f1bf, cbrec, whi, cot, csPad, cellTot, Ph);
    node_b32<<<5000, 256, 0, stream>>>(Ph, cpos, dbase, boff, dcnt, BiasB.p[0], f2);
    conv_b64<<<4944, 256, 0, stream>>>(f1bf, cbrec, whi, cot, csPad, cellTot, Ph);
    node_b64<<<4688, 256, 0, stream>>>(Ph, cpos, dbase, boff, dcnt, BiasB, f2);

    // readout + FC
    k_read<<<606, 256, 0, stream>>>(f2, Batch, hsum, gcnt);
    fc_kernel<<<64, 64, 0, stream>>>(hsum, gcnt, (const float*)d_in[50], (const float*)d_in[51],
                                     (float*)d_out);
}